// Round 1
// 2851.305 us; speedup vs baseline: 1.7864x; 1.7864x over previous
//
#include <hip/hip_runtime.h>
#include <math.h>

// ---------------- problem constants ----------------
constexpr int S_    = 4096;
constexpr int NKV   = 2048;
constexpr int NAUX  = 512;
constexpr int NNEW  = 1536;
constexpr int H_    = 2048;
constexpr int NH_   = 16;
constexpr int HD_   = 128;
constexpr int FF_   = 8192;
constexpr int NQ_   = 2048;   // NNEW + NAUX
constexpr int NK_   = 4096;   // NKV + NQ
constexpr int PRUNE = 409;
constexpr float EPSF = 1e-6f;

typedef __attribute__((ext_vector_type(8))) short bf16x8;
typedef __attribute__((ext_vector_type(16))) float f32x16;

__device__ __forceinline__ ushort f2bf(float x) {
  union { float f; unsigned u; } a; a.f = x;
  unsigned r = a.u + 0x7fffu + ((a.u >> 16) & 1u);
  return (ushort)(r >> 16);
}
__device__ __forceinline__ float bf2f(ushort h) {
  union { unsigned u; float f; } a; a.u = ((unsigned)h) << 16;
  return a.f;
}

// ---------------- index prep ----------------
__global__ __launch_bounds__(256) void prep_build(
    const int* __restrict__ kv_idxs, const int* __restrict__ aux_idxs,
    const int* __restrict__ new_idxs, const int* __restrict__ positions,
    int* hs_idxs, int* q_pos, int* key_tok, int* k_pos,
    int* map_full, int* in_hs, int* aux_bit, int* pruned_bit, int* last_hs)
{
  int t = blockIdx.x * 256 + threadIdx.x;     // grid covers 4096
  if (t < S_) { map_full[t] = 0; in_hs[t] = 0; aux_bit[t] = 0; pruned_bit[t] = 0; }
  if (t < NQ_) {
    int tok = (t < NNEW) ? new_idxs[t] : aux_idxs[t - NNEW];
    hs_idxs[t] = tok;
    q_pos[t] = positions[tok];
  }
  if (t < NK_) {
    int tok;
    if (t < NKV) tok = kv_idxs[t];
    else { int i = t - NKV; tok = (i < NNEW) ? new_idxs[i] : aux_idxs[i - NNEW]; }
    key_tok[t] = tok;
    k_pos[t] = positions[tok];
  }
  if (t < NNEW && new_idxs[t] == S_ - 1) last_hs[0] = t;
}

__global__ __launch_bounds__(256) void prep_scatter(
    const int* __restrict__ hs_idxs, const int* __restrict__ aux_idxs,
    int* map_full, int* in_hs, int* aux_bit)
{
  int t = blockIdx.x * 256 + threadIdx.x;
  if (t < NQ_) { int tok = hs_idxs[t]; map_full[tok] = t; in_hs[tok] = 1; }
  else if (t < NQ_ + NAUX) { aux_bit[aux_idxs[t - NQ_]] = 1; }
}

// Prune semantics of the reference (bug-compatible): see previous session note.
__global__ __launch_bounds__(256) void prune_set(
    const int* __restrict__ kv_idxs, int* __restrict__ pruned_bit)
{
  int t = blockIdx.x * 256 + threadIdx.x;
  if (t < PRUNE - 1) pruned_bit[kv_idxs[t]] = 1;
  if (t == PRUNE - 1) pruned_bit[S_ - 1] = 1;
}

// ---------------- hs = concat(hidden_states, aux_cache[aux_idxs]) ----------------
__global__ __launch_bounds__(256) void build_hs(
    const float* __restrict__ hidden, const float* __restrict__ auxc,
    const int* __restrict__ aux_idxs, float* __restrict__ hs)
{
  int gid = blockIdx.x * 256 + threadIdx.x;   // NQ*H/4 float4
  int c4 = gid & 511;                          // H/4 = 512
  int i  = gid >> 9;
  const float4* src;
  if (i < NNEW) src = (const float4*)hidden + (size_t)i * 512 + c4;
  else          src = (const float4*)auxc + (size_t)aux_idxs[i - NNEW] * 512 + c4;
  ((float4*)hs)[gid] = *src;
}

// ---------------- rmsnorm ----------------
__global__ __launch_bounds__(256) void rmsnorm_k(
    const float* __restrict__ in, const float* __restrict__ w, float* __restrict__ out)
{
  int row = blockIdx.x, t = threadIdx.x;
  const float4* r4 = (const float4*)(in + (size_t)row * H_);
  const float4* w4 = (const float4*)w;
  float ss = 0.f;
  float4 v0 = r4[t], v1 = r4[t + 256];
  ss += v0.x*v0.x + v0.y*v0.y + v0.z*v0.z + v0.w*v0.w;
  ss += v1.x*v1.x + v1.y*v1.y + v1.z*v1.z + v1.w*v1.w;
  __shared__ float red[256];
  red[t] = ss; __syncthreads();
  for (int s = 128; s > 0; s >>= 1) { if (t < s) red[t] += red[t + s]; __syncthreads(); }
  float inv = rsqrtf(red[0] / (float)H_ + EPSF);
  float4* o4 = (float4*)(out + (size_t)row * H_);
  float4 wv0 = w4[t], wv1 = w4[t + 256];
  float4 r0, r1;
  r0.x = v0.x*inv*wv0.x; r0.y = v0.y*inv*wv0.y; r0.z = v0.z*inv*wv0.z; r0.w = v0.w*inv*wv0.w;
  r1.x = v1.x*inv*wv1.x; r1.y = v1.y*inv*wv1.y; r1.z = v1.z*inv*wv1.z; r1.w = v1.w*inv*wv1.w;
  o4[t] = r0; o4[t + 256] = r1;
}

// ---------------- weight transpose + bf16 hi/lo split ----------------
// W[K][N] f32 -> Th/Tl [N][K] bf16 planes.  grid = (N/64, K/64)
__global__ __launch_bounds__(256) void wsplit_t(
    const float* __restrict__ Wsrc, ushort* __restrict__ Th, ushort* __restrict__ Tl,
    int K, int N)
{
  __shared__ float tile[64][65];
  const int bn = blockIdx.x * 64, bk = blockIdx.y * 64;
  const int t = threadIdx.x;
  #pragma unroll
  for (int r = 0; r < 4; ++r) {
    int idx = t + 256 * r;
    int row = idx >> 4, c = (idx & 15) * 4;
    float4 v = *(const float4*)(Wsrc + (size_t)(bk + row) * N + bn + c);
    tile[row][c] = v.x; tile[row][c+1] = v.y; tile[row][c+2] = v.z; tile[row][c+3] = v.w;
  }
  __syncthreads();
  #pragma unroll
  for (int r = 0; r < 4; ++r) {
    int idx = t + 256 * r;
    int n = idx >> 4, k = (idx & 15) * 4;
    float v0 = tile[k][n], v1 = tile[k+1][n], v2 = tile[k+2][n], v3 = tile[k+3][n];
    ushort4 h, l;
    h.x = f2bf(v0); l.x = f2bf(v0 - bf2f(h.x));
    h.y = f2bf(v1); l.y = f2bf(v1 - bf2f(h.y));
    h.z = f2bf(v2); l.z = f2bf(v2 - bf2f(h.z));
    h.w = f2bf(v3); l.w = f2bf(v3 - bf2f(h.w));
    size_t off = (size_t)(bn + n) * K + bk + k;
    *(ushort4*)(Th + off) = h;
    *(ushort4*)(Tl + off) = l;
  }
}

// ---------------- bf16x3 MFMA GEMM: C[M,N] = A[M,K] @ B[K,N] (+epilogue) ----------------
// A: f32 [M][K] (split in-flight).  Bh/Bl: bf16 [N][K] (pre-transposed planes).
// epi: 0 plain, 1 C = X + acc, 2 C = silu(X) * acc   (X may alias C for epi 2)
// tile 128x128, BK=32, 4 waves each own a 64x64 quadrant = 2x2 frags of 32x32.
__global__ __launch_bounds__(256) void gemm_mfma(
    const float* __restrict__ A, const ushort* __restrict__ Bh,
    const ushort* __restrict__ Bl, float* __restrict__ C,
    const float* __restrict__ X, int M, int N, int K, int epi)
{
  // rows padded to 40 u16 (80 B): b128 frag reads cover all 32 banks per 8 lanes
  __shared__ ushort As_h[128][40];
  __shared__ ushort As_l[128][40];
  __shared__ ushort Bs_h[128][40];
  __shared__ ushort Bs_l[128][40];
  const int bm = blockIdx.y * 128, bn = blockIdx.x * 128;
  const int t = threadIdx.x;
  const int lane = t & 63;
  const int wid = t >> 6;
  const int wr = wid >> 1, wc = wid & 1;   // wave quadrant (2x2)
  const int fr = lane & 31;                // A row / B col within 32-frag
  const int kg = lane >> 5;                // k-group (0/1) within K=16 slice

  f32x16 acc[2][2];
  #pragma unroll
  for (int mi = 0; mi < 2; ++mi)
    #pragma unroll
    for (int ni = 0; ni < 2; ++ni)
      #pragma unroll
      for (int r = 0; r < 16; ++r) acc[mi][ni][r] = 0.f;

  for (int k0 = 0; k0 < K; k0 += 32) {
    // stage A tile 128x32 f32 -> hi/lo bf16 (4 float4 per thread)
    #pragma unroll
    for (int r = 0; r < 4; ++r) {
      int idx = t + 256 * r;
      int row = idx >> 3, c = (idx & 7) * 4;
      float4 v = *(const float4*)(A + (size_t)(bm + row) * K + k0 + c);
      ushort4 h, l;
      h.x = f2bf(v.x); l.x = f2bf(v.x - bf2f(h.x));
      h.y = f2bf(v.y); l.y = f2bf(v.y - bf2f(h.y));
      h.z = f2bf(v.z); l.z = f2bf(v.z - bf2f(h.z));
      h.w = f2bf(v.w); l.w = f2bf(v.w - bf2f(h.w));
      *(ushort4*)(&As_h[row][c]) = h;
      *(ushort4*)(&As_l[row][c]) = l;
    }
    // stage B tile 128(n) x 32(k) bf16 hi/lo (4 ushort4 per thread per plane)
    #pragma unroll
    for (int r = 0; r < 4; ++r) {
      int idx = t + 256 * r;
      int n = idx >> 3, c = (idx & 7) * 4;
      size_t off = (size_t)(bn + n) * K + k0 + c;
      *(ushort4*)(&Bs_h[n][c]) = *(const ushort4*)(Bh + off);
      *(ushort4*)(&Bs_l[n][c]) = *(const ushort4*)(Bl + off);
    }
    __syncthreads();
    #pragma unroll
    for (int ks = 0; ks < 2; ++ks) {
      const int ko = ks * 16 + kg * 8;
      bf16x8 ah[2], al[2], bh[2], bl[2];
      #pragma unroll
      for (int mi = 0; mi < 2; ++mi) {
        ah[mi] = *(const bf16x8*)(&As_h[wr * 64 + mi * 32 + fr][ko]);
        al[mi] = *(const bf16x8*)(&As_l[wr * 64 + mi * 32 + fr][ko]);
        bh[mi] = *(const bf16x8*)(&Bs_h[wc * 64 + mi * 32 + fr][ko]);
        bl[mi] = *(const bf16x8*)(&Bs_l[wc * 64 + mi * 32 + fr][ko]);
      }
      #pragma unroll
      for (int mi = 0; mi < 2; ++mi)
        #pragma unroll
        for (int ni = 0; ni < 2; ++ni) {
          acc[mi][ni] = __builtin_amdgcn_mfma_f32_32x32x16_bf16(ah[mi], bh[ni], acc[mi][ni], 0, 0, 0);
          acc[mi][ni] = __builtin_amdgcn_mfma_f32_32x32x16_bf16(ah[mi], bl[ni], acc[mi][ni], 0, 0, 0);
          acc[mi][ni] = __builtin_amdgcn_mfma_f32_32x32x16_bf16(al[mi], bh[ni], acc[mi][ni], 0, 0, 0);
        }
    }
    __syncthreads();
  }
  // epilogue: C/D layout col = lane&31, row = (r&3) + 8*(r>>2) + 4*(lane>>5)
  #pragma unroll
  for (int mi = 0; mi < 2; ++mi) {
    #pragma unroll
    for (int ni = 0; ni < 2; ++ni) {
      #pragma unroll
      for (int r = 0; r < 16; ++r) {
        int row = bm + wr * 64 + mi * 32 + (r & 3) + 8 * (r >> 2) + 4 * kg;
        int col = bn + wc * 64 + ni * 32 + fr;
        size_t idx = (size_t)row * N + col;
        float v = acc[mi][ni][r];
        if (epi == 1) v += X[idx];
        else if (epi == 2) { float g = X[idx]; v = (g / (1.f + expf(-g))) * v; }
        C[idx] = v;
      }
    }
  }
}

// ---------------- RoPE in-place on q and k (f64 angles: pos amplifies ulp err) ----------------
__global__ __launch_bounds__(256) void rope_k(
    float* __restrict__ qb, float* __restrict__ kb, const int* __restrict__ q_pos)
{
  int gid = blockIdx.x * 256 + threadIdx.x;   // NQ*NH*64
  int d = gid & 63;
  int h = (gid >> 6) & 15;
  int i = gid >> 10;
  int p = q_pos[i];
  double ang = (double)p * exp((double)d * -0.14391156831212787);
  float c = (float)cos(ang), s = (float)sin(ang);
  size_t ia = (size_t)i * H_ + h * HD_ + d;
  size_t ib = ia + 64;
  float qa = qb[ia], qbv = qb[ib];
  qb[ia] = qa * c - qbv * s;
  qb[ib] = qbv * c + qa * s;
  float ka = kb[ia], kbv = kb[ib];
  kb[ia] = ka * c - kbv * s;
  kb[ib] = kbv * c + ka * s;
}

// ---------------- gather k_all/v_all = [cache rows | new rows], head-major ----------------
__global__ __launch_bounds__(256) void fill_kvall(
    const float* __restrict__ kcache, const float* __restrict__ vcache,
    const float* __restrict__ kb, const float* __restrict__ vb,
    const int* __restrict__ kv_idxs, float* __restrict__ k_all, float* __restrict__ v_all)
{
  int gid = blockIdx.x * 256 + threadIdx.x;   // NH*NK*HD/4
  int d4 = gid & 31;
  int j  = (gid >> 5) & (NK_ - 1);
  int h  = gid >> 17;
  float4 kv, vv;
  if (j < NKV) {
    int tok = kv_idxs[j];
    size_t src = ((size_t)h * S_ + tok) * 32 + d4;
    kv = ((const float4*)kcache)[src];
    vv = ((const float4*)vcache)[src];
  } else {
    int i = j - NKV;
    size_t src = (size_t)i * (H_ / 4) + h * 32 + d4;
    kv = ((const float4*)kb)[src];
    vv = ((const float4*)vb)[src];
  }
  ((float4*)k_all)[gid] = kv;
  ((float4*)v_all)[gid] = vv;
}

// ---------------- flash attention (f32), 64 queries x 32-key chunks ----------------
__global__ __launch_bounds__(256) void flash_attn(
    const float* __restrict__ qb, const float* __restrict__ k_all,
    const float* __restrict__ v_all, const int* __restrict__ q_pos,
    const int* __restrict__ k_pos, float* __restrict__ ctx)
{
  const int h = blockIdx.y;
  const int q0 = blockIdx.x * 64;
  __shared__ float qs[64][132];
  __shared__ float ks[32][132];
  __shared__ float vs[32][132];
  __shared__ float sc[64][33];
  __shared__ float mrow[64], lrow[64], arw[64];
  __shared__ int qps[64];
  __shared__ int tile_maxq;
  const int t = threadIdx.x;
  const int tr = t >> 4, tc = t & 15;
  const float scale = 0.08838834764831844f;   // 1/sqrt(128)

  #pragma unroll
  for (int r = 0; r < 8; ++r) {
    int idx = t + 256 * r;
    int qi = idx >> 5;
    int c = (idx & 31) * 4;
    *(float4*)(&qs[qi][c]) = *(const float4*)(qb + (size_t)(q0 + qi) * H_ + h * HD_ + c);
  }
  if (t < 64) { mrow[t] = -INFINITY; lrow[t] = 0.f; qps[t] = q_pos[q0 + t]; }
  __syncthreads();
  if (t == 0) {
    int mx = qps[0];
    for (int i = 1; i < 64; ++i) mx = max(mx, qps[i]);
    tile_maxq = mx;
  }
  __syncthreads();

  float acc[4][8];
  #pragma unroll
  for (int j = 0; j < 4; ++j)
    #pragma unroll
    for (int i = 0; i < 8; ++i) acc[j][i] = 0.f;

  for (int kt = 0; kt < NK_ / 32; ++kt) {
    int kbase = kt * 32;
    if (k_pos[kbase] > tile_maxq) continue;
    #pragma unroll
    for (int r = 0; r < 4; ++r) {
      int idx = t + 256 * r;
      int row = idx >> 5;
      int c = (idx & 31) * 4;
      *(float4*)(&ks[row][c]) = *(const float4*)(k_all + ((size_t)h * NK_ + kbase + row) * HD_ + c);
      *(float4*)(&vs[row][c]) = *(const float4*)(v_all + ((size_t)h * NK_ + kbase + row) * HD_ + c);
    }
    __syncthreads();
    float sv0[4] = {0,0,0,0}, sv1[4] = {0,0,0,0};
    #pragma unroll
    for (int d4 = 0; d4 < 32; ++d4) {
      float4 k0v = *(const float4*)(&ks[tc][d4 * 4]);
      float4 k1v = *(const float4*)(&ks[tc + 16][d4 * 4]);
      #pragma unroll
      for (int j = 0; j < 4; ++j) {
        float4 qv = *(const float4*)(&qs[tr * 4 + j][d4 * 4]);
        sv0[j] += qv.x*k0v.x + qv.y*k0v.y + qv.z*k0v.z + qv.w*k0v.w;
        sv1[j] += qv.x*k1v.x + qv.y*k1v.y + qv.z*k1v.z + qv.w*k1v.w;
      }
    }
    int kp0 = k_pos[kbase + tc], kp1 = k_pos[kbase + tc + 16];
    #pragma unroll
    for (int j = 0; j < 4; ++j) {
      int qp = qps[tr * 4 + j];
      sc[tr * 4 + j][tc]      = (kp0 <= qp) ? sv0[j] * scale : -INFINITY;
      sc[tr * 4 + j][tc + 16] = (kp1 <= qp) ? sv1[j] * scale : -INFINITY;
    }
    __syncthreads();
    if (t < 64) {
      float mo = mrow[t];
      float cm = mo;
      for (int k = 0; k < 32; ++k) cm = fmaxf(cm, sc[t][k]);
      float a = (cm == -INFINITY) ? 1.f : expf(mo - cm);
      float sum = 0.f;
      for (int k = 0; k < 32; ++k) {
        float v = sc[t][k];
        float p = (v == -INFINITY) ? 0.f : expf(v - cm);
        sc[t][k] = p; sum += p;
      }
      mrow[t] = cm; lrow[t] = lrow[t] * a + sum; arw[t] = a;
    }
    __syncthreads();
    #pragma unroll
    for (int j = 0; j < 4; ++j) {
      float a = arw[tr * 4 + j];
      #pragma unroll
      for (int i = 0; i < 8; ++i) acc[j][i] *= a;
    }
    for (int k = 0; k < 32; ++k) {
      float4 v0 = *(const float4*)(&vs[k][tc * 4]);
      float4 v1 = *(const float4*)(&vs[k][64 + tc * 4]);
      #pragma unroll
      for (int j = 0; j < 4; ++j) {
        float p = sc[tr * 4 + j][k];
        acc[j][0] += p*v0.x; acc[j][1] += p*v0.y; acc[j][2] += p*v0.z; acc[j][3] += p*v0.w;
        acc[j][4] += p*v1.x; acc[j][5] += p*v1.y; acc[j][6] += p*v1.z; acc[j][7] += p*v1.w;
      }
    }
    __syncthreads();
  }
  #pragma unroll
  for (int j = 0; j < 4; ++j) {
    int qi = tr * 4 + j;
    float inv = 1.f / lrow[qi];
    float4 o0, o1;
    o0.x = acc[j][0]*inv; o0.y = acc[j][1]*inv; o0.z = acc[j][2]*inv; o0.w = acc[j][3]*inv;
    o1.x = acc[j][4]*inv; o1.y = acc[j][5]*inv; o1.z = acc[j][6]*inv; o1.w = acc[j][7]*inv;
    *(float4*)(ctx + (size_t)(q0 + qi) * H_ + h * HD_ + tc * 4) = o0;
    *(float4*)(ctx + (size_t)(q0 + qi) * H_ + h * HD_ + 64 + tc * 4) = o1;
  }
}

// ---------------- cache scatter outputs ----------------
__global__ __launch_bounds__(256) void write_kv(
    const float* __restrict__ kcache, const float* __restrict__ vcache,
    const float* __restrict__ kb, const float* __restrict__ vb,
    const int* __restrict__ in_hs, const int* __restrict__ map_full,
    float* __restrict__ kc_o, float* __restrict__ vc_o)
{
  int gid = blockIdx.x * 256 + threadIdx.x;   // NH*S*HD/4
  int d4 = gid & 31;
  int s  = (gid >> 5) & (S_ - 1);
  int h  = gid >> 17;
  float4 kv, vv;
  if (in_hs[s]) {
    int i = map_full[s];
    size_t src = (size_t)i * (H_ / 4) + h * 32 + d4;
    kv = ((const float4*)kb)[src];
    vv = ((const float4*)vb)[src];
  } else {
    kv = ((const float4*)kcache)[gid];
    vv = ((const float4*)vcache)[gid];
  }
  ((float4*)kc_o)[gid] = kv;
  ((float4*)vc_o)[gid] = vv;
}

__global__ __launch_bounds__(256) void aux_write(
    const float* __restrict__ outb, const float* __restrict__ auxc,
    const int* __restrict__ pruned_bit, const int* __restrict__ aux_bit,
    const int* __restrict__ map_full, float* __restrict__ aux_o)
{
  int gid = blockIdx.x * 256 + threadIdx.x;   // S*H/4
  int c4 = gid & 511;
  int s  = gid >> 9;
  float4 v;
  if (pruned_bit[s] && !aux_bit[s])
    v = ((const float4*)outb)[(size_t)map_full[s] * 512 + c4];
  else
    v = ((const float4*)auxc)[gid];
  ((float4*)aux_o)[gid] = v;
}

// ---------------- host ----------------
extern "C" void kernel_launch(void* const* d_in, const int* in_sizes, int n_in,
                              void* d_out, int out_size, void* d_ws, size_t ws_size,
                              hipStream_t stream) {
  (void)in_sizes; (void)n_in; (void)out_size; (void)ws_size;
  const float* hidden  = (const float*)d_in[0];
  const float* kcache  = (const float*)d_in[1];
  const float* vcache  = (const float*)d_in[2];
  const float* auxc    = (const float*)d_in[3];
  const int* kv_idxs   = (const int*)d_in[4];
  const int* aux_idxs  = (const int*)d_in[5];
  const int* new_idxs  = (const int*)d_in[6];
  const int* positions = (const int*)d_in[7];
  const float* wq      = (const float*)d_in[8];
  const float* wk      = (const float*)d_in[9];
  const float* wv      = (const float*)d_in[10];
  const float* wo      = (const float*)d_in[11];
  const float* w_gate  = (const float*)d_in[12];
  const float* w_up    = (const float*)d_in[13];
  const float* w_down  = (const float*)d_in[14];
  const float* ln1     = (const float*)d_in[15];
  const float* ln2     = (const float*)d_in[16];

  float* out_o = (float*)d_out;
  float* kc_o  = out_o + (size_t)NQ_ * H_;
  float* vc_o  = kc_o + (size_t)NH_ * S_ * HD_;
  float* aux_o = vc_o + (size_t)NH_ * S_ * HD_;

  // workspace layout (units of M4 = 4M floats = 16.78 MB):
  //  0:hs 1:x(y) 2:qb 3:kb 4:vb 5-6:k_all 7-8:v_all 9:ctx 10:hs2  act=2-5  ints@11
  // weight-plane scratch (time-multiplexed into dead regions):
  //  QKV planes  -> slot 9   (ctx not written until flash_attn)
  //  wo planes   -> slot 6   (k_all dead after flash_attn)
  //  FFN planes  -> slots 6-9 (k_all/v_all/ctx all dead in FFN phase)
  float* W = (float*)d_ws;
  const size_t M4 = 4194304;                  // NQ*H
  float* hs    = W;
  float* x     = W + 1 * M4;                  // also y after attention
  float* qb    = W + 2 * M4;
  float* kb    = W + 3 * M4;
  float* vb    = W + 4 * M4;
  float* k_all = W + 5 * M4;                  // 2*M4
  float* v_all = W + 7 * M4;                  // 2*M4
  float* ctx   = W + 9 * M4;
  float* hs2   = W + 10 * M4;
  float* act   = W + 2 * M4;                  // 4*M4, alias qb..k_all (dead by FFN)
  ushort* bt9_h = (ushort*)(W + 9 * M4);               // H*H bf16 = 0.5*M4
  ushort* bt9_l = bt9_h + (size_t)H_ * H_;
  ushort* bt6_h = (ushort*)(W + 6 * M4);
  ushort* bt6_l = bt6_h + (size_t)H_ * H_;
  ushort* btg_h = (ushort*)(W + 6 * M4);               // H*FF bf16 = 2*M4
  ushort* btg_l = (ushort*)(W + 8 * M4);               // 2*M4
  int* ip = (int*)(W + 11 * M4);
  int* hs_idxs = ip;           ip += NQ_;
  int* q_pos   = ip;           ip += NQ_;
  int* key_tok = ip;           ip += NK_;
  int* k_pos   = ip;           ip += NK_;
  int* map_full= ip;           ip += S_;
  int* in_hs   = ip;           ip += S_;
  int* aux_bit = ip;           ip += S_;
  int* pruned  = ip;           ip += S_;
  int* last_hs = ip;           ip += 4;

  prep_build<<<16, 256, 0, stream>>>(kv_idxs, aux_idxs, new_idxs, positions,
      hs_idxs, q_pos, key_tok, k_pos, map_full, in_hs, aux_bit, pruned, last_hs);
  prep_scatter<<<10, 256, 0, stream>>>(hs_idxs, aux_idxs, map_full, in_hs, aux_bit);
  prune_set<<<2, 256, 0, stream>>>(kv_idxs, pruned);
  build_hs<<<4096, 256, 0, stream>>>(hidden, auxc, aux_idxs, hs);
  rmsnorm_k<<<NQ_, 256, 0, stream>>>(hs, ln1, x);

  const dim3 gTH(H_ / 64, H_ / 64);           // H x H weight transpose
  const dim3 gG(H_ / 128, NQ_ / 128);         // (16,16) M=NQ, N=H
  wsplit_t<<<gTH, 256, 0, stream>>>(wq, bt9_h, bt9_l, H_, H_);
  gemm_mfma<<<gG, 256, 0, stream>>>(x, bt9_h, bt9_l, qb, nullptr, NQ_, H_, H_, 0);
  wsplit_t<<<gTH, 256, 0, stream>>>(wk, bt9_h, bt9_l, H_, H_);
  gemm_mfma<<<gG, 256, 0, stream>>>(x, bt9_h, bt9_l, kb, nullptr, NQ_, H_, H_, 0);
  wsplit_t<<<gTH, 256, 0, stream>>>(wv, bt9_h, bt9_l, H_, H_);
  gemm_mfma<<<gG, 256, 0, stream>>>(x, bt9_h, bt9_l, vb, nullptr, NQ_, H_, H_, 0);

  rope_k<<<8192, 256, 0, stream>>>(qb, kb, q_pos);
  fill_kvall<<<8192, 256, 0, stream>>>(kcache, vcache, kb, vb, kv_idxs, k_all, v_all);

  flash_attn<<<dim3(32, 16), 256, 0, stream>>>(qb, k_all, v_all, q_pos, k_pos, ctx);
  write_kv<<<8192, 256, 0, stream>>>(kcache, vcache, kb, vb, in_hs, map_full, kc_o, vc_o);

  wsplit_t<<<gTH, 256, 0, stream>>>(wo, bt6_h, bt6_l, H_, H_);
  gemm_mfma<<<gG, 256, 0, stream>>>(ctx, bt6_h, bt6_l, hs2, hs, NQ_, H_, H_, 1);
  rmsnorm_k<<<NQ_, 256, 0, stream>>>(hs2, ln2, x);

  wsplit_t<<<dim3(FF_ / 64, H_ / 64), 256, 0, stream>>>(w_gate, btg_h, btg_l, H_, FF_);
  gemm_mfma<<<dim3(FF_ / 128, NQ_ / 128), 256, 0, stream>>>(x, btg_h, btg_l, act, nullptr, NQ_, FF_, H_, 0);
  wsplit_t<<<dim3(FF_ / 64, H_ / 64), 256, 0, stream>>>(w_up, btg_h, btg_l, H_, FF_);
  gemm_mfma<<<dim3(FF_ / 128, NQ_ / 128), 256, 0, stream>>>(x, btg_h, btg_l, act, act, NQ_, FF_, H_, 2);
  wsplit_t<<<dim3(H_ / 64, FF_ / 64), 256, 0, stream>>>(w_down, btg_h, btg_l, FF_, H_);
  gemm_mfma<<<gG, 256, 0, stream>>>(act, btg_h, btg_l, out_o, hs2, NQ_, H_, FF_, 1);

  aux_write<<<8192, 256, 0, stream>>>(out_o, auxc, pruned, aux_bit, map_full, aux_o);
}

// Round 2
// 2151.547 us; speedup vs baseline: 2.3675x; 1.3252x over previous
//
#include <hip/hip_runtime.h>
#include <math.h>

// ---------------- problem constants ----------------
constexpr int S_    = 4096;
constexpr int NKV   = 2048;
constexpr int NAUX  = 512;
constexpr int NNEW  = 1536;
constexpr int H_    = 2048;
constexpr int NH_   = 16;
constexpr int HD_   = 128;
constexpr int FF_   = 8192;
constexpr int NQ_   = 2048;   // NNEW + NAUX
constexpr int NK_   = 4096;   // NKV + NQ
constexpr int PRUNE = 409;
constexpr float EPSF = 1e-6f;

typedef __attribute__((ext_vector_type(8))) short bf16x8;
typedef __attribute__((ext_vector_type(16))) float f32x16;

__device__ __forceinline__ ushort f2bf(float x) {
  union { float f; unsigned u; } a; a.f = x;
  unsigned r = a.u + 0x7fffu + ((a.u >> 16) & 1u);
  return (ushort)(r >> 16);
}
__device__ __forceinline__ float bf2f(ushort h) {
  union { unsigned u; float f; } a; a.u = ((unsigned)h) << 16;
  return a.f;
}
__device__ __forceinline__ unsigned cvt_pk_bf16(float a, float b) {
  unsigned r;
  asm("v_cvt_pk_bf16_f32 %0, %1, %2" : "=v"(r) : "v"(a), "v"(b));
  return r;
}
__device__ __forceinline__ float bflo(unsigned w) { union { unsigned u; float f; } x; x.u = w << 16; return x.f; }
__device__ __forceinline__ float bfhi(unsigned w) { union { unsigned u; float f; } x; x.u = w & 0xffff0000u; return x.f; }

// ---------------- index prep ----------------
__global__ __launch_bounds__(256) void prep_build(
    const int* __restrict__ kv_idxs, const int* __restrict__ aux_idxs,
    const int* __restrict__ new_idxs, const int* __restrict__ positions,
    int* hs_idxs, int* q_pos, int* key_tok, int* k_pos,
    int* map_full, int* in_hs, int* aux_bit, int* pruned_bit, int* last_hs)
{
  int t = blockIdx.x * 256 + threadIdx.x;     // grid covers 4096
  if (t < S_) { map_full[t] = 0; in_hs[t] = 0; aux_bit[t] = 0; pruned_bit[t] = 0; }
  if (t < NQ_) {
    int tok = (t < NNEW) ? new_idxs[t] : aux_idxs[t - NNEW];
    hs_idxs[t] = tok;
    q_pos[t] = positions[tok];
  }
  if (t < NK_) {
    int tok;
    if (t < NKV) tok = kv_idxs[t];
    else { int i = t - NKV; tok = (i < NNEW) ? new_idxs[i] : aux_idxs[i - NNEW]; }
    key_tok[t] = tok;
    k_pos[t] = positions[tok];
  }
  if (t < NNEW && new_idxs[t] == S_ - 1) last_hs[0] = t;
}

__global__ __launch_bounds__(256) void prep_scatter(
    const int* __restrict__ hs_idxs, const int* __restrict__ aux_idxs,
    int* map_full, int* in_hs, int* aux_bit)
{
  int t = blockIdx.x * 256 + threadIdx.x;
  if (t < NQ_) { int tok = hs_idxs[t]; map_full[tok] = t; in_hs[tok] = 1; }
  else if (t < NQ_ + NAUX) { aux_bit[aux_idxs[t - NQ_]] = 1; }
}

// Prune semantics of the reference (bug-compatible): see previous session note.
__global__ __launch_bounds__(256) void prune_set(
    const int* __restrict__ kv_idxs, int* __restrict__ pruned_bit)
{
  int t = blockIdx.x * 256 + threadIdx.x;
  if (t < PRUNE - 1) pruned_bit[kv_idxs[t]] = 1;
  if (t == PRUNE - 1) pruned_bit[S_ - 1] = 1;
}

// ---------------- hs = concat(hidden_states, aux_cache[aux_idxs]) ----------------
__global__ __launch_bounds__(256) void build_hs(
    const float* __restrict__ hidden, const float* __restrict__ auxc,
    const int* __restrict__ aux_idxs, float* __restrict__ hs)
{
  int gid = blockIdx.x * 256 + threadIdx.x;   // NQ*H/4 float4
  int c4 = gid & 511;                          // H/4 = 512
  int i  = gid >> 9;
  const float4* src;
  if (i < NNEW) src = (const float4*)hidden + (size_t)i * 512 + c4;
  else          src = (const float4*)auxc + (size_t)aux_idxs[i - NNEW] * 512 + c4;
  ((float4*)hs)[gid] = *src;
}

// ---------------- rmsnorm ----------------
__global__ __launch_bounds__(256) void rmsnorm_k(
    const float* __restrict__ in, const float* __restrict__ w, float* __restrict__ out)
{
  int row = blockIdx.x, t = threadIdx.x;
  const float4* r4 = (const float4*)(in + (size_t)row * H_);
  const float4* w4 = (const float4*)w;
  float ss = 0.f;
  float4 v0 = r4[t], v1 = r4[t + 256];
  ss += v0.x*v0.x + v0.y*v0.y + v0.z*v0.z + v0.w*v0.w;
  ss += v1.x*v1.x + v1.y*v1.y + v1.z*v1.z + v1.w*v1.w;
  __shared__ float red[256];
  red[t] = ss; __syncthreads();
  for (int s = 128; s > 0; s >>= 1) { if (t < s) red[t] += red[t + s]; __syncthreads(); }
  float inv = rsqrtf(red[0] / (float)H_ + EPSF);
  float4* o4 = (float4*)(out + (size_t)row * H_);
  float4 wv0 = w4[t], wv1 = w4[t + 256];
  float4 r0, r1;
  r0.x = v0.x*inv*wv0.x; r0.y = v0.y*inv*wv0.y; r0.z = v0.z*inv*wv0.z; r0.w = v0.w*inv*wv0.w;
  r1.x = v1.x*inv*wv1.x; r1.y = v1.y*inv*wv1.y; r1.z = v1.z*inv*wv1.z; r1.w = v1.w*inv*wv1.w;
  o4[t] = r0; o4[t + 256] = r1;
}

// ---------------- weight transpose + bf16 hi/lo split ----------------
// W[K][N] f32 -> Th/Tl [N][K] bf16 planes.  grid = (N/64, K/64)
__global__ __launch_bounds__(256) void wsplit_t(
    const float* __restrict__ Wsrc, ushort* __restrict__ Th, ushort* __restrict__ Tl,
    int K, int N)
{
  __shared__ float tile[64][65];
  const int bn = blockIdx.x * 64, bk = blockIdx.y * 64;
  const int t = threadIdx.x;
  #pragma unroll
  for (int r = 0; r < 4; ++r) {
    int idx = t + 256 * r;
    int row = idx >> 4, c = (idx & 15) * 4;
    float4 v = *(const float4*)(Wsrc + (size_t)(bk + row) * N + bn + c);
    tile[row][c] = v.x; tile[row][c+1] = v.y; tile[row][c+2] = v.z; tile[row][c+3] = v.w;
  }
  __syncthreads();
  #pragma unroll
  for (int r = 0; r < 4; ++r) {
    int idx = t + 256 * r;
    int n = idx >> 4, k = (idx & 15) * 4;
    float v0 = tile[k][n], v1 = tile[k+1][n], v2 = tile[k+2][n], v3 = tile[k+3][n];
    ushort4 h, l;
    h.x = f2bf(v0); l.x = f2bf(v0 - bf2f(h.x));
    h.y = f2bf(v1); l.y = f2bf(v1 - bf2f(h.y));
    h.z = f2bf(v2); l.z = f2bf(v2 - bf2f(h.z));
    h.w = f2bf(v3); l.w = f2bf(v3 - bf2f(h.w));
    size_t off = (size_t)(bn + n) * K + bk + k;
    *(ushort4*)(Th + off) = h;
    *(ushort4*)(Tl + off) = l;
  }
}

// ---------------- bf16x3 MFMA GEMM: C[M,N] = A[M,K] @ B[K,N] (+epilogue) ----------------
__global__ __launch_bounds__(256) void gemm_mfma(
    const float* __restrict__ A, const ushort* __restrict__ Bh,
    const ushort* __restrict__ Bl, float* __restrict__ C,
    const float* __restrict__ X, int M, int N, int K, int epi)
{
  __shared__ ushort As_h[128][40];
  __shared__ ushort As_l[128][40];
  __shared__ ushort Bs_h[128][40];
  __shared__ ushort Bs_l[128][40];
  const int bm = blockIdx.y * 128, bn = blockIdx.x * 128;
  const int t = threadIdx.x;
  const int lane = t & 63;
  const int wid = t >> 6;
  const int wr = wid >> 1, wc = wid & 1;
  const int fr = lane & 31;
  const int kg = lane >> 5;

  f32x16 acc[2][2];
  #pragma unroll
  for (int mi = 0; mi < 2; ++mi)
    #pragma unroll
    for (int ni = 0; ni < 2; ++ni)
      #pragma unroll
      for (int r = 0; r < 16; ++r) acc[mi][ni][r] = 0.f;

  for (int k0 = 0; k0 < K; k0 += 32) {
    #pragma unroll
    for (int r = 0; r < 4; ++r) {
      int idx = t + 256 * r;
      int row = idx >> 3, c = (idx & 7) * 4;
      float4 v = *(const float4*)(A + (size_t)(bm + row) * K + k0 + c);
      ushort4 h, l;
      h.x = f2bf(v.x); l.x = f2bf(v.x - bf2f(h.x));
      h.y = f2bf(v.y); l.y = f2bf(v.y - bf2f(h.y));
      h.z = f2bf(v.z); l.z = f2bf(v.z - bf2f(h.z));
      h.w = f2bf(v.w); l.w = f2bf(v.w - bf2f(h.w));
      *(ushort4*)(&As_h[row][c]) = h;
      *(ushort4*)(&As_l[row][c]) = l;
    }
    #pragma unroll
    for (int r = 0; r < 4; ++r) {
      int idx = t + 256 * r;
      int n = idx >> 3, c = (idx & 7) * 4;
      size_t off = (size_t)(bn + n) * K + k0 + c;
      *(ushort4*)(&Bs_h[n][c]) = *(const ushort4*)(Bh + off);
      *(ushort4*)(&Bs_l[n][c]) = *(const ushort4*)(Bl + off);
    }
    __syncthreads();
    #pragma unroll
    for (int ks = 0; ks < 2; ++ks) {
      const int ko = ks * 16 + kg * 8;
      bf16x8 ah[2], al[2], bh[2], bl[2];
      #pragma unroll
      for (int mi = 0; mi < 2; ++mi) {
        ah[mi] = *(const bf16x8*)(&As_h[wr * 64 + mi * 32 + fr][ko]);
        al[mi] = *(const bf16x8*)(&As_l[wr * 64 + mi * 32 + fr][ko]);
        bh[mi] = *(const bf16x8*)(&Bs_h[wc * 64 + mi * 32 + fr][ko]);
        bl[mi] = *(const bf16x8*)(&Bs_l[wc * 64 + mi * 32 + fr][ko]);
      }
      #pragma unroll
      for (int mi = 0; mi < 2; ++mi)
        #pragma unroll
        for (int ni = 0; ni < 2; ++ni) {
          acc[mi][ni] = __builtin_amdgcn_mfma_f32_32x32x16_bf16(ah[mi], bh[ni], acc[mi][ni], 0, 0, 0);
          acc[mi][ni] = __builtin_amdgcn_mfma_f32_32x32x16_bf16(ah[mi], bl[ni], acc[mi][ni], 0, 0, 0);
          acc[mi][ni] = __builtin_amdgcn_mfma_f32_32x32x16_bf16(al[mi], bh[ni], acc[mi][ni], 0, 0, 0);
        }
    }
    __syncthreads();
  }
  #pragma unroll
  for (int mi = 0; mi < 2; ++mi) {
    #pragma unroll
    for (int ni = 0; ni < 2; ++ni) {
      #pragma unroll
      for (int r = 0; r < 16; ++r) {
        int row = bm + wr * 64 + mi * 32 + (r & 3) + 8 * (r >> 2) + 4 * kg;
        int col = bn + wc * 64 + ni * 32 + fr;
        size_t idx = (size_t)row * N + col;
        float v = acc[mi][ni][r];
        if (epi == 1) v += X[idx];
        else if (epi == 2) { float g = X[idx]; v = (g / (1.f + expf(-g))) * v; }
        C[idx] = v;
      }
    }
  }
}

// ---------------- RoPE in-place on q and k ----------------
__global__ __launch_bounds__(256) void rope_k(
    float* __restrict__ qb, float* __restrict__ kb, const int* __restrict__ q_pos)
{
  int gid = blockIdx.x * 256 + threadIdx.x;   // NQ*NH*64
  int d = gid & 63;
  int h = (gid >> 6) & 15;
  int i = gid >> 10;
  int p = q_pos[i];
  double ang = (double)p * exp((double)d * -0.14391156831212787);
  float c = (float)cos(ang), s = (float)sin(ang);
  size_t ia = (size_t)i * H_ + h * HD_ + d;
  size_t ib = ia + 64;
  float qa = qb[ia], qbv = qb[ib];
  qb[ia] = qa * c - qbv * s;
  qb[ib] = qbv * c + qa * s;
  float ka = kb[ia], kbv = kb[ib];
  kb[ia] = ka * c - kbv * s;
  kb[ib] = kbv * c + ka * s;
}

// ---------------- K/V -> bf16 hi/lo planes (V transposed) ----------------
// kh/kl: [NH][NK][HD]; vth/vtl: [NH][HD][NK].  grid = (NK/64, NH)
__global__ __launch_bounds__(256) void fill_kv_planes(
    const float* __restrict__ kcache, const float* __restrict__ vcache,
    const float* __restrict__ kb, const float* __restrict__ vb,
    const int* __restrict__ kv_idxs,
    ushort* __restrict__ kh, ushort* __restrict__ kl,
    ushort* __restrict__ vth, ushort* __restrict__ vtl)
{
  __shared__ float vt[64][133];
  const int h = blockIdx.y;
  const int kbase = blockIdx.x * 64;
  const int t = threadIdx.x;
  #pragma unroll
  for (int r = 0; r < 8; ++r) {
    int idx = t + 256 * r;                     // 2048 float4
    int key = idx >> 5, d4 = idx & 31;
    int j = kbase + key;
    float4 kv, vv;
    if (j < NKV) {
      int tok = kv_idxs[j];
      size_t src = ((size_t)h * S_ + tok) * 32 + d4;
      kv = ((const float4*)kcache)[src];
      vv = ((const float4*)vcache)[src];
    } else {
      int i = j - NKV;
      size_t src = (size_t)i * 512 + h * 32 + d4;
      kv = ((const float4*)kb)[src];
      vv = ((const float4*)vb)[src];
    }
    ushort4 hh, ll;
    hh.x = f2bf(kv.x); ll.x = f2bf(kv.x - bf2f(hh.x));
    hh.y = f2bf(kv.y); ll.y = f2bf(kv.y - bf2f(hh.y));
    hh.z = f2bf(kv.z); ll.z = f2bf(kv.z - bf2f(hh.z));
    hh.w = f2bf(kv.w); ll.w = f2bf(kv.w - bf2f(hh.w));
    size_t dst = ((size_t)(h * NK_ + j)) * 128 + d4 * 4;
    *(ushort4*)(kh + dst) = hh;
    *(ushort4*)(kl + dst) = ll;
    vt[key][d4 * 4 + 0] = vv.x; vt[key][d4 * 4 + 1] = vv.y;
    vt[key][d4 * 4 + 2] = vv.z; vt[key][d4 * 4 + 3] = vv.w;
  }
  __syncthreads();
  #pragma unroll
  for (int r = 0; r < 8; ++r) {
    int idx = t + 256 * r;                     // 2048 groups of 4 keys
    int d = idx >> 4, kq = (idx & 15) * 4;
    float v0 = vt[kq + 0][d], v1 = vt[kq + 1][d], v2 = vt[kq + 2][d], v3 = vt[kq + 3][d];
    ushort4 hh, ll;
    hh.x = f2bf(v0); ll.x = f2bf(v0 - bf2f(hh.x));
    hh.y = f2bf(v1); ll.y = f2bf(v1 - bf2f(hh.y));
    hh.z = f2bf(v2); ll.z = f2bf(v2 - bf2f(hh.z));
    hh.w = f2bf(v3); ll.w = f2bf(v3 - bf2f(hh.w));
    size_t dst = ((size_t)(h * 128 + d)) * NK_ + kbase + kq;
    *(ushort4*)(vth + dst) = hh;
    *(ushort4*)(vtl + dst) = ll;
  }
}

// ---------------- MFMA flash attention ----------------
// Block: 64 queries x 1 head, 4 waves = 2(q-half) x 2(key-parity of 64-key superstep).
// Swapped QK^T: S^T = mfma(K, Q) so q = lane column -> softmax is lane-local.
// hi/lo bf16 split (3-product) for QK and PV, f32 accumulate.
union FlashLDS {
  struct { ushort K[2][64][136]; ushort V[2][128][72]; int kps[64]; } s;
  struct { float acc[2][32][128]; float ml[2][2][32]; } m;
};

__global__ __launch_bounds__(256, 2) void flash_mfma(
    const float* __restrict__ qb, const ushort* __restrict__ khg,
    const ushort* __restrict__ klg, const ushort* __restrict__ vthg,
    const ushort* __restrict__ vtlg, const int* __restrict__ q_pos,
    const int* __restrict__ k_pos, float* __restrict__ ctx)
{
  __shared__ FlashLDS U;
  const int h = blockIdx.y;
  const int q0 = blockIdx.x * 64;
  const int t = threadIdx.x;
  const int w = t >> 6, lane = t & 63;
  const int wq = w & 1, wk = w >> 1;
  const int kg = lane >> 5;
  const int qc = lane & 31;
  const int qi = q0 + wq * 32 + qc;
  const float scale = 0.08838834764831844f;    // 1/sqrt(128)

  // Q fragments, scale folded in, hi/lo split. 8 k-slices of 16 dims.
  bf16x8 qh[8], ql[8];
  {
    const float4* q4 = (const float4*)qb;
    #pragma unroll
    for (int s = 0; s < 8; ++s) {
      size_t a = (size_t)qi * 512 + h * 32 + s * 4 + kg * 2;
      float4 f0 = q4[a], f1 = q4[a + 1];
      float f[8] = {f0.x, f0.y, f0.z, f0.w, f1.x, f1.y, f1.z, f1.w};
      union { ushort u[8]; bf16x8 v; } Hq, Lq;
      #pragma unroll
      for (int j = 0; j < 8; ++j) {
        float qs = f[j] * scale;
        ushort hh = f2bf(qs);
        Hq.u[j] = hh; Lq.u[j] = f2bf(qs - bf2f(hh));
      }
      qh[s] = Hq.v; ql[s] = Lq.v;
    }
  }
  const int qp = q_pos[qi];
  const int wave_qmin = __shfl(qp, 0);
  const int wave_qmax = __shfl(qp, 31);
  const int bqmax = q_pos[q0 + 63];

  f32x16 acc[4];
  #pragma unroll
  for (int f = 0; f < 4; ++f)
    #pragma unroll
    for (int r = 0; r < 16; ++r) acc[f][r] = 0.f;
  float m_run = -INFINITY, l_run = 0.f;

  for (int kt = 0; kt < NK_ / 64; ++kt) {
    const int kbase = kt * 64;
    if (k_pos[kbase] > bqmax) continue;        // block-uniform causal skip
    // ---- stage K (2 planes) ----
    #pragma unroll
    for (int r = 0; r < 8; ++r) {
      int idx = t + 256 * r;                   // 2048 uint4
      int p = idx >> 10, rem = idx & 1023;
      int key = rem >> 4, c8 = (rem & 15) * 8;
      const ushort* src = (p ? klg : khg) + ((size_t)(h * NK_ + kbase + key) * 128 + c8);
      *(uint4*)(&U.s.K[p][key][c8]) = *(const uint4*)src;
    }
    // ---- stage V^T (2 planes) ----
    #pragma unroll
    for (int r = 0; r < 8; ++r) {
      int idx = t + 256 * r;                   // 2048 uint4
      int p = idx >> 10, rem = idx & 1023;
      int d = rem >> 3, c8 = (rem & 7) * 8;
      const ushort* src = (p ? vtlg : vthg) + ((size_t)(h * 128 + d) * NK_ + kbase + c8);
      *(uint4*)(&U.s.V[p][d][c8]) = *(const uint4*)src;
    }
    if (t < 64) U.s.kps[t] = k_pos[kbase + t];
    __syncthreads();

    const int kpmin_half = U.s.kps[wk * 32];
    if (kpmin_half <= wave_qmax) {
      const bool needmask = (U.s.kps[wk * 32 + 31] > wave_qmin);
      // ---- QK^T (swapped): S^T = K . Q ----
      f32x16 sA, sB;
      #pragma unroll
      for (int r = 0; r < 16; ++r) { sA[r] = 0.f; sB[r] = 0.f; }
      __builtin_amdgcn_s_setprio(1);
      #pragma unroll
      for (int s = 0; s < 8; ++s) {
        const int co = s * 16 + kg * 8;
        bf16x8 khf = *(const bf16x8*)(&U.s.K[0][wk * 32 + qc][co]);
        bf16x8 klf = *(const bf16x8*)(&U.s.K[1][wk * 32 + qc][co]);
        sA = __builtin_amdgcn_mfma_f32_32x32x16_bf16(khf, qh[s], sA, 0, 0, 0);
        sB = __builtin_amdgcn_mfma_f32_32x32x16_bf16(khf, ql[s], sB, 0, 0, 0);
        sB = __builtin_amdgcn_mfma_f32_32x32x16_bf16(klf, qh[s], sB, 0, 0, 0);
      }
      __builtin_amdgcn_s_setprio(0);
      float sc[16];
      #pragma unroll
      for (int r = 0; r < 16; ++r) sc[r] = sA[r] + sB[r];
      if (needmask) {
        #pragma unroll
        for (int r = 0; r < 16; ++r) {
          int kloc = wk * 32 + (r & 3) + 8 * (r >> 2) + 4 * kg;
          sc[r] = (U.s.kps[kloc] <= qp) ? sc[r] : -INFINITY;
        }
      }
      // ---- lane-local online softmax (q = lane column) ----
      float mloc = sc[0];
      #pragma unroll
      for (int r = 1; r < 16; ++r) mloc = fmaxf(mloc, sc[r]);
      mloc = fmaxf(mloc, __shfl_xor(mloc, 32));
      float m_new = fmaxf(m_run, mloc);
      float mexp = (m_new == -INFINITY) ? 0.f : m_new;
      if (__any(m_new > m_run)) {
        float aa = __expf(m_run - mexp);
        l_run *= aa;
        #pragma unroll
        for (int f = 0; f < 4; ++f)
          #pragma unroll
          for (int r = 0; r < 16; ++r) acc[f][r] *= aa;
      }
      m_run = m_new;
      float p[16]; float psum = 0.f;
      #pragma unroll
      for (int r = 0; r < 16; ++r) { p[r] = __expf(sc[r] - mexp); psum += p[r]; }
      psum += __shfl_xor(psum, 32);
      l_run += psum;
      // ---- pack P -> bf16 hi/lo B-fragments (cvt_pk + shfl_xor(32)) ----
      bf16x8 pfh[2], pfl[2];
      #pragma unroll
      for (int sl = 0; sl < 2; ++sl) {
        const float* pp = p + sl * 8;
        unsigned a0 = cvt_pk_bf16(pp[0], pp[1]);
        unsigned a1 = cvt_pk_bf16(pp[2], pp[3]);
        unsigned b0 = cvt_pk_bf16(pp[4], pp[5]);
        unsigned b1 = cvt_pk_bf16(pp[6], pp[7]);
        unsigned a0x = (unsigned)__shfl_xor((int)a0, 32);
        unsigned a1x = (unsigned)__shfl_xor((int)a1, 32);
        unsigned b0x = (unsigned)__shfl_xor((int)b0, 32);
        unsigned b1x = (unsigned)__shfl_xor((int)b1, 32);
        union { unsigned wd[4]; bf16x8 v; } PH, PL;
        PH.wd[0] = kg ? b0x : a0;
        PH.wd[1] = kg ? b1x : a1;
        PH.wd[2] = kg ? b0 : a0x;
        PH.wd[3] = kg ? b1 : a1x;
        float r0 = pp[0] - bflo(a0), r1 = pp[1] - bfhi(a0);
        float r2 = pp[2] - bflo(a1), r3 = pp[3] - bfhi(a1);
        float r4 = pp[4] - bflo(b0), r5 = pp[5] - bfhi(b0);
        float r6 = pp[6] - bflo(b1), r7 = pp[7] - bfhi(b1);
        unsigned c0 = cvt_pk_bf16(r0, r1);
        unsigned c1 = cvt_pk_bf16(r2, r3);
        unsigned d0 = cvt_pk_bf16(r4, r5);
        unsigned d1 = cvt_pk_bf16(r6, r7);
        unsigned c0x = (unsigned)__shfl_xor((int)c0, 32);
        unsigned c1x = (unsigned)__shfl_xor((int)c1, 32);
        unsigned d0x = (unsigned)__shfl_xor((int)d0, 32);
        unsigned d1x = (unsigned)__shfl_xor((int)d1, 32);
        PL.wd[0] = kg ? d0x : c0;
        PL.wd[1] = kg ? d1x : c1;
        PL.wd[2] = kg ? d0 : c0x;
        PL.wd[3] = kg ? d1 : c1x;
        pfh[sl] = PH.v; pfl[sl] = PL.v;
      }
      // ---- PV: ctx^T += V^T . P^T ----
      __builtin_amdgcn_s_setprio(1);
      #pragma unroll
      for (int ks = 0; ks < 2; ++ks) {
        const int kc = wk * 32 + ks * 16 + kg * 8;
        bf16x8 vh0 = *(const bf16x8*)(&U.s.V[0][0 * 32 + qc][kc]);
        bf16x8 vh1 = *(const bf16x8*)(&U.s.V[0][1 * 32 + qc][kc]);
        bf16x8 vh2 = *(const bf16x8*)(&U.s.V[0][2 * 32 + qc][kc]);
        bf16x8 vh3 = *(const bf16x8*)(&U.s.V[0][3 * 32 + qc][kc]);
        bf16x8 vl0 = *(const bf16x8*)(&U.s.V[1][0 * 32 + qc][kc]);
        bf16x8 vl1 = *(const bf16x8*)(&U.s.V[1][1 * 32 + qc][kc]);
        bf16x8 vl2 = *(const bf16x8*)(&U.s.V[1][2 * 32 + qc][kc]);
        bf16x8 vl3 = *(const bf16x8*)(&U.s.V[1][3 * 32 + qc][kc]);
        acc[0] = __builtin_amdgcn_mfma_f32_32x32x16_bf16(vh0, pfh[ks], acc[0], 0, 0, 0);
        acc[1] = __builtin_amdgcn_mfma_f32_32x32x16_bf16(vh1, pfh[ks], acc[1], 0, 0, 0);
        acc[2] = __builtin_amdgcn_mfma_f32_32x32x16_bf16(vh2, pfh[ks], acc[2], 0, 0, 0);
        acc[3] = __builtin_amdgcn_mfma_f32_32x32x16_bf16(vh3, pfh[ks], acc[3], 0, 0, 0);
        acc[0] = __builtin_amdgcn_mfma_f32_32x32x16_bf16(vl0, pfh[ks], acc[0], 0, 0, 0);
        acc[1] = __builtin_amdgcn_mfma_f32_32x32x16_bf16(vl1, pfh[ks], acc[1], 0, 0, 0);
        acc[2] = __builtin_amdgcn_mfma_f32_32x32x16_bf16(vl2, pfh[ks], acc[2], 0, 0, 0);
        acc[3] = __builtin_amdgcn_mfma_f32_32x32x16_bf16(vl3, pfh[ks], acc[3], 0, 0, 0);
        acc[0] = __builtin_amdgcn_mfma_f32_32x32x16_bf16(vh0, pfl[ks], acc[0], 0, 0, 0);
        acc[1] = __builtin_amdgcn_mfma_f32_32x32x16_bf16(vh1, pfl[ks], acc[1], 0, 0, 0);
        acc[2] = __builtin_amdgcn_mfma_f32_32x32x16_bf16(vh2, pfl[ks], acc[2], 0, 0, 0);
        acc[3] = __builtin_amdgcn_mfma_f32_32x32x16_bf16(vh3, pfl[ks], acc[3], 0, 0, 0);
      }
      __builtin_amdgcn_s_setprio(0);
    }
    __syncthreads();
  }

  // ---- merge key-parity halves (wk=1 publishes, wk=0 combines) ----
  if (wk == 1) {
    #pragma unroll
    for (int f = 0; f < 4; ++f)
      #pragma unroll
      for (int rq = 0; rq < 4; ++rq) {
        float4 v;
        v.x = acc[f][rq * 4 + 0]; v.y = acc[f][rq * 4 + 1];
        v.z = acc[f][rq * 4 + 2]; v.w = acc[f][rq * 4 + 3];
        *(float4*)(&U.m.acc[wq][qc][f * 32 + kg * 4 + rq * 8]) = v;
      }
    if (kg == 0) { U.m.ml[wq][0][qc] = m_run; U.m.ml[wq][1][qc] = l_run; }
  }
  __syncthreads();
  if (wk == 0) {
    float m2 = U.m.ml[wq][0][qc];
    float l2 = U.m.ml[wq][1][qc];
    float mm = fmaxf(m_run, m2);
    float a1 = __expf(m_run - mm);
    float a2 = __expf(m2 - mm);
    float inv = 1.f / (l_run * a1 + l2 * a2);
    #pragma unroll
    for (int f = 0; f < 4; ++f)
      #pragma unroll
      for (int rq = 0; rq < 4; ++rq) {
        float4 oth = *(const float4*)(&U.m.acc[wq][qc][f * 32 + kg * 4 + rq * 8]);
        float4 o;
        o.x = (acc[f][rq * 4 + 0] * a1 + oth.x * a2) * inv;
        o.y = (acc[f][rq * 4 + 1] * a1 + oth.y * a2) * inv;
        o.z = (acc[f][rq * 4 + 2] * a1 + oth.z * a2) * inv;
        o.w = (acc[f][rq * 4 + 3] * a1 + oth.w * a2) * inv;
        *(float4*)(ctx + (size_t)qi * H_ + h * 128 + f * 32 + kg * 4 + rq * 8) = o;
      }
  }
}

// ---------------- cache scatter outputs ----------------
__global__ __launch_bounds__(256) void write_kv(
    const float* __restrict__ kcache, const float* __restrict__ vcache,
    const float* __restrict__ kb, const float* __restrict__ vb,
    const int* __restrict__ in_hs, const int* __restrict__ map_full,
    float* __restrict__ kc_o, float* __restrict__ vc_o)
{
  int gid = blockIdx.x * 256 + threadIdx.x;   // NH*S*HD/4
  int d4 = gid & 31;
  int s  = (gid >> 5) & (S_ - 1);
  int h  = gid >> 17;
  float4 kv, vv;
  if (in_hs[s]) {
    int i = map_full[s];
    size_t src = (size_t)i * (H_ / 4) + h * 32 + d4;
    kv = ((const float4*)kb)[src];
    vv = ((const float4*)vb)[src];
  } else {
    kv = ((const float4*)kcache)[gid];
    vv = ((const float4*)vcache)[gid];
  }
  ((float4*)kc_o)[gid] = kv;
  ((float4*)vc_o)[gid] = vv;
}

__global__ __launch_bounds__(256) void aux_write(
    const float* __restrict__ outb, const float* __restrict__ auxc,
    const int* __restrict__ pruned_bit, const int* __restrict__ aux_bit,
    const int* __restrict__ map_full, float* __restrict__ aux_o)
{
  int gid = blockIdx.x * 256 + threadIdx.x;   // S*H/4
  int c4 = gid & 511;
  int s  = gid >> 9;
  float4 v;
  if (pruned_bit[s] && !aux_bit[s])
    v = ((const float4*)outb)[(size_t)map_full[s] * 512 + c4];
  else
    v = ((const float4*)auxc)[gid];
  ((float4*)aux_o)[gid] = v;
}

// ---------------- host ----------------
extern "C" void kernel_launch(void* const* d_in, const int* in_sizes, int n_in,
                              void* d_out, int out_size, void* d_ws, size_t ws_size,
                              hipStream_t stream) {
  (void)in_sizes; (void)n_in; (void)out_size; (void)ws_size;
  const float* hidden  = (const float*)d_in[0];
  const float* kcache  = (const float*)d_in[1];
  const float* vcache  = (const float*)d_in[2];
  const float* auxc    = (const float*)d_in[3];
  const int* kv_idxs   = (const int*)d_in[4];
  const int* aux_idxs  = (const int*)d_in[5];
  const int* new_idxs  = (const int*)d_in[6];
  const int* positions = (const int*)d_in[7];
  const float* wq      = (const float*)d_in[8];
  const float* wk      = (const float*)d_in[9];
  const float* wv      = (const float*)d_in[10];
  const float* wo      = (const float*)d_in[11];
  const float* w_gate  = (const float*)d_in[12];
  const float* w_up    = (const float*)d_in[13];
  const float* w_down  = (const float*)d_in[14];
  const float* ln1     = (const float*)d_in[15];
  const float* ln2     = (const float*)d_in[16];

  float* out_o = (float*)d_out;
  float* kc_o  = out_o + (size_t)NQ_ * H_;
  float* vc_o  = kc_o + (size_t)NH_ * S_ * HD_;
  float* aux_o = vc_o + (size_t)NH_ * S_ * HD_;

  // workspace layout (units of M4 = 4M floats = 16.78 MB):
  //  0:hs 1:x(y) 2:qb 3:kb 4:vb 5:kh 6:kl 7:vth 8:vtl 9:ctx 10:hs2  act=2-5  ints@11
  //  QKV weight planes -> slot 9 (ctx written only by flash, after QKV gemms)
  //  wo planes -> slot 6 (kl dead after flash)  FFN planes -> slots 6-9
  float* W = (float*)d_ws;
  const size_t M4 = 4194304;                  // NQ*H
  float* hs    = W;
  float* x     = W + 1 * M4;                  // also y after attention
  float* qb    = W + 2 * M4;
  float* kb    = W + 3 * M4;
  float* vb    = W + 4 * M4;
  ushort* khp  = (ushort*)(W + 5 * M4);       // NH*NK*HD bf16 = 1 slot each
  ushort* klp  = (ushort*)(W + 6 * M4);
  ushort* vthp = (ushort*)(W + 7 * M4);
  ushort* vtlp = (ushort*)(W + 8 * M4);
  float* ctx   = W + 9 * M4;
  float* hs2   = W + 10 * M4;
  float* act   = W + 2 * M4;                  // 4*M4, alias qb..khp (dead by FFN)
  ushort* bt9_h = (ushort*)(W + 9 * M4);      // H*H bf16 planes (QKV phase)
  ushort* bt9_l = bt9_h + (size_t)H_ * H_;
  ushort* bt6_h = (ushort*)(W + 6 * M4);
  ushort* bt6_l = bt6_h + (size_t)H_ * H_;
  ushort* btg_h = (ushort*)(W + 6 * M4);      // H*FF bf16 = 2 slots
  ushort* btg_l = (ushort*)(W + 8 * M4);      // 2 slots
  int* ip = (int*)(W + 11 * M4);
  int* hs_idxs = ip;           ip += NQ_;
  int* q_pos   = ip;           ip += NQ_;
  int* key_tok = ip;           ip += NK_;
  int* k_pos   = ip;           ip += NK_;
  int* map_full= ip;           ip += S_;
  int* in_hs   = ip;           ip += S_;
  int* aux_bit = ip;           ip += S_;
  int* pruned  = ip;           ip += S_;
  int* last_hs = ip;           ip += 4;

  prep_build<<<16, 256, 0, stream>>>(kv_idxs, aux_idxs, new_idxs, positions,
      hs_idxs, q_pos, key_tok, k_pos, map_full, in_hs, aux_bit, pruned, last_hs);
  prep_scatter<<<10, 256, 0, stream>>>(hs_idxs, aux_idxs, map_full, in_hs, aux_bit);
  prune_set<<<2, 256, 0, stream>>>(kv_idxs, pruned);
  build_hs<<<4096, 256, 0, stream>>>(hidden, auxc, aux_idxs, hs);
  rmsnorm_k<<<NQ_, 256, 0, stream>>>(hs, ln1, x);

  const dim3 gTH(H_ / 64, H_ / 64);
  const dim3 gG(H_ / 128, NQ_ / 128);
  wsplit_t<<<gTH, 256, 0, stream>>>(wq, bt9_h, bt9_l, H_, H_);
  gemm_mfma<<<gG, 256, 0, stream>>>(x, bt9_h, bt9_l, qb, nullptr, NQ_, H_, H_, 0);
  wsplit_t<<<gTH, 256, 0, stream>>>(wk, bt9_h, bt9_l, H_, H_);
  gemm_mfma<<<gG, 256, 0, stream>>>(x, bt9_h, bt9_l, kb, nullptr, NQ_, H_, H_, 0);
  wsplit_t<<<gTH, 256, 0, stream>>>(wv, bt9_h, bt9_l, H_, H_);
  gemm_mfma<<<gG, 256, 0, stream>>>(x, bt9_h, bt9_l, vb, nullptr, NQ_, H_, H_, 0);

  rope_k<<<8192, 256, 0, stream>>>(qb, kb, q_pos);
  fill_kv_planes<<<dim3(64, 16), 256, 0, stream>>>(kcache, vcache, kb, vb, kv_idxs,
      khp, klp, vthp, vtlp);

  flash_mfma<<<dim3(32, 16), 256, 0, stream>>>(qb, khp, klp, vthp, vtlp, q_pos, k_pos, ctx);
  write_kv<<<8192, 256, 0, stream>>>(kcache, vcache, kb, vb, in_hs, map_full, kc_o, vc_o);

  wsplit_t<<<gTH, 256, 0, stream>>>(wo, bt6_h, bt6_l, H_, H_);
  gemm_mfma<<<gG, 256, 0, stream>>>(ctx, bt6_h, bt6_l, hs2, hs, NQ_, H_, H_, 1);
  rmsnorm_k<<<NQ_, 256, 0, stream>>>(hs2, ln2, x);

  wsplit_t<<<dim3(FF_ / 64, H_ / 64), 256, 0, stream>>>(w_gate, btg_h, btg_l, H_, FF_);
  gemm_mfma<<<dim3(FF_ / 128, NQ_ / 128), 256, 0, stream>>>(x, btg_h, btg_l, act, nullptr, NQ_, FF_, H_, 0);
  wsplit_t<<<dim3(FF_ / 64, H_ / 64), 256, 0, stream>>>(w_up, btg_h, btg_l, H_, FF_);
  gemm_mfma<<<dim3(FF_ / 128, NQ_ / 128), 256, 0, stream>>>(x, btg_h, btg_l, act, act, NQ_, FF_, H_, 2);
  wsplit_t<<<dim3(H_ / 64, FF_ / 64), 256, 0, stream>>>(w_down, btg_h, btg_l, FF_, H_);
  gemm_mfma<<<gG, 256, 0, stream>>>(act, btg_h, btg_l, out_o, hs2, NQ_, H_, FF_, 1);

  aux_write<<<8192, 256, 0, stream>>>(out_o, auxc, pruned, aux_bit, map_full, aux_o);
}

// Round 3
// 1827.953 us; speedup vs baseline: 2.7866x; 1.1770x over previous
//
#include <hip/hip_runtime.h>
#include <math.h>

// ---------------- problem constants ----------------
constexpr int S_    = 4096;
constexpr int NKV   = 2048;
constexpr int NAUX  = 512;
constexpr int NNEW  = 1536;
constexpr int H_    = 2048;
constexpr int NH_   = 16;
constexpr int HD_   = 128;
constexpr int FF_   = 8192;
constexpr int NQ_   = 2048;   // NNEW + NAUX
constexpr int NK_   = 4096;   // NKV + NQ
constexpr int PRUNE = 409;
constexpr float EPSF = 1e-6f;

typedef __attribute__((ext_vector_type(8))) short bf16x8;
typedef __attribute__((ext_vector_type(16))) float f32x16;

__device__ __forceinline__ ushort f2bf(float x) {
  union { float f; unsigned u; } a; a.f = x;
  unsigned r = a.u + 0x7fffu + ((a.u >> 16) & 1u);
  return (ushort)(r >> 16);
}
__device__ __forceinline__ float bf2f(ushort h) {
  union { unsigned u; float f; } a; a.u = ((unsigned)h) << 16;
  return a.f;
}
__device__ __forceinline__ unsigned cvt_pk_bf16(float a, float b) {
  unsigned r;
  asm("v_cvt_pk_bf16_f32 %0, %1, %2" : "=v"(r) : "v"(a), "v"(b));
  return r;
}
__device__ __forceinline__ float bflo(unsigned w) { union { unsigned u; float f; } x; x.u = w << 16; return x.f; }
__device__ __forceinline__ float bfhi(unsigned w) { union { unsigned u; float f; } x; x.u = w & 0xffff0000u; return x.f; }

// ---------------- index prep ----------------
__global__ __launch_bounds__(256) void prep_build(
    const int* __restrict__ kv_idxs, const int* __restrict__ aux_idxs,
    const int* __restrict__ new_idxs, const int* __restrict__ positions,
    int* hs_idxs, int* q_pos, int* key_tok, int* k_pos,
    int* map_full, int* in_hs, int* aux_bit, int* pruned_bit, int* last_hs)
{
  int t = blockIdx.x * 256 + threadIdx.x;     // grid covers 4096
  if (t < S_) { map_full[t] = 0; in_hs[t] = 0; aux_bit[t] = 0; pruned_bit[t] = 0; }
  if (t < NQ_) {
    int tok = (t < NNEW) ? new_idxs[t] : aux_idxs[t - NNEW];
    hs_idxs[t] = tok;
    q_pos[t] = positions[tok];
  }
  if (t < NK_) {
    int tok;
    if (t < NKV) tok = kv_idxs[t];
    else { int i = t - NKV; tok = (i < NNEW) ? new_idxs[i] : aux_idxs[i - NNEW]; }
    key_tok[t] = tok;
    k_pos[t] = positions[tok];
  }
  if (t < NNEW && new_idxs[t] == S_ - 1) last_hs[0] = t;
}

__global__ __launch_bounds__(256) void prep_scatter(
    const int* __restrict__ hs_idxs, const int* __restrict__ aux_idxs,
    int* map_full, int* in_hs, int* aux_bit)
{
  int t = blockIdx.x * 256 + threadIdx.x;
  if (t < NQ_) { int tok = hs_idxs[t]; map_full[tok] = t; in_hs[tok] = 1; }
  else if (t < NQ_ + NAUX) { aux_bit[aux_idxs[t - NQ_]] = 1; }
}

// Prune semantics of the reference (bug-compatible): see previous session note.
__global__ __launch_bounds__(256) void prune_set(
    const int* __restrict__ kv_idxs, int* __restrict__ pruned_bit)
{
  int t = blockIdx.x * 256 + threadIdx.x;
  if (t < PRUNE - 1) pruned_bit[kv_idxs[t]] = 1;
  if (t == PRUNE - 1) pruned_bit[S_ - 1] = 1;
}

// ---------------- hs = concat(hidden_states, aux_cache[aux_idxs]) ----------------
__global__ __launch_bounds__(256) void build_hs(
    const float* __restrict__ hidden, const float* __restrict__ auxc,
    const int* __restrict__ aux_idxs, float* __restrict__ hs)
{
  int gid = blockIdx.x * 256 + threadIdx.x;   // NQ*H/4 float4
  int c4 = gid & 511;                          // H/4 = 512
  int i  = gid >> 9;
  const float4* src;
  if (i < NNEW) src = (const float4*)hidden + (size_t)i * 512 + c4;
  else          src = (const float4*)auxc + (size_t)aux_idxs[i - NNEW] * 512 + c4;
  ((float4*)hs)[gid] = *src;
}

// ---------------- rmsnorm -> bf16 hi/lo planes ----------------
__global__ __launch_bounds__(256) void rmsnorm_split(
    const float* __restrict__ in, const float* __restrict__ w,
    ushort* __restrict__ oh, ushort* __restrict__ ol)
{
  int row = blockIdx.x, t = threadIdx.x;
  const float4* r4 = (const float4*)(in + (size_t)row * H_);
  const float4* w4 = (const float4*)w;
  float ss = 0.f;
  float4 v0 = r4[t], v1 = r4[t + 256];
  ss += v0.x*v0.x + v0.y*v0.y + v0.z*v0.z + v0.w*v0.w;
  ss += v1.x*v1.x + v1.y*v1.y + v1.z*v1.z + v1.w*v1.w;
  __shared__ float red[256];
  red[t] = ss; __syncthreads();
  for (int s = 128; s > 0; s >>= 1) { if (t < s) red[t] += red[t + s]; __syncthreads(); }
  float inv = rsqrtf(red[0] / (float)H_ + EPSF);
  float4 wv0 = w4[t], wv1 = w4[t + 256];
  float f[8];
  f[0] = v0.x*inv*wv0.x; f[1] = v0.y*inv*wv0.y; f[2] = v0.z*inv*wv0.z; f[3] = v0.w*inv*wv0.w;
  f[4] = v1.x*inv*wv1.x; f[5] = v1.y*inv*wv1.y; f[6] = v1.z*inv*wv1.z; f[7] = v1.w*inv*wv1.w;
  ushort4 h0, l0, h1, l1;
  h0.x = f2bf(f[0]); l0.x = f2bf(f[0] - bf2f(h0.x));
  h0.y = f2bf(f[1]); l0.y = f2bf(f[1] - bf2f(h0.y));
  h0.z = f2bf(f[2]); l0.z = f2bf(f[2] - bf2f(h0.z));
  h0.w = f2bf(f[3]); l0.w = f2bf(f[3] - bf2f(h0.w));
  h1.x = f2bf(f[4]); l1.x = f2bf(f[4] - bf2f(h1.x));
  h1.y = f2bf(f[5]); l1.y = f2bf(f[5] - bf2f(h1.y));
  h1.z = f2bf(f[6]); l1.z = f2bf(f[6] - bf2f(h1.z));
  h1.w = f2bf(f[7]); l1.w = f2bf(f[7] - bf2f(h1.w));
  size_t o = (size_t)row * H_ + t * 4;
  *(ushort4*)(oh + o) = h0; *(ushort4*)(ol + o) = l0;
  *(ushort4*)(oh + o + 1024) = h1; *(ushort4*)(ol + o + 1024) = l1;
}

// ---------------- weight transpose + bf16 hi/lo split ----------------
// W[K][N] f32 -> Th/Tl [N][K] bf16 planes.  grid = (N/64, K/64)
__global__ __launch_bounds__(256) void wsplit_t(
    const float* __restrict__ Wsrc, ushort* __restrict__ Th, ushort* __restrict__ Tl,
    int K, int N)
{
  __shared__ float tile[64][65];
  const int bn = blockIdx.x * 64, bk = blockIdx.y * 64;
  const int t = threadIdx.x;
  #pragma unroll
  for (int r = 0; r < 4; ++r) {
    int idx = t + 256 * r;
    int row = idx >> 4, c = (idx & 15) * 4;
    float4 v = *(const float4*)(Wsrc + (size_t)(bk + row) * N + bn + c);
    tile[row][c] = v.x; tile[row][c+1] = v.y; tile[row][c+2] = v.z; tile[row][c+3] = v.w;
  }
  __syncthreads();
  #pragma unroll
  for (int r = 0; r < 4; ++r) {
    int idx = t + 256 * r;
    int n = idx >> 4, k = (idx & 15) * 4;
    float v0 = tile[k][n], v1 = tile[k+1][n], v2 = tile[k+2][n], v3 = tile[k+3][n];
    ushort4 h, l;
    h.x = f2bf(v0); l.x = f2bf(v0 - bf2f(h.x));
    h.y = f2bf(v1); l.y = f2bf(v1 - bf2f(h.y));
    h.z = f2bf(v2); l.z = f2bf(v2 - bf2f(h.z));
    h.w = f2bf(v3); l.w = f2bf(v3 - bf2f(h.w));
    size_t off = (size_t)(bn + n) * K + bk + k;
    *(ushort4*)(Th + off) = h;
    *(ushort4*)(Tl + off) = l;
  }
}

// ---------------- bf16x3 MFMA GEMM: C[M,N] = A[M,K] @ B[K,N] (+epilogue) ----------------
// A: either pre-split planes Ah/Al (bf16 [M][K]) or f32 Af (split in-flight).
// Bh/Bl: bf16 [N][K] pre-transposed planes.
// epi: 0 plain, 1 C = X + acc, 2 C = silu(X) * acc (X may alias C)
__global__ __launch_bounds__(256) void gemm_mfma(
    const ushort* __restrict__ Ah, const ushort* __restrict__ Al,
    const float* __restrict__ Af,
    const ushort* __restrict__ Bh, const ushort* __restrict__ Bl,
    float* __restrict__ C, const float* __restrict__ X,
    int M, int N, int K, int epi)
{
  __shared__ ushort As_h[128][40];
  __shared__ ushort As_l[128][40];
  __shared__ ushort Bs_h[128][40];
  __shared__ ushort Bs_l[128][40];
  const int bm = blockIdx.y * 128, bn = blockIdx.x * 128;
  const int t = threadIdx.x;
  const int lane = t & 63;
  const int wid = t >> 6;
  const int wr = wid >> 1, wc = wid & 1;
  const int fr = lane & 31;
  const int kg = lane >> 5;

  f32x16 acc[2][2];
  #pragma unroll
  for (int mi = 0; mi < 2; ++mi)
    #pragma unroll
    for (int ni = 0; ni < 2; ++ni)
      #pragma unroll
      for (int r = 0; r < 16; ++r) acc[mi][ni][r] = 0.f;

  for (int k0 = 0; k0 < K; k0 += 32) {
    if (Af) {
      // stage A tile 128x32 f32 -> hi/lo bf16 (4 float4 per thread)
      #pragma unroll
      for (int r = 0; r < 4; ++r) {
        int idx = t + 256 * r;
        int row = idx >> 3, c = (idx & 7) * 4;
        float4 v = *(const float4*)(Af + (size_t)(bm + row) * K + k0 + c);
        ushort4 h, l;
        h.x = f2bf(v.x); l.x = f2bf(v.x - bf2f(h.x));
        h.y = f2bf(v.y); l.y = f2bf(v.y - bf2f(h.y));
        h.z = f2bf(v.z); l.z = f2bf(v.z - bf2f(h.z));
        h.w = f2bf(v.w); l.w = f2bf(v.w - bf2f(h.w));
        *(ushort4*)(&As_h[row][c]) = h;
        *(ushort4*)(&As_l[row][c]) = l;
      }
    } else {
      // stage A planes: 1024 uint4 (both planes), pure copy
      #pragma unroll
      for (int r = 0; r < 4; ++r) {
        int idx = t + 256 * r;
        int pl = idx >> 9, rem = idx & 511;
        int row = rem >> 2, c8 = (rem & 3) * 8;
        const ushort* src = (pl ? Al : Ah) + (size_t)(bm + row) * K + k0 + c8;
        ushort* dst = (pl ? &As_l[row][c8] : &As_h[row][c8]);
        *(uint4*)dst = *(const uint4*)src;
      }
    }
    // stage B planes: 1024 uint4
    #pragma unroll
    for (int r = 0; r < 4; ++r) {
      int idx = t + 256 * r;
      int pl = idx >> 9, rem = idx & 511;
      int n = rem >> 2, c8 = (rem & 3) * 8;
      const ushort* src = (pl ? Bl : Bh) + (size_t)(bn + n) * K + k0 + c8;
      ushort* dst = (pl ? &Bs_l[n][c8] : &Bs_h[n][c8]);
      *(uint4*)dst = *(const uint4*)src;
    }
    __syncthreads();
    #pragma unroll
    for (int ks = 0; ks < 2; ++ks) {
      const int ko = ks * 16 + kg * 8;
      bf16x8 ah[2], al[2], bh[2], bl[2];
      #pragma unroll
      for (int mi = 0; mi < 2; ++mi) {
        ah[mi] = *(const bf16x8*)(&As_h[wr * 64 + mi * 32 + fr][ko]);
        al[mi] = *(const bf16x8*)(&As_l[wr * 64 + mi * 32 + fr][ko]);
        bh[mi] = *(const bf16x8*)(&Bs_h[wc * 64 + mi * 32 + fr][ko]);
        bl[mi] = *(const bf16x8*)(&Bs_l[wc * 64 + mi * 32 + fr][ko]);
      }
      #pragma unroll
      for (int mi = 0; mi < 2; ++mi)
        #pragma unroll
        for (int ni = 0; ni < 2; ++ni) {
          acc[mi][ni] = __builtin_amdgcn_mfma_f32_32x32x16_bf16(ah[mi], bh[ni], acc[mi][ni], 0, 0, 0);
          acc[mi][ni] = __builtin_amdgcn_mfma_f32_32x32x16_bf16(ah[mi], bl[ni], acc[mi][ni], 0, 0, 0);
          acc[mi][ni] = __builtin_amdgcn_mfma_f32_32x32x16_bf16(al[mi], bh[ni], acc[mi][ni], 0, 0, 0);
        }
    }
    __syncthreads();
  }
  #pragma unroll
  for (int mi = 0; mi < 2; ++mi) {
    #pragma unroll
    for (int ni = 0; ni < 2; ++ni) {
      #pragma unroll
      for (int r = 0; r < 16; ++r) {
        int row = bm + wr * 64 + mi * 32 + (r & 3) + 8 * (r >> 2) + 4 * kg;
        int col = bn + wc * 64 + ni * 32 + fr;
        size_t idx = (size_t)row * N + col;
        float v = acc[mi][ni][r];
        if (epi == 1) v += X[idx];
        else if (epi == 2) { float g = X[idx]; v = (g / (1.f + expf(-g))) * v; }
        C[idx] = v;
      }
    }
  }
}

// ---------------- RoPE in-place on q and k ----------------
__global__ __launch_bounds__(256) void rope_k(
    float* __restrict__ qb, float* __restrict__ kb, const int* __restrict__ q_pos)
{
  int gid = blockIdx.x * 256 + threadIdx.x;   // NQ*NH*64
  int d = gid & 63;
  int h = (gid >> 6) & 15;
  int i = gid >> 10;
  int p = q_pos[i];
  double ang = (double)p * exp((double)d * -0.14391156831212787);
  float c = (float)cos(ang), s = (float)sin(ang);
  size_t ia = (size_t)i * H_ + h * HD_ + d;
  size_t ib = ia + 64;
  float qa = qb[ia], qbv = qb[ib];
  qb[ia] = qa * c - qbv * s;
  qb[ib] = qbv * c + qa * s;
  float ka = kb[ia], kbv = kb[ib];
  kb[ia] = ka * c - kbv * s;
  kb[ib] = kbv * c + ka * s;
}

// ---------------- K (hi/lo) + V^T (hi) bf16 planes ----------------
// kh/kl: [NH][NK][HD]; vth: [NH][HD][NK].  grid = (NK/64, NH)
__global__ __launch_bounds__(256) void fill_kv_planes(
    const float* __restrict__ kcache, const float* __restrict__ vcache,
    const float* __restrict__ kb, const float* __restrict__ vb,
    const int* __restrict__ kv_idxs,
    ushort* __restrict__ kh, ushort* __restrict__ kl,
    ushort* __restrict__ vth)
{
  __shared__ float vt[64][133];
  const int h = blockIdx.y;
  const int kbase = blockIdx.x * 64;
  const int t = threadIdx.x;
  #pragma unroll
  for (int r = 0; r < 8; ++r) {
    int idx = t + 256 * r;                     // 2048 float4
    int key = idx >> 5, d4 = idx & 31;
    int j = kbase + key;
    float4 kv, vv;
    if (j < NKV) {
      int tok = kv_idxs[j];
      size_t src = ((size_t)h * S_ + tok) * 32 + d4;
      kv = ((const float4*)kcache)[src];
      vv = ((const float4*)vcache)[src];
    } else {
      int i = j - NKV;
      size_t src = (size_t)i * 512 + h * 32 + d4;
      kv = ((const float4*)kb)[src];
      vv = ((const float4*)vb)[src];
    }
    ushort4 hh, ll;
    hh.x = f2bf(kv.x); ll.x = f2bf(kv.x - bf2f(hh.x));
    hh.y = f2bf(kv.y); ll.y = f2bf(kv.y - bf2f(hh.y));
    hh.z = f2bf(kv.z); ll.z = f2bf(kv.z - bf2f(hh.z));
    hh.w = f2bf(kv.w); ll.w = f2bf(kv.w - bf2f(hh.w));
    size_t dst = ((size_t)(h * NK_ + j)) * 128 + d4 * 4;
    *(ushort4*)(kh + dst) = hh;
    *(ushort4*)(kl + dst) = ll;
    vt[key][d4 * 4 + 0] = vv.x; vt[key][d4 * 4 + 1] = vv.y;
    vt[key][d4 * 4 + 2] = vv.z; vt[key][d4 * 4 + 3] = vv.w;
  }
  __syncthreads();
  #pragma unroll
  for (int r = 0; r < 8; ++r) {
    int idx = t + 256 * r;                     // 2048 groups of 4 keys
    int d = idx >> 4, kq = (idx & 15) * 4;
    float v0 = vt[kq + 0][d], v1 = vt[kq + 1][d], v2 = vt[kq + 2][d], v3 = vt[kq + 3][d];
    ushort4 hh;
    hh.x = f2bf(v0); hh.y = f2bf(v1); hh.z = f2bf(v2); hh.w = f2bf(v3);
    size_t dst = ((size_t)(h * 128 + d)) * NK_ + kbase + kq;
    *(ushort4*)(vth + dst) = hh;
  }
}

// ---------------- MFMA flash attention ----------------
// Flat grid 512. Block mapping: XCD-affine heads (2 heads per XCD) and
// work-balanced q-block pairing (half 0: even qb ascending; half 1: odd qb
// descending) so co-resident blocks sum to ~constant causal work.
// 4 waves = 2(q-half) x 2(key-parity). Swapped QK^T, lane-local softmax.
// K hi/lo, P hi/lo, V hi only. ctx written as bf16 hi/lo planes.
union FlashLDS {
  struct { ushort K[2][64][136]; ushort V[128][72]; int kps[64]; } s;
  struct { float acc[2][32][128]; float ml[2][2][32]; } m;
};

__global__ __launch_bounds__(256, 3) void flash_mfma(
    const float* __restrict__ qb, const ushort* __restrict__ khg,
    const ushort* __restrict__ klg, const ushort* __restrict__ vthg,
    const int* __restrict__ q_pos, const int* __restrict__ k_pos,
    ushort* __restrict__ ctxh, ushort* __restrict__ ctxl)
{
  __shared__ FlashLDS U;
  const int b = blockIdx.x;
  const int half = b >> 8, r_ = b & 255;
  const int h = (r_ & 7) * 2 + ((r_ >> 3) & 1);
  const int q16 = r_ >> 4;
  const int q0 = (half ? (31 - 2 * q16) : (2 * q16)) * 64;
  const int t = threadIdx.x;
  const int w = t >> 6, lane = t & 63;
  const int wq = w & 1, wk = w >> 1;
  const int kg = lane >> 5;
  const int qc = lane & 31;
  const int qi = q0 + wq * 32 + qc;
  const float scale = 0.08838834764831844f;    // 1/sqrt(128)

  // Q fragments, scale folded in, hi/lo split. 8 k-slices of 16 dims.
  bf16x8 qh[8], ql[8];
  {
    const float4* q4 = (const float4*)qb;
    #pragma unroll
    for (int s = 0; s < 8; ++s) {
      size_t a = (size_t)qi * 512 + h * 32 + s * 4 + kg * 2;
      float4 f0 = q4[a], f1 = q4[a + 1];
      float f[8] = {f0.x, f0.y, f0.z, f0.w, f1.x, f1.y, f1.z, f1.w};
      union { ushort u[8]; bf16x8 v; } Hq, Lq;
      #pragma unroll
      for (int j = 0; j < 8; ++j) {
        float qs = f[j] * scale;
        ushort hh = f2bf(qs);
        Hq.u[j] = hh; Lq.u[j] = f2bf(qs - bf2f(hh));
      }
      qh[s] = Hq.v; ql[s] = Lq.v;
    }
  }
  const int qp = q_pos[qi];
  const int wave_qmin = __shfl(qp, 0);
  const int wave_qmax = __shfl(qp, 31);
  const int bqmax = q_pos[q0 + 63];

  f32x16 acc[4];
  #pragma unroll
  for (int f = 0; f < 4; ++f)
    #pragma unroll
    for (int r = 0; r < 16; ++r) acc[f][r] = 0.f;
  float m_run = -INFINITY, l_run = 0.f;

  for (int kt = 0; kt < NK_ / 64; ++kt) {
    const int kbase = kt * 64;
    if (k_pos[kbase] > bqmax) continue;        // block-uniform causal skip
    // ---- stage K (2 planes): 2048 uint4 ----
    #pragma unroll
    for (int r = 0; r < 8; ++r) {
      int idx = t + 256 * r;
      int p = idx >> 10, rem = idx & 1023;
      int key = rem >> 4, c8 = (rem & 15) * 8;
      const ushort* src = (p ? klg : khg) + ((size_t)(h * NK_ + kbase + key) * 128 + c8);
      *(uint4*)(&U.s.K[p][key][c8]) = *(const uint4*)src;
    }
    // ---- stage V^T (hi only): 1024 uint4 ----
    #pragma unroll
    for (int r = 0; r < 4; ++r) {
      int idx = t + 256 * r;
      int d = idx >> 3, c8 = (idx & 7) * 8;
      const ushort* src = vthg + ((size_t)(h * 128 + d) * NK_ + kbase + c8);
      *(uint4*)(&U.s.V[d][c8]) = *(const uint4*)src;
    }
    if (t < 64) U.s.kps[t] = k_pos[kbase + t];
    __syncthreads();

    const int kpmin_half = U.s.kps[wk * 32];
    if (kpmin_half <= wave_qmax) {
      const bool needmask = (U.s.kps[wk * 32 + 31] > wave_qmin);
      // ---- QK^T (swapped): S^T = K . Q ----
      f32x16 sA, sB;
      #pragma unroll
      for (int r = 0; r < 16; ++r) { sA[r] = 0.f; sB[r] = 0.f; }
      __builtin_amdgcn_s_setprio(1);
      #pragma unroll
      for (int s = 0; s < 8; ++s) {
        const int co = s * 16 + kg * 8;
        bf16x8 khf = *(const bf16x8*)(&U.s.K[0][wk * 32 + qc][co]);
        bf16x8 klf = *(const bf16x8*)(&U.s.K[1][wk * 32 + qc][co]);
        sA = __builtin_amdgcn_mfma_f32_32x32x16_bf16(khf, qh[s], sA, 0, 0, 0);
        sB = __builtin_amdgcn_mfma_f32_32x32x16_bf16(khf, ql[s], sB, 0, 0, 0);
        sB = __builtin_amdgcn_mfma_f32_32x32x16_bf16(klf, qh[s], sB, 0, 0, 0);
      }
      __builtin_amdgcn_s_setprio(0);
      float sc[16];
      #pragma unroll
      for (int r = 0; r < 16; ++r) sc[r] = sA[r] + sB[r];
      if (needmask) {
        #pragma unroll
        for (int r = 0; r < 16; ++r) {
          int kloc = wk * 32 + (r & 3) + 8 * (r >> 2) + 4 * kg;
          sc[r] = (U.s.kps[kloc] <= qp) ? sc[r] : -INFINITY;
        }
      }
      // ---- lane-local online softmax (q = lane column) ----
      float mloc = sc[0];
      #pragma unroll
      for (int r = 1; r < 16; ++r) mloc = fmaxf(mloc, sc[r]);
      mloc = fmaxf(mloc, __shfl_xor(mloc, 32));
      float m_new = fmaxf(m_run, mloc);
      float mexp = (m_new == -INFINITY) ? 0.f : m_new;
      if (__any(m_new > m_run)) {
        float aa = __expf(m_run - mexp);
        l_run *= aa;
        #pragma unroll
        for (int f = 0; f < 4; ++f)
          #pragma unroll
          for (int r = 0; r < 16; ++r) acc[f][r] *= aa;
      }
      m_run = m_new;
      float p[16]; float psum = 0.f;
      #pragma unroll
      for (int r = 0; r < 16; ++r) { p[r] = __expf(sc[r] - mexp); psum += p[r]; }
      psum += __shfl_xor(psum, 32);
      l_run += psum;
      // ---- pack P -> bf16 hi/lo B-fragments (cvt_pk + shfl_xor(32)) ----
      bf16x8 pfh[2], pfl[2];
      #pragma unroll
      for (int sl = 0; sl < 2; ++sl) {
        const float* pp = p + sl * 8;
        unsigned a0 = cvt_pk_bf16(pp[0], pp[1]);
        unsigned a1 = cvt_pk_bf16(pp[2], pp[3]);
        unsigned b0 = cvt_pk_bf16(pp[4], pp[5]);
        unsigned b1 = cvt_pk_bf16(pp[6], pp[7]);
        unsigned a0x = (unsigned)__shfl_xor((int)a0, 32);
        unsigned a1x = (unsigned)__shfl_xor((int)a1, 32);
        unsigned b0x = (unsigned)__shfl_xor((int)b0, 32);
        unsigned b1x = (unsigned)__shfl_xor((int)b1, 32);
        union { unsigned wd[4]; bf16x8 v; } PH, PL;
        PH.wd[0] = kg ? b0x : a0;
        PH.wd[1] = kg ? b1x : a1;
        PH.wd[2] = kg ? b0 : a0x;
        PH.wd[3] = kg ? b1 : a1x;
        float r0 = pp[0] - bflo(a0), r1 = pp[1] - bfhi(a0);
        float r2 = pp[2] - bflo(a1), r3 = pp[3] - bfhi(a1);
        float r4 = pp[4] - bflo(b0), r5 = pp[5] - bfhi(b0);
        float r6 = pp[6] - bflo(b1), r7 = pp[7] - bfhi(b1);
        unsigned c0 = cvt_pk_bf16(r0, r1);
        unsigned c1 = cvt_pk_bf16(r2, r3);
        unsigned d0 = cvt_pk_bf16(r4, r5);
        unsigned d1 = cvt_pk_bf16(r6, r7);
        unsigned c0x = (unsigned)__shfl_xor((int)c0, 32);
        unsigned c1x = (unsigned)__shfl_xor((int)c1, 32);
        unsigned d0x = (unsigned)__shfl_xor((int)d0, 32);
        unsigned d1x = (unsigned)__shfl_xor((int)d1, 32);
        PL.wd[0] = kg ? d0x : c0;
        PL.wd[1] = kg ? d1x : c1;
        PL.wd[2] = kg ? d0 : c0x;
        PL.wd[3] = kg ? d1 : c1x;
        pfh[sl] = PH.v; pfl[sl] = PL.v;
      }
      // ---- PV: ctx^T += V^T . P^T  (V hi plane only) ----
      __builtin_amdgcn_s_setprio(1);
      #pragma unroll
      for (int ks = 0; ks < 2; ++ks) {
        const int kc = wk * 32 + ks * 16 + kg * 8;
        bf16x8 vh0 = *(const bf16x8*)(&U.s.V[0 * 32 + qc][kc]);
        bf16x8 vh1 = *(const bf16x8*)(&U.s.V[1 * 32 + qc][kc]);
        bf16x8 vh2 = *(const bf16x8*)(&U.s.V[2 * 32 + qc][kc]);
        bf16x8 vh3 = *(const bf16x8*)(&U.s.V[3 * 32 + qc][kc]);
        acc[0] = __builtin_amdgcn_mfma_f32_32x32x16_bf16(vh0, pfh[ks], acc[0], 0, 0, 0);
        acc[1] = __builtin_amdgcn_mfma_f32_32x32x16_bf16(vh1, pfh[ks], acc[1], 0, 0, 0);
        acc[2] = __builtin_amdgcn_mfma_f32_32x32x16_bf16(vh2, pfh[ks], acc[2], 0, 0, 0);
        acc[3] = __builtin_amdgcn_mfma_f32_32x32x16_bf16(vh3, pfh[ks], acc[3], 0, 0, 0);
        acc[0] = __builtin_amdgcn_mfma_f32_32x32x16_bf16(vh0, pfl[ks], acc[0], 0, 0, 0);
        acc[1] = __builtin_amdgcn_mfma_f32_32x32x16_bf16(vh1, pfl[ks], acc[1], 0, 0, 0);
        acc[2] = __builtin_amdgcn_mfma_f32_32x32x16_bf16(vh2, pfl[ks], acc[2], 0, 0, 0);
        acc[3] = __builtin_amdgcn_mfma_f32_32x32x16_bf16(vh3, pfl[ks], acc[3], 0, 0, 0);
      }
      __builtin_amdgcn_s_setprio(0);
    }
    __syncthreads();
  }

  // ---- merge key-parity halves (wk=1 publishes, wk=0 combines) ----
  if (wk == 1) {
    #pragma unroll
    for (int f = 0; f < 4; ++f)
      #pragma unroll
      for (int rq = 0; rq < 4; ++rq) {
        float4 v;
        v.x = acc[f][rq * 4 + 0]; v.y = acc[f][rq * 4 + 1];
        v.z = acc[f][rq * 4 + 2]; v.w = acc[f][rq * 4 + 3];
        *(float4*)(&U.m.acc[wq][qc][f * 32 + kg * 4 + rq * 8]) = v;
      }
    if (kg == 0) { U.m.ml[wq][0][qc] = m_run; U.m.ml[wq][1][qc] = l_run; }
  }
  __syncthreads();
  if (wk == 0) {
    float m2 = U.m.ml[wq][0][qc];
    float l2 = U.m.ml[wq][1][qc];
    float mm = fmaxf(m_run, m2);
    float a1 = __expf(m_run - mm);
    float a2 = __expf(m2 - mm);
    float inv = 1.f / (l_run * a1 + l2 * a2);
    #pragma unroll
    for (int f = 0; f < 4; ++f)
      #pragma unroll
      for (int rq = 0; rq < 4; ++rq) {
        float4 oth = *(const float4*)(&U.m.acc[wq][qc][f * 32 + kg * 4 + rq * 8]);
        float o[4];
        o[0] = (acc[f][rq * 4 + 0] * a1 + oth.x * a2) * inv;
        o[1] = (acc[f][rq * 4 + 1] * a1 + oth.y * a2) * inv;
        o[2] = (acc[f][rq * 4 + 2] * a1 + oth.z * a2) * inv;
        o[3] = (acc[f][rq * 4 + 3] * a1 + oth.w * a2) * inv;
        ushort4 hh, ll;
        hh.x = f2bf(o[0]); ll.x = f2bf(o[0] - bf2f(hh.x));
        hh.y = f2bf(o[1]); ll.y = f2bf(o[1] - bf2f(hh.y));
        hh.z = f2bf(o[2]); ll.z = f2bf(o[2] - bf2f(hh.z));
        hh.w = f2bf(o[3]); ll.w = f2bf(o[3] - bf2f(hh.w));
        size_t oidx = (size_t)qi * H_ + h * 128 + f * 32 + kg * 4 + rq * 8;
        *(ushort4*)(ctxh + oidx) = hh;
        *(ushort4*)(ctxl + oidx) = ll;
      }
  }
}

// ---------------- cache scatter outputs ----------------
__global__ __launch_bounds__(256) void write_kv(
    const float* __restrict__ kcache, const float* __restrict__ vcache,
    const float* __restrict__ kb, const float* __restrict__ vb,
    const int* __restrict__ in_hs, const int* __restrict__ map_full,
    float* __restrict__ kc_o, float* __restrict__ vc_o)
{
  int gid = blockIdx.x * 256 + threadIdx.x;   // NH*S*HD/4
  int d4 = gid & 31;
  int s  = (gid >> 5) & (S_ - 1);
  int h  = gid >> 17;
  float4 kv, vv;
  if (in_hs[s]) {
    int i = map_full[s];
    size_t src = (size_t)i * (H_ / 4) + h * 32 + d4;
    kv = ((const float4*)kb)[src];
    vv = ((const float4*)vb)[src];
  } else {
    kv = ((const float4*)kcache)[gid];
    vv = ((const float4*)vcache)[gid];
  }
  ((float4*)kc_o)[gid] = kv;
  ((float4*)vc_o)[gid] = vv;
}

__global__ __launch_bounds__(256) void aux_write(
    const float* __restrict__ outb, const float* __restrict__ auxc,
    const int* __restrict__ pruned_bit, const int* __restrict__ aux_bit,
    const int* __restrict__ map_full, float* __restrict__ aux_o)
{
  int gid = blockIdx.x * 256 + threadIdx.x;   // S*H/4
  int c4 = gid & 511;
  int s  = gid >> 9;
  float4 v;
  if (pruned_bit[s] && !aux_bit[s])
    v = ((const float4*)outb)[(size_t)map_full[s] * 512 + c4];
  else
    v = ((const float4*)auxc)[gid];
  ((float4*)aux_o)[gid] = v;
}

// ---------------- host ----------------
extern "C" void kernel_launch(void* const* d_in, const int* in_sizes, int n_in,
                              void* d_out, int out_size, void* d_ws, size_t ws_size,
                              hipStream_t stream) {
  (void)in_sizes; (void)n_in; (void)out_size; (void)ws_size;
  const float* hidden  = (const float*)d_in[0];
  const float* kcache  = (const float*)d_in[1];
  const float* vcache  = (const float*)d_in[2];
  const float* auxc    = (const float*)d_in[3];
  const int* kv_idxs   = (const int*)d_in[4];
  const int* aux_idxs  = (const int*)d_in[5];
  const int* new_idxs  = (const int*)d_in[6];
  const int* positions = (const int*)d_in[7];
  const float* wq      = (const float*)d_in[8];
  const float* wk      = (const float*)d_in[9];
  const float* wv      = (const float*)d_in[10];
  const float* wo      = (const float*)d_in[11];
  const float* w_gate  = (const float*)d_in[12];
  const float* w_up    = (const float*)d_in[13];
  const float* w_down  = (const float*)d_in[14];
  const float* ln1     = (const float*)d_in[15];
  const float* ln2     = (const float*)d_in[16];

  float* out_o = (float*)d_out;
  float* kc_o  = out_o + (size_t)NQ_ * H_;
  float* vc_o  = kc_o + (size_t)NH_ * S_ * HD_;
  float* aux_o = vc_o + (size_t)NH_ * S_ * HD_;

  // workspace layout (units of M4 = 4M floats = 16.78 MB), 11 slots + ints:
  //  0: hs(f32)            [live until wo-GEMM]
  //  1: xh|xl bf16 planes  [QKV phase; rewritten for FFN phase]
  //  2: qb  3: kb  4: vb   (f32)
  //  5: khp  6: klp  7: vthp (attn bf16 planes)
  //  8: ctxh|ctxl planes   [attn out; dead after wo-GEMM]
  //  9: QKV/wo weight planes (bt)  [dead by FFN]
  //  10: hs2 (f32)
  //  FFN: act f32 -> slots 2-5; btg_h -> 6-7; btg_l -> 8-9
  float* W = (float*)d_ws;
  const size_t M4 = 4194304;                  // NQ*H
  float* hs    = W;
  ushort* xh   = (ushort*)(W + 1 * M4);
  ushort* xl   = xh + (size_t)NQ_ * H_;
  float* qb    = W + 2 * M4;
  float* kb    = W + 3 * M4;
  float* vb    = W + 4 * M4;
  ushort* khp  = (ushort*)(W + 5 * M4);
  ushort* klp  = (ushort*)(W + 6 * M4);
  ushort* vthp = (ushort*)(W + 7 * M4);
  ushort* ctxh = (ushort*)(W + 8 * M4);
  ushort* ctxl = ctxh + (size_t)NQ_ * H_;
  ushort* bt_h = (ushort*)(W + 9 * M4);
  ushort* bt_l = bt_h + (size_t)H_ * H_;
  float* hs2   = W + 10 * M4;
  float* act   = W + 2 * M4;                  // slots 2-5 (FFN phase)
  ushort* btg_h = (ushort*)(W + 6 * M4);      // slots 6-7
  ushort* btg_l = (ushort*)(W + 8 * M4);      // slots 8-9
  int* ip = (int*)(W + 11 * M4);
  int* hs_idxs = ip;           ip += NQ_;
  int* q_pos   = ip;           ip += NQ_;
  int* key_tok = ip;           ip += NK_;
  int* k_pos   = ip;           ip += NK_;
  int* map_full= ip;           ip += S_;
  int* in_hs   = ip;           ip += S_;
  int* aux_bit = ip;           ip += S_;
  int* pruned  = ip;           ip += S_;
  int* last_hs = ip;           ip += 4;

  prep_build<<<16, 256, 0, stream>>>(kv_idxs, aux_idxs, new_idxs, positions,
      hs_idxs, q_pos, key_tok, k_pos, map_full, in_hs, aux_bit, pruned, last_hs);
  prep_scatter<<<10, 256, 0, stream>>>(hs_idxs, aux_idxs, map_full, in_hs, aux_bit);
  prune_set<<<2, 256, 0, stream>>>(kv_idxs, pruned);
  build_hs<<<4096, 256, 0, stream>>>(hidden, auxc, aux_idxs, hs);
  rmsnorm_split<<<NQ_, 256, 0, stream>>>(hs, ln1, xh, xl);

  const dim3 gTH(H_ / 64, H_ / 64);
  const dim3 gG(H_ / 128, NQ_ / 128);
  wsplit_t<<<gTH, 256, 0, stream>>>(wq, bt_h, bt_l, H_, H_);
  gemm_mfma<<<gG, 256, 0, stream>>>(xh, xl, nullptr, bt_h, bt_l, qb, nullptr, NQ_, H_, H_, 0);
  wsplit_t<<<gTH, 256, 0, stream>>>(wk, bt_h, bt_l, H_, H_);
  gemm_mfma<<<gG, 256, 0, stream>>>(xh, xl, nullptr, bt_h, bt_l, kb, nullptr, NQ_, H_, H_, 0);
  wsplit_t<<<gTH, 256, 0, stream>>>(wv, bt_h, bt_l, H_, H_);
  gemm_mfma<<<gG, 256, 0, stream>>>(xh, xl, nullptr, bt_h, bt_l, vb, nullptr, NQ_, H_, H_, 0);

  rope_k<<<8192, 256, 0, stream>>>(qb, kb, q_pos);
  fill_kv_planes<<<dim3(64, 16), 256, 0, stream>>>(kcache, vcache, kb, vb, kv_idxs,
      khp, klp, vthp);

  flash_mfma<<<512, 256, 0, stream>>>(qb, khp, klp, vthp, q_pos, k_pos, ctxh, ctxl);
  write_kv<<<8192, 256, 0, stream>>>(kcache, vcache, kb, vb, in_hs, map_full, kc_o, vc_o);

  wsplit_t<<<gTH, 256, 0, stream>>>(wo, bt_h, bt_l, H_, H_);
  gemm_mfma<<<gG, 256, 0, stream>>>(ctxh, ctxl, nullptr, bt_h, bt_l, hs2, hs, NQ_, H_, H_, 1);
  rmsnorm_split<<<NQ_, 256, 0, stream>>>(hs2, ln2, xh, xl);

  wsplit_t<<<dim3(FF_ / 64, H_ / 64), 256, 0, stream>>>(w_gate, btg_h, btg_l, H_, FF_);
  gemm_mfma<<<dim3(FF_ / 128, NQ_ / 128), 256, 0, stream>>>(xh, xl, nullptr, btg_h, btg_l, act, nullptr, NQ_, FF_, H_, 0);
  wsplit_t<<<dim3(FF_ / 64, H_ / 64), 256, 0, stream>>>(w_up, btg_h, btg_l, H_, FF_);
  gemm_mfma<<<dim3(FF_ / 128, NQ_ / 128), 256, 0, stream>>>(xh, xl, nullptr, btg_h, btg_l, act, act, NQ_, FF_, H_, 2);
  wsplit_t<<<dim3(H_ / 64, FF_ / 64), 256, 0, stream>>>(w_down, btg_h, btg_l, FF_, H_);
  gemm_mfma<<<gG, 256, 0, stream>>>(nullptr, nullptr, act, btg_h, btg_l, out_o, hs2, NQ_, H_, FF_, 1);

  aux_write<<<8192, 256, 0, stream>>>(out_o, auxc, pruned, aux_bit, map_full, aux_o);
}

// Round 4
// 1613.715 us; speedup vs baseline: 3.1565x; 1.1328x over previous
//
#include <hip/hip_runtime.h>
#include <math.h>

// ---------------- problem constants ----------------
constexpr int S_    = 4096;
constexpr int NKV   = 2048;
constexpr int NAUX  = 512;
constexpr int NNEW  = 1536;
constexpr int H_    = 2048;
constexpr int NH_   = 16;
constexpr int HD_   = 128;
constexpr int FF_   = 8192;
constexpr int NQ_   = 2048;   // NNEW + NAUX
constexpr int NK_   = 4096;   // NKV + NQ
constexpr int PRUNE = 409;
constexpr float EPSF = 1e-6f;

typedef __attribute__((ext_vector_type(8))) short bf16x8;
typedef __attribute__((ext_vector_type(16))) float f32x16;

__device__ __forceinline__ ushort f2bf(float x) {
  union { float f; unsigned u; } a; a.f = x;
  unsigned r = a.u + 0x7fffu + ((a.u >> 16) & 1u);
  return (ushort)(r >> 16);
}
__device__ __forceinline__ float bf2f(ushort h) {
  union { unsigned u; float f; } a; a.u = ((unsigned)h) << 16;
  return a.f;
}
__device__ __forceinline__ unsigned cvt_pk_bf16(float a, float b) {
  unsigned r;
  asm("v_cvt_pk_bf16_f32 %0, %1, %2" : "=v"(r) : "v"(a), "v"(b));
  return r;
}
__device__ __forceinline__ float bflo(unsigned w) { union { unsigned u; float f; } x; x.u = w << 16; return x.f; }
__device__ __forceinline__ float bfhi(unsigned w) { union { unsigned u; float f; } x; x.u = w & 0xffff0000u; return x.f; }

// async global->LDS, 16B per lane. LDS dest = base + lane*16 (HW); global src per-lane.
__device__ __forceinline__ void gload16(const ushort* g, ushort* l) {
  __builtin_amdgcn_global_load_lds(
      (const __attribute__((address_space(1))) unsigned int*)g,
      (__attribute__((address_space(3))) unsigned int*)l, 16, 0, 0);
}

// tiled bf16-plane layout: [row>>7][k>>5][(k>>3)&3][row&127][k&7]
// each 128x32 tile = 8KB contiguous = the exact LDS staging image (chunk-major).
__device__ __forceinline__ size_t tileoff(int row, int k, int K) {
  return ((size_t)((row >> 7) * (K >> 5) + (k >> 5)) << 12)
       + (size_t)((((k >> 3) & 3) << 10) + ((row & 127) << 3) + (k & 7));
}

// ---------------- index prep ----------------
__global__ __launch_bounds__(256) void prep_build(
    const int* __restrict__ kv_idxs, const int* __restrict__ aux_idxs,
    const int* __restrict__ new_idxs, const int* __restrict__ positions,
    int* hs_idxs, int* q_pos, int* key_tok, int* k_pos,
    int* map_full, int* in_hs, int* aux_bit, int* pruned_bit, int* last_hs)
{
  int t = blockIdx.x * 256 + threadIdx.x;     // grid covers 4096
  if (t < S_) { map_full[t] = 0; in_hs[t] = 0; aux_bit[t] = 0; pruned_bit[t] = 0; }
  if (t < NQ_) {
    int tok = (t < NNEW) ? new_idxs[t] : aux_idxs[t - NNEW];
    hs_idxs[t] = tok;
    q_pos[t] = positions[tok];
  }
  if (t < NK_) {
    int tok;
    if (t < NKV) tok = kv_idxs[t];
    else { int i = t - NKV; tok = (i < NNEW) ? new_idxs[i] : aux_idxs[i - NNEW]; }
    key_tok[t] = tok;
    k_pos[t] = positions[tok];
  }
  if (t < NNEW && new_idxs[t] == S_ - 1) last_hs[0] = t;
}

__global__ __launch_bounds__(256) void prep_scatter(
    const int* __restrict__ hs_idxs, const int* __restrict__ aux_idxs,
    int* map_full, int* in_hs, int* aux_bit)
{
  int t = blockIdx.x * 256 + threadIdx.x;
  if (t < NQ_) { int tok = hs_idxs[t]; map_full[tok] = t; in_hs[tok] = 1; }
  else if (t < NQ_ + NAUX) { aux_bit[aux_idxs[t - NQ_]] = 1; }
}

// Prune semantics of the reference (bug-compatible): see previous session note.
__global__ __launch_bounds__(256) void prune_set(
    const int* __restrict__ kv_idxs, int* __restrict__ pruned_bit)
{
  int t = blockIdx.x * 256 + threadIdx.x;
  if (t < PRUNE - 1) pruned_bit[kv_idxs[t]] = 1;
  if (t == PRUNE - 1) pruned_bit[S_ - 1] = 1;
}

// ---------------- hs = concat(hidden_states, aux_cache[aux_idxs]) ----------------
__global__ __launch_bounds__(256) void build_hs(
    const float* __restrict__ hidden, const float* __restrict__ auxc,
    const int* __restrict__ aux_idxs, float* __restrict__ hs)
{
  int gid = blockIdx.x * 256 + threadIdx.x;   // NQ*H/4 float4
  int c4 = gid & 511;                          // H/4 = 512
  int i  = gid >> 9;
  const float4* src;
  if (i < NNEW) src = (const float4*)hidden + (size_t)i * 512 + c4;
  else          src = (const float4*)auxc + (size_t)aux_idxs[i - NNEW] * 512 + c4;
  ((float4*)hs)[gid] = *src;
}

// ---------------- rmsnorm -> tiled bf16 hi/lo planes ----------------
__global__ __launch_bounds__(256) void rmsnorm_split(
    const float* __restrict__ in, const float* __restrict__ w,
    ushort* __restrict__ oh, ushort* __restrict__ ol)
{
  int row = blockIdx.x, t = threadIdx.x;
  const float4* r4 = (const float4*)(in + (size_t)row * H_);
  const float4* w4 = (const float4*)w;
  float ss = 0.f;
  float4 v0 = r4[t], v1 = r4[t + 256];
  ss += v0.x*v0.x + v0.y*v0.y + v0.z*v0.z + v0.w*v0.w;
  ss += v1.x*v1.x + v1.y*v1.y + v1.z*v1.z + v1.w*v1.w;
  __shared__ float red[256];
  red[t] = ss; __syncthreads();
  for (int s = 128; s > 0; s >>= 1) { if (t < s) red[t] += red[t + s]; __syncthreads(); }
  float inv = rsqrtf(red[0] / (float)H_ + EPSF);
  float4 wv0 = w4[t], wv1 = w4[t + 256];
  float f[8];
  f[0] = v0.x*inv*wv0.x; f[1] = v0.y*inv*wv0.y; f[2] = v0.z*inv*wv0.z; f[3] = v0.w*inv*wv0.w;
  f[4] = v1.x*inv*wv1.x; f[5] = v1.y*inv*wv1.y; f[6] = v1.z*inv*wv1.z; f[7] = v1.w*inv*wv1.w;
  ushort4 h0, l0, h1, l1;
  h0.x = f2bf(f[0]); l0.x = f2bf(f[0] - bf2f(h0.x));
  h0.y = f2bf(f[1]); l0.y = f2bf(f[1] - bf2f(h0.y));
  h0.z = f2bf(f[2]); l0.z = f2bf(f[2] - bf2f(h0.z));
  h0.w = f2bf(f[3]); l0.w = f2bf(f[3] - bf2f(h0.w));
  h1.x = f2bf(f[4]); l1.x = f2bf(f[4] - bf2f(h1.x));
  h1.y = f2bf(f[5]); l1.y = f2bf(f[5] - bf2f(h1.y));
  h1.z = f2bf(f[6]); l1.z = f2bf(f[6] - bf2f(h1.z));
  h1.w = f2bf(f[7]); l1.w = f2bf(f[7] - bf2f(h1.w));
  size_t o0 = tileoff(row, t * 4, H_);
  size_t o1 = tileoff(row, 1024 + t * 4, H_);
  *(ushort4*)(oh + o0) = h0; *(ushort4*)(ol + o0) = l0;
  *(ushort4*)(oh + o1) = h1; *(ushort4*)(ol + o1) = l1;
}

// ---------------- weight transpose + bf16 hi/lo split (tiled output) ----------------
// W[K][N] f32 -> Th/Tl tiled [N-panel][kstep][chunk][row][8].  grid = (N/64, K/64)
__global__ __launch_bounds__(256) void wsplit_t(
    const float* __restrict__ Wsrc, ushort* __restrict__ Th, ushort* __restrict__ Tl,
    int K, int N)
{
  __shared__ float tile[64][65];
  const int bn = blockIdx.x * 64, bk = blockIdx.y * 64;
  const int t = threadIdx.x;
  #pragma unroll
  for (int r = 0; r < 4; ++r) {
    int idx = t + 256 * r;
    int row = idx >> 4, c = (idx & 15) * 4;
    float4 v = *(const float4*)(Wsrc + (size_t)(bk + row) * N + bn + c);
    tile[row][c] = v.x; tile[row][c+1] = v.y; tile[row][c+2] = v.z; tile[row][c+3] = v.w;
  }
  __syncthreads();
  #pragma unroll
  for (int r = 0; r < 4; ++r) {
    int idx = t + 256 * r;
    int n = bn + (idx >> 4), k = bk + (idx & 15) * 4;
    int kl = k - bk;
    float v0 = tile[kl][n - bn], v1 = tile[kl+1][n - bn], v2 = tile[kl+2][n - bn], v3 = tile[kl+3][n - bn];
    ushort4 h, l;
    h.x = f2bf(v0); l.x = f2bf(v0 - bf2f(h.x));
    h.y = f2bf(v1); l.y = f2bf(v1 - bf2f(h.y));
    h.z = f2bf(v2); l.z = f2bf(v2 - bf2f(h.z));
    h.w = f2bf(v3); l.w = f2bf(v3 - bf2f(h.w));
    size_t off = tileoff(n, k, K);
    *(ushort4*)(Th + off) = h;
    *(ushort4*)(Tl + off) = l;
  }
}

// ---------------- bf16x3 MFMA GEMM, global_load_lds staging ----------------
// A: tiled planes Ah/Al, or f32 Af (split in-flight, chunk-major ds_write).
// B: tiled planes Bh/Bl. C f32 row-major.
// epi: 0 plain, 1 C=X+acc, 2 C=silu(X)*acc, 3 QKV-fused de-concat (N=3*2048).
// 1D grid, bijective XCD swizzle: XCD x owns bn-chunk [x*NXB/8, (x+1)*NXB/8).
__global__ __launch_bounds__(256) void gemm_mfma(
    const ushort* __restrict__ Ah, const ushort* __restrict__ Al,
    const float* __restrict__ Af,
    const ushort* __restrict__ Bh, const ushort* __restrict__ Bl,
    float* __restrict__ C, const float* __restrict__ X,
    int M, int N, int K, int epi)
{
  __shared__ __align__(16) ushort sAh[4096];
  __shared__ __align__(16) ushort sAl[4096];
  __shared__ __align__(16) ushort sBh[4096];
  __shared__ __align__(16) ushort sBl[4096];
  const int NXB = N >> 7;
  const int cx = NXB >> 3;
  const int flat = blockIdx.x;
  const int xcd = flat & 7, idxr = flat >> 3;
  const int bxi = xcd * cx + (idxr % cx);
  const int byi = idxr / cx;
  const int bm = byi * 128, bn = bxi * 128;
  const int t = threadIdx.x;
  const int lane = t & 63;
  const int wid = t >> 6;
  const int wr = wid >> 1, wc = wid & 1;
  const int fr = lane & 31;
  const int kg = lane >> 5;
  const int ub0 = wid * 128;
  const int Ksteps = K >> 5;

  f32x16 acc[2][2];
  #pragma unroll
  for (int mi = 0; mi < 2; ++mi)
    #pragma unroll
    for (int ni = 0; ni < 2; ++ni)
      #pragma unroll
      for (int r = 0; r < 16; ++r) acc[mi][ni][r] = 0.f;

  for (int k0 = 0; k0 < K; k0 += 32) {
    const int ks = k0 >> 5;
    const size_t tB = ((size_t)(bxi * Ksteps + ks)) << 12;
    if (Af) {
      // split-stage A f32 -> chunk-major hi/lo images
      #pragma unroll
      for (int r = 0; r < 2; ++r) {
        int u = t + 256 * r;
        int row = u >> 2, ch = u & 3;
        const float* s0 = Af + (size_t)(bm + row) * K + k0 + ch * 8;
        float4 v0 = *(const float4*)s0, v1 = *(const float4*)(s0 + 4);
        float f[8] = {v0.x,v0.y,v0.z,v0.w,v1.x,v1.y,v1.z,v1.w};
        union { ushort u16[8]; uint4 q; } Hh, Ll;
        #pragma unroll
        for (int j = 0; j < 8; ++j) {
          ushort hh = f2bf(f[j]);
          Hh.u16[j] = hh; Ll.u16[j] = f2bf(f[j] - bf2f(hh));
        }
        *(uint4*)&sAh[ch * 1024 + row * 8] = Hh.q;
        *(uint4*)&sAl[ch * 1024 + row * 8] = Ll.q;
      }
    } else {
      const size_t tA = ((size_t)(byi * Ksteps + ks)) << 12;
      const ushort* a0 = Ah + tA;
      const ushort* a1 = Al + tA;
      gload16(a0 + (size_t)(ub0 + lane) * 8,      sAh + ub0 * 8);
      gload16(a0 + (size_t)(ub0 + 64 + lane) * 8, sAh + (ub0 + 64) * 8);
      gload16(a1 + (size_t)(ub0 + lane) * 8,      sAl + ub0 * 8);
      gload16(a1 + (size_t)(ub0 + 64 + lane) * 8, sAl + (ub0 + 64) * 8);
    }
    {
      const ushort* b0 = Bh + tB;
      const ushort* b1 = Bl + tB;
      gload16(b0 + (size_t)(ub0 + lane) * 8,      sBh + ub0 * 8);
      gload16(b0 + (size_t)(ub0 + 64 + lane) * 8, sBh + (ub0 + 64) * 8);
      gload16(b1 + (size_t)(ub0 + lane) * 8,      sBl + ub0 * 8);
      gload16(b1 + (size_t)(ub0 + 64 + lane) * 8, sBl + (ub0 + 64) * 8);
    }
    __syncthreads();
    #pragma unroll
    for (int ksl = 0; ksl < 2; ++ksl) {
      const int co = (ksl * 2 + kg) * 1024;
      bf16x8 ah[2], al[2], bh[2], bl[2];
      #pragma unroll
      for (int mi = 0; mi < 2; ++mi) {
        ah[mi] = *(const bf16x8*)&sAh[co + (wr * 64 + mi * 32 + fr) * 8];
        al[mi] = *(const bf16x8*)&sAl[co + (wr * 64 + mi * 32 + fr) * 8];
        bh[mi] = *(const bf16x8*)&sBh[co + (wc * 64 + mi * 32 + fr) * 8];
        bl[mi] = *(const bf16x8*)&sBl[co + (wc * 64 + mi * 32 + fr) * 8];
      }
      #pragma unroll
      for (int mi = 0; mi < 2; ++mi)
        #pragma unroll
        for (int ni = 0; ni < 2; ++ni) {
          acc[mi][ni] = __builtin_amdgcn_mfma_f32_32x32x16_bf16(ah[mi], bh[ni], acc[mi][ni], 0, 0, 0);
          acc[mi][ni] = __builtin_amdgcn_mfma_f32_32x32x16_bf16(ah[mi], bl[ni], acc[mi][ni], 0, 0, 0);
          acc[mi][ni] = __builtin_amdgcn_mfma_f32_32x32x16_bf16(al[mi], bh[ni], acc[mi][ni], 0, 0, 0);
        }
    }
    __syncthreads();
  }
  #pragma unroll
  for (int mi = 0; mi < 2; ++mi) {
    #pragma unroll
    for (int ni = 0; ni < 2; ++ni) {
      #pragma unroll
      for (int r = 0; r < 16; ++r) {
        int row = bm + wr * 64 + mi * 32 + (r & 3) + 8 * (r >> 2) + 4 * kg;
        int col = bn + wc * 64 + ni * 32 + fr;
        float v = acc[mi][ni][r];
        size_t idx;
        if (epi == 3) {
          int mtx = col >> 11, cc = col & 2047;
          idx = ((size_t)mtx * M + row) * 2048 + cc;
        } else {
          idx = (size_t)row * N + col;
          if (epi == 1) v += X[idx];
          else if (epi == 2) { float g = X[idx]; v = (g / (1.f + expf(-g))) * v; }
        }
        C[idx] = v;
      }
    }
  }
}

// ---------------- RoPE in-place on q and k ----------------
__global__ __launch_bounds__(256) void rope_k(
    float* __restrict__ qb, float* __restrict__ kb, const int* __restrict__ q_pos)
{
  int gid = blockIdx.x * 256 + threadIdx.x;   // NQ*NH*64
  int d = gid & 63;
  int h = (gid >> 6) & 15;
  int i = gid >> 10;
  int p = q_pos[i];
  double ang = (double)p * exp((double)d * -0.14391156831212787);
  float c = (float)cos(ang), s = (float)sin(ang);
  size_t ia = (size_t)i * H_ + h * HD_ + d;
  size_t ib = ia + 64;
  float qa = qb[ia], qbv = qb[ib];
  qb[ia] = qa * c - qbv * s;
  qb[ib] = qbv * c + qa * s;
  float ka = kb[ia], kbv = kb[ib];
  kb[ia] = ka * c - kbv * s;
  kb[ib] = kbv * c + ka * s;
}

// ---------------- K (hi/lo) + V^T (hi) bf16 planes ----------------
// kh/kl: [NH][NK][HD]; vth: [NH][HD][NK].  grid = (NK/64, NH)
__global__ __launch_bounds__(256) void fill_kv_planes(
    const float* __restrict__ kcache, const float* __restrict__ vcache,
    const float* __restrict__ kb, const float* __restrict__ vb,
    const int* __restrict__ kv_idxs,
    ushort* __restrict__ kh, ushort* __restrict__ kl,
    ushort* __restrict__ vth)
{
  __shared__ float vt[64][133];
  const int h = blockIdx.y;
  const int kbase = blockIdx.x * 64;
  const int t = threadIdx.x;
  #pragma unroll
  for (int r = 0; r < 8; ++r) {
    int idx = t + 256 * r;                     // 2048 float4
    int key = idx >> 5, d4 = idx & 31;
    int j = kbase + key;
    float4 kv, vv;
    if (j < NKV) {
      int tok = kv_idxs[j];
      size_t src = ((size_t)h * S_ + tok) * 32 + d4;
      kv = ((const float4*)kcache)[src];
      vv = ((const float4*)vcache)[src];
    } else {
      int i = j - NKV;
      size_t src = (size_t)i * 512 + h * 32 + d4;
      kv = ((const float4*)kb)[src];
      vv = ((const float4*)vb)[src];
    }
    ushort4 hh, ll;
    hh.x = f2bf(kv.x); ll.x = f2bf(kv.x - bf2f(hh.x));
    hh.y = f2bf(kv.y); ll.y = f2bf(kv.y - bf2f(hh.y));
    hh.z = f2bf(kv.z); ll.z = f2bf(kv.z - bf2f(hh.z));
    hh.w = f2bf(kv.w); ll.w = f2bf(kv.w - bf2f(hh.w));
    size_t dst = ((size_t)(h * NK_ + j)) * 128 + d4 * 4;
    *(ushort4*)(kh + dst) = hh;
    *(ushort4*)(kl + dst) = ll;
    vt[key][d4 * 4 + 0] = vv.x; vt[key][d4 * 4 + 1] = vv.y;
    vt[key][d4 * 4 + 2] = vv.z; vt[key][d4 * 4 + 3] = vv.w;
  }
  __syncthreads();
  #pragma unroll
  for (int r = 0; r < 8; ++r) {
    int idx = t + 256 * r;                     // 2048 groups of 4 keys
    int d = idx >> 4, kq = (idx & 15) * 4;
    float v0 = vt[kq + 0][d], v1 = vt[kq + 1][d], v2 = vt[kq + 2][d], v3 = vt[kq + 3][d];
    ushort4 hh;
    hh.x = f2bf(v0); hh.y = f2bf(v1); hh.z = f2bf(v2); hh.w = f2bf(v3);
    size_t dst = ((size_t)(h * 128 + d)) * NK_ + kbase + kq;
    *(ushort4*)(vth + dst) = hh;
  }
}

// ---------------- MFMA flash attention ----------------
// Flat grid 512, XCD-affine heads + balanced q-block pairing (round 2 design).
// ctx written as TILED bf16 hi/lo planes (A-operand of the wo GEMM).
union FlashLDS {
  struct { ushort K[2][64][136]; ushort V[128][72]; int kps[64]; } s;
  struct { float acc[2][32][128]; float ml[2][2][32]; } m;
};

__global__ __launch_bounds__(256, 3) void flash_mfma(
    const float* __restrict__ qb, const ushort* __restrict__ khg,
    const ushort* __restrict__ klg, const ushort* __restrict__ vthg,
    const int* __restrict__ q_pos, const int* __restrict__ k_pos,
    ushort* __restrict__ ctxh, ushort* __restrict__ ctxl)
{
  __shared__ FlashLDS U;
  const int b = blockIdx.x;
  const int half = b >> 8, r_ = b & 255;
  const int h = (r_ & 7) * 2 + ((r_ >> 3) & 1);
  const int q16 = r_ >> 4;
  const int q0 = (half ? (31 - 2 * q16) : (2 * q16)) * 64;
  const int t = threadIdx.x;
  const int w = t >> 6, lane = t & 63;
  const int wq = w & 1, wk = w >> 1;
  const int kg = lane >> 5;
  const int qc = lane & 31;
  const int qi = q0 + wq * 32 + qc;
  const float scale = 0.08838834764831844f;    // 1/sqrt(128)

  bf16x8 qh[8], ql[8];
  {
    const float4* q4 = (const float4*)qb;
    #pragma unroll
    for (int s = 0; s < 8; ++s) {
      size_t a = (size_t)qi * 512 + h * 32 + s * 4 + kg * 2;
      float4 f0 = q4[a], f1 = q4[a + 1];
      float f[8] = {f0.x, f0.y, f0.z, f0.w, f1.x, f1.y, f1.z, f1.w};
      union { ushort u[8]; bf16x8 v; } Hq, Lq;
      #pragma unroll
      for (int j = 0; j < 8; ++j) {
        float qs = f[j] * scale;
        ushort hh = f2bf(qs);
        Hq.u[j] = hh; Lq.u[j] = f2bf(qs - bf2f(hh));
      }
      qh[s] = Hq.v; ql[s] = Lq.v;
    }
  }
  const int qp = q_pos[qi];
  const int wave_qmin = __shfl(qp, 0);
  const int wave_qmax = __shfl(qp, 31);
  const int bqmax = q_pos[q0 + 63];

  f32x16 acc[4];
  #pragma unroll
  for (int f = 0; f < 4; ++f)
    #pragma unroll
    for (int r = 0; r < 16; ++r) acc[f][r] = 0.f;
  float m_run = -INFINITY, l_run = 0.f;

  for (int kt = 0; kt < NK_ / 64; ++kt) {
    const int kbase = kt * 64;
    if (k_pos[kbase] > bqmax) continue;        // block-uniform causal skip
    #pragma unroll
    for (int r = 0; r < 8; ++r) {
      int idx = t + 256 * r;
      int p = idx >> 10, rem = idx & 1023;
      int key = rem >> 4, c8 = (rem & 15) * 8;
      const ushort* src = (p ? klg : khg) + ((size_t)(h * NK_ + kbase + key) * 128 + c8);
      *(uint4*)(&U.s.K[p][key][c8]) = *(const uint4*)src;
    }
    #pragma unroll
    for (int r = 0; r < 4; ++r) {
      int idx = t + 256 * r;
      int d = idx >> 3, c8 = (idx & 7) * 8;
      const ushort* src = vthg + ((size_t)(h * 128 + d) * NK_ + kbase + c8);
      *(uint4*)(&U.s.V[d][c8]) = *(const uint4*)src;
    }
    if (t < 64) U.s.kps[t] = k_pos[kbase + t];
    __syncthreads();

    const int kpmin_half = U.s.kps[wk * 32];
    if (kpmin_half <= wave_qmax) {
      const bool needmask = (U.s.kps[wk * 32 + 31] > wave_qmin);
      f32x16 sA, sB;
      #pragma unroll
      for (int r = 0; r < 16; ++r) { sA[r] = 0.f; sB[r] = 0.f; }
      __builtin_amdgcn_s_setprio(1);
      #pragma unroll
      for (int s = 0; s < 8; ++s) {
        const int co = s * 16 + kg * 8;
        bf16x8 khf = *(const bf16x8*)(&U.s.K[0][wk * 32 + qc][co]);
        bf16x8 klf = *(const bf16x8*)(&U.s.K[1][wk * 32 + qc][co]);
        sA = __builtin_amdgcn_mfma_f32_32x32x16_bf16(khf, qh[s], sA, 0, 0, 0);
        sB = __builtin_amdgcn_mfma_f32_32x32x16_bf16(khf, ql[s], sB, 0, 0, 0);
        sB = __builtin_amdgcn_mfma_f32_32x32x16_bf16(klf, qh[s], sB, 0, 0, 0);
      }
      __builtin_amdgcn_s_setprio(0);
      float sc[16];
      #pragma unroll
      for (int r = 0; r < 16; ++r) sc[r] = sA[r] + sB[r];
      if (needmask) {
        #pragma unroll
        for (int r = 0; r < 16; ++r) {
          int kloc = wk * 32 + (r & 3) + 8 * (r >> 2) + 4 * kg;
          sc[r] = (U.s.kps[kloc] <= qp) ? sc[r] : -INFINITY;
        }
      }
      float mloc = sc[0];
      #pragma unroll
      for (int r = 1; r < 16; ++r) mloc = fmaxf(mloc, sc[r]);
      mloc = fmaxf(mloc, __shfl_xor(mloc, 32));
      float m_new = fmaxf(m_run, mloc);
      float mexp = (m_new == -INFINITY) ? 0.f : m_new;
      if (__any(m_new > m_run)) {
        float aa = __expf(m_run - mexp);
        l_run *= aa;
        #pragma unroll
        for (int f = 0; f < 4; ++f)
          #pragma unroll
          for (int r = 0; r < 16; ++r) acc[f][r] *= aa;
      }
      m_run = m_new;
      float p[16]; float psum = 0.f;
      #pragma unroll
      for (int r = 0; r < 16; ++r) { p[r] = __expf(sc[r] - mexp); psum += p[r]; }
      psum += __shfl_xor(psum, 32);
      l_run += psum;
      bf16x8 pfh[2], pfl[2];
      #pragma unroll
      for (int sl = 0; sl < 2; ++sl) {
        const float* pp = p + sl * 8;
        unsigned a0 = cvt_pk_bf16(pp[0], pp[1]);
        unsigned a1 = cvt_pk_bf16(pp[2], pp[3]);
        unsigned b0 = cvt_pk_bf16(pp[4], pp[5]);
        unsigned b1 = cvt_pk_bf16(pp[6], pp[7]);
        unsigned a0x = (unsigned)__shfl_xor((int)a0, 32);
        unsigned a1x = (unsigned)__shfl_xor((int)a1, 32);
        unsigned b0x = (unsigned)__shfl_xor((int)b0, 32);
        unsigned b1x = (unsigned)__shfl_xor((int)b1, 32);
        union { unsigned wd[4]; bf16x8 v; } PH, PL;
        PH.wd[0] = kg ? b0x : a0;
        PH.wd[1] = kg ? b1x : a1;
        PH.wd[2] = kg ? b0 : a0x;
        PH.wd[3] = kg ? b1 : a1x;
        float r0 = pp[0] - bflo(a0), r1 = pp[1] - bfhi(a0);
        float r2 = pp[2] - bflo(a1), r3 = pp[3] - bfhi(a1);
        float r4 = pp[4] - bflo(b0), r5 = pp[5] - bfhi(b0);
        float r6 = pp[6] - bflo(b1), r7 = pp[7] - bfhi(b1);
        unsigned c0 = cvt_pk_bf16(r0, r1);
        unsigned c1 = cvt_pk_bf16(r2, r3);
        unsigned d0 = cvt_pk_bf16(r4, r5);
        unsigned d1 = cvt_pk_bf16(r6, r7);
        unsigned c0x = (unsigned)__shfl_xor((int)c0, 32);
        unsigned c1x = (unsigned)__shfl_xor((int)c1, 32);
        unsigned d0x = (unsigned)__shfl_xor((int)d0, 32);
        unsigned d1x = (unsigned)__shfl_xor((int)d1, 32);
        PL.wd[0] = kg ? d0x : c0;
        PL.wd[1] = kg ? d1x : c1;
        PL.wd[2] = kg ? d0 : c0x;
        PL.wd[3] = kg ? d1 : c1x;
        pfh[sl] = PH.v; pfl[sl] = PL.v;
      }
      __builtin_amdgcn_s_setprio(1);
      #pragma unroll
      for (int ks = 0; ks < 2; ++ks) {
        const int kc = wk * 32 + ks * 16 + kg * 8;
        bf16x8 vh0 = *(const bf16x8*)(&U.s.V[0 * 32 + qc][kc]);
        bf16x8 vh1 = *(const bf16x8*)(&U.s.V[1 * 32 + qc][kc]);
        bf16x8 vh2 = *(const bf16x8*)(&U.s.V[2 * 32 + qc][kc]);
        bf16x8 vh3 = *(const bf16x8*)(&U.s.V[3 * 32 + qc][kc]);
        acc[0] = __builtin_amdgcn_mfma_f32_32x32x16_bf16(vh0, pfh[ks], acc[0], 0, 0, 0);
        acc[1] = __builtin_amdgcn_mfma_f32_32x32x16_bf16(vh1, pfh[ks], acc[1], 0, 0, 0);
        acc[2] = __builtin_amdgcn_mfma_f32_32x32x16_bf16(vh2, pfh[ks], acc[2], 0, 0, 0);
        acc[3] = __builtin_amdgcn_mfma_f32_32x32x16_bf16(vh3, pfh[ks], acc[3], 0, 0, 0);
        acc[0] = __builtin_amdgcn_mfma_f32_32x32x16_bf16(vh0, pfl[ks], acc[0], 0, 0, 0);
        acc[1] = __builtin_amdgcn_mfma_f32_32x32x16_bf16(vh1, pfl[ks], acc[1], 0, 0, 0);
        acc[2] = __builtin_amdgcn_mfma_f32_32x32x16_bf16(vh2, pfl[ks], acc[2], 0, 0, 0);
        acc[3] = __builtin_amdgcn_mfma_f32_32x32x16_bf16(vh3, pfl[ks], acc[3], 0, 0, 0);
      }
      __builtin_amdgcn_s_setprio(0);
    }
    __syncthreads();
  }

  if (wk == 1) {
    #pragma unroll
    for (int f = 0; f < 4; ++f)
      #pragma unroll
      for (int rq = 0; rq < 4; ++rq) {
        float4 v;
        v.x = acc[f][rq * 4 + 0]; v.y = acc[f][rq * 4 + 1];
        v.z = acc[f][rq * 4 + 2]; v.w = acc[f][rq * 4 + 3];
        *(float4*)(&U.m.acc[wq][qc][f * 32 + kg * 4 + rq * 8]) = v;
      }
    if (kg == 0) { U.m.ml[wq][0][qc] = m_run; U.m.ml[wq][1][qc] = l_run; }
  }
  __syncthreads();
  if (wk == 0) {
    float m2 = U.m.ml[wq][0][qc];
    float l2 = U.m.ml[wq][1][qc];
    float mm = fmaxf(m_run, m2);
    float a1 = __expf(m_run - mm);
    float a2 = __expf(m2 - mm);
    float inv = 1.f / (l_run * a1 + l2 * a2);
    #pragma unroll
    for (int f = 0; f < 4; ++f)
      #pragma unroll
      for (int rq = 0; rq < 4; ++rq) {
        float4 oth = *(const float4*)(&U.m.acc[wq][qc][f * 32 + kg * 4 + rq * 8]);
        float o[4];
        o[0] = (acc[f][rq * 4 + 0] * a1 + oth.x * a2) * inv;
        o[1] = (acc[f][rq * 4 + 1] * a1 + oth.y * a2) * inv;
        o[2] = (acc[f][rq * 4 + 2] * a1 + oth.z * a2) * inv;
        o[3] = (acc[f][rq * 4 + 3] * a1 + oth.w * a2) * inv;
        ushort4 hh, ll;
        hh.x = f2bf(o[0]); ll.x = f2bf(o[0] - bf2f(hh.x));
        hh.y = f2bf(o[1]); ll.y = f2bf(o[1] - bf2f(hh.y));
        hh.z = f2bf(o[2]); ll.z = f2bf(o[2] - bf2f(hh.z));
        hh.w = f2bf(o[3]); ll.w = f2bf(o[3] - bf2f(hh.w));
        int d = h * 128 + f * 32 + kg * 4 + rq * 8;
        size_t oidx = tileoff(qi, d, H_);
        *(ushort4*)(ctxh + oidx) = hh;
        *(ushort4*)(ctxl + oidx) = ll;
      }
  }
}

// ---------------- cache scatter outputs ----------------
__global__ __launch_bounds__(256) void write_kv(
    const float* __restrict__ kcache, const float* __restrict__ vcache,
    const float* __restrict__ kb, const float* __restrict__ vb,
    const int* __restrict__ in_hs, const int* __restrict__ map_full,
    float* __restrict__ kc_o, float* __restrict__ vc_o)
{
  int gid = blockIdx.x * 256 + threadIdx.x;   // NH*S*HD/4
  int d4 = gid & 31;
  int s  = (gid >> 5) & (S_ - 1);
  int h  = gid >> 17;
  float4 kv, vv;
  if (in_hs[s]) {
    int i = map_full[s];
    size_t src = (size_t)i * (H_ / 4) + h * 32 + d4;
    kv = ((const float4*)kb)[src];
    vv = ((const float4*)vb)[src];
  } else {
    kv = ((const float4*)kcache)[gid];
    vv = ((const float4*)vcache)[gid];
  }
  ((float4*)kc_o)[gid] = kv;
  ((float4*)vc_o)[gid] = vv;
}

__global__ __launch_bounds__(256) void aux_write(
    const float* __restrict__ outb, const float* __restrict__ auxc,
    const int* __restrict__ pruned_bit, const int* __restrict__ aux_bit,
    const int* __restrict__ map_full, float* __restrict__ aux_o)
{
  int gid = blockIdx.x * 256 + threadIdx.x;   // S*H/4
  int c4 = gid & 511;
  int s  = gid >> 9;
  float4 v;
  if (pruned_bit[s] && !aux_bit[s])
    v = ((const float4*)outb)[(size_t)map_full[s] * 512 + c4];
  else
    v = ((const float4*)auxc)[gid];
  ((float4*)aux_o)[gid] = v;
}

// ---------------- host ----------------
extern "C" void kernel_launch(void* const* d_in, const int* in_sizes, int n_in,
                              void* d_out, int out_size, void* d_ws, size_t ws_size,
                              hipStream_t stream) {
  (void)in_sizes; (void)n_in; (void)out_size; (void)ws_size;
  const float* hidden  = (const float*)d_in[0];
  const float* kcache  = (const float*)d_in[1];
  const float* vcache  = (const float*)d_in[2];
  const float* auxc    = (const float*)d_in[3];
  const int* kv_idxs   = (const int*)d_in[4];
  const int* aux_idxs  = (const int*)d_in[5];
  const int* new_idxs  = (const int*)d_in[6];
  const int* positions = (const int*)d_in[7];
  const float* wq      = (const float*)d_in[8];
  const float* wk      = (const float*)d_in[9];
  const float* wv      = (const float*)d_in[10];
  const float* wo      = (const float*)d_in[11];
  const float* w_gate  = (const float*)d_in[12];
  const float* w_up    = (const float*)d_in[13];
  const float* w_down  = (const float*)d_in[14];
  const float* ln1     = (const float*)d_in[15];
  const float* ln2     = (const float*)d_in[16];

  float* out_o = (float*)d_out;
  float* kc_o  = out_o + (size_t)NQ_ * H_;
  float* vc_o  = kc_o + (size_t)NH_ * S_ * HD_;
  float* aux_o = vc_o + (size_t)NH_ * S_ * HD_;

  // workspace (units of M4 = 4M floats = 16.78 MB), 11 slots + ints:
  //  0: hs(f32)                      [live until wo-GEMM]
  //  1: xh|xl tiled bf16 planes      [QKV phase; rewritten for FFN]
  //  2: qb  3: kb  4: vb (f32)       [FFN: act f32 spans 2-5]
  //  5-6: QKV fused B-hi planes bt3_h (25.2MB)   [later: khp(5), klp(6)]
  //  7: vthp                          [FFN: btg_h spans 6-7]
  //  8: ctxh|ctxl tiled planes        [FFN: btg_l spans 8-9]
  //  8-9 (QKV phase): bt3_l (25.2MB)
  //  9: wo weight planes bt_h|bt_l
  //  10: hs2 (f32)
  float* W = (float*)d_ws;
  const size_t M4 = 4194304;                  // NQ*H
  float* hs    = W;
  ushort* xh   = (ushort*)(W + 1 * M4);
  ushort* xl   = xh + (size_t)NQ_ * H_;
  float* qb    = W + 2 * M4;
  float* kb    = W + 3 * M4;
  float* vb    = W + 4 * M4;
  ushort* bt3_h = (ushort*)(W + 5 * M4);      // 3*H*H ushorts = 25.2MB (slots 5-6)
  ushort* bt3_l = (ushort*)(W + 8 * M4);      // slots 8-9 (QKV phase only)
  ushort* khp  = (ushort*)(W + 5 * M4);
  ushort* klp  = (ushort*)(W + 6 * M4);
  ushort* vthp = (ushort*)(W + 7 * M4);
  ushort* ctxh = (ushort*)(W + 8 * M4);
  ushort* ctxl = ctxh + (size_t)NQ_ * H_;
  ushort* bt_h = (ushort*)(W + 9 * M4);
  ushort* bt_l = bt_h + (size_t)H_ * H_;
  float* hs2   = W + 10 * M4;
  float* act   = W + 2 * M4;                  // slots 2-5 (FFN phase)
  ushort* btg_h = (ushort*)(W + 6 * M4);      // slots 6-7
  ushort* btg_l = (ushort*)(W + 8 * M4);      // slots 8-9
  int* ip = (int*)(W + 11 * M4);
  int* hs_idxs = ip;           ip += NQ_;
  int* q_pos   = ip;           ip += NQ_;
  int* key_tok = ip;           ip += NK_;
  int* k_pos   = ip;           ip += NK_;
  int* map_full= ip;           ip += S_;
  int* in_hs   = ip;           ip += S_;
  int* aux_bit = ip;           ip += S_;
  int* pruned  = ip;           ip += S_;
  int* last_hs = ip;           ip += 4;

  prep_build<<<16, 256, 0, stream>>>(kv_idxs, aux_idxs, new_idxs, positions,
      hs_idxs, q_pos, key_tok, k_pos, map_full, in_hs, aux_bit, pruned, last_hs);
  prep_scatter<<<10, 256, 0, stream>>>(hs_idxs, aux_idxs, map_full, in_hs, aux_bit);
  prune_set<<<2, 256, 0, stream>>>(kv_idxs, pruned);
  build_hs<<<4096, 256, 0, stream>>>(hidden, auxc, aux_idxs, hs);
  rmsnorm_split<<<NQ_, 256, 0, stream>>>(hs, ln1, xh, xl);

  const dim3 gTH(H_ / 64, H_ / 64);
  // QKV fused: B = concat(wq,wk,wv) panels, N = 6144, epi 3 de-concats C.
  wsplit_t<<<gTH, 256, 0, stream>>>(wq, bt3_h,                      bt3_l,                      H_, H_);
  wsplit_t<<<gTH, 256, 0, stream>>>(wk, bt3_h + (size_t)H_ * H_,    bt3_l + (size_t)H_ * H_,    H_, H_);
  wsplit_t<<<gTH, 256, 0, stream>>>(wv, bt3_h + (size_t)2 * H_ * H_, bt3_l + (size_t)2 * H_ * H_, H_, H_);
  gemm_mfma<<<768, 256, 0, stream>>>(xh, xl, nullptr, bt3_h, bt3_l, qb, nullptr, NQ_, 3 * H_, H_, 3);

  rope_k<<<8192, 256, 0, stream>>>(qb, kb, q_pos);
  fill_kv_planes<<<dim3(64, 16), 256, 0, stream>>>(kcache, vcache, kb, vb, kv_idxs,
      khp, klp, vthp);

  flash_mfma<<<512, 256, 0, stream>>>(qb, khp, klp, vthp, q_pos, k_pos, ctxh, ctxl);
  write_kv<<<8192, 256, 0, stream>>>(kcache, vcache, kb, vb, in_hs, map_full, kc_o, vc_o);

  wsplit_t<<<gTH, 256, 0, stream>>>(wo, bt_h, bt_l, H_, H_);
  gemm_mfma<<<256, 256, 0, stream>>>(ctxh, ctxl, nullptr, bt_h, bt_l, hs2, hs, NQ_, H_, H_, 1);
  rmsnorm_split<<<NQ_, 256, 0, stream>>>(hs2, ln2, xh, xl);

  wsplit_t<<<dim3(FF_ / 64, H_ / 64), 256, 0, stream>>>(w_gate, btg_h, btg_l, H_, FF_);
  gemm_mfma<<<1024, 256, 0, stream>>>(xh, xl, nullptr, btg_h, btg_l, act, nullptr, NQ_, FF_, H_, 0);
  wsplit_t<<<dim3(FF_ / 64, H_ / 64), 256, 0, stream>>>(w_up, btg_h, btg_l, H_, FF_);
  gemm_mfma<<<1024, 256, 0, stream>>>(xh, xl, nullptr, btg_h, btg_l, act, act, NQ_, FF_, H_, 2);
  wsplit_t<<<dim3(H_ / 64, FF_ / 64), 256, 0, stream>>>(w_down, btg_h, btg_l, FF_, H_);
  gemm_mfma<<<256, 256, 0, stream>>>(nullptr, nullptr, act, btg_h, btg_l, out_o, hs2, NQ_, H_, FF_, 1);

  aux_write<<<8192, 256, 0, stream>>>(out_o, auxc, pruned, aux_bit, map_full, aux_o);
}

// Round 5
// 1491.798 us; speedup vs baseline: 3.4145x; 1.0817x over previous
//
#include <hip/hip_runtime.h>
#include <math.h>

// ---------------- problem constants ----------------
constexpr int S_    = 4096;
constexpr int NKV   = 2048;
constexpr int NAUX  = 512;
constexpr int NNEW  = 1536;
constexpr int H_    = 2048;
constexpr int NH_   = 16;
constexpr int HD_   = 128;
constexpr int FF_   = 8192;
constexpr int NQ_   = 2048;   // NNEW + NAUX
constexpr int NK_   = 4096;   // NKV + NQ
constexpr int PRUNE = 409;
constexpr float EPSF = 1e-6f;

typedef __attribute__((ext_vector_type(8))) short bf16x8;
typedef __attribute__((ext_vector_type(16))) float f32x16;

__device__ __forceinline__ ushort f2bf(float x) {
  union { float f; unsigned u; } a; a.f = x;
  unsigned r = a.u + 0x7fffu + ((a.u >> 16) & 1u);
  return (ushort)(r >> 16);
}
__device__ __forceinline__ float bf2f(ushort h) {
  union { unsigned u; float f; } a; a.u = ((unsigned)h) << 16;
  return a.f;
}
__device__ __forceinline__ unsigned cvt_pk_bf16(float a, float b) {
  unsigned r;
  asm("v_cvt_pk_bf16_f32 %0, %1, %2" : "=v"(r) : "v"(a), "v"(b));
  return r;
}
__device__ __forceinline__ float bflo(unsigned w) { union { unsigned u; float f; } x; x.u = w << 16; return x.f; }
__device__ __forceinline__ float bfhi(unsigned w) { union { unsigned u; float f; } x; x.u = w & 0xffff0000u; return x.f; }

// async global->LDS, 16B per lane. LDS dest = base + lane*16 (HW); global src per-lane.
__device__ __forceinline__ void gload16(const ushort* g, ushort* l) {
  __builtin_amdgcn_global_load_lds(
      (const __attribute__((address_space(1))) unsigned int*)g,
      (__attribute__((address_space(3))) unsigned int*)l, 16, 0, 0);
}

// tiled bf16-plane layout: [row>>7][k>>5][(k>>3)&3][row&127][k&7]
// each 128x32 tile = 8KB contiguous = the exact LDS staging image (chunk-major).
__device__ __forceinline__ size_t tileoff(int row, int k, int K) {
  return ((size_t)((row >> 7) * (K >> 5) + (k >> 5)) << 12)
       + (size_t)((((k >> 3) & 3) << 10) + ((row & 127) << 3) + (k & 7));
}

// ---------------- index prep ----------------
__global__ __launch_bounds__(256) void prep_build(
    const int* __restrict__ kv_idxs, const int* __restrict__ aux_idxs,
    const int* __restrict__ new_idxs, const int* __restrict__ positions,
    int* hs_idxs, int* q_pos, int* key_tok, int* k_pos,
    int* map_full, int* in_hs, int* aux_bit, int* pruned_bit, int* last_hs)
{
  int t = blockIdx.x * 256 + threadIdx.x;     // grid covers 4096
  if (t < S_) { map_full[t] = 0; in_hs[t] = 0; aux_bit[t] = 0; pruned_bit[t] = 0; }
  if (t < NQ_) {
    int tok = (t < NNEW) ? new_idxs[t] : aux_idxs[t - NNEW];
    hs_idxs[t] = tok;
    q_pos[t] = positions[tok];
  }
  if (t < NK_) {
    int tok;
    if (t < NKV) tok = kv_idxs[t];
    else { int i = t - NKV; tok = (i < NNEW) ? new_idxs[i] : aux_idxs[i - NNEW]; }
    key_tok[t] = tok;
    k_pos[t] = positions[tok];
  }
  if (t < NNEW && new_idxs[t] == S_ - 1) last_hs[0] = t;
}

__global__ __launch_bounds__(256) void prep_scatter(
    const int* __restrict__ hs_idxs, const int* __restrict__ aux_idxs,
    int* map_full, int* in_hs, int* aux_bit)
{
  int t = blockIdx.x * 256 + threadIdx.x;
  if (t < NQ_) { int tok = hs_idxs[t]; map_full[tok] = t; in_hs[tok] = 1; }
  else if (t < NQ_ + NAUX) { aux_bit[aux_idxs[t - NQ_]] = 1; }
}

// Prune semantics of the reference (bug-compatible): see previous session note.
__global__ __launch_bounds__(256) void prune_set(
    const int* __restrict__ kv_idxs, int* __restrict__ pruned_bit)
{
  int t = blockIdx.x * 256 + threadIdx.x;
  if (t < PRUNE - 1) pruned_bit[kv_idxs[t]] = 1;
  if (t == PRUNE - 1) pruned_bit[S_ - 1] = 1;
}

// ---------------- hs = concat(hidden_states, aux_cache[aux_idxs]) ----------------
__global__ __launch_bounds__(256) void build_hs(
    const float* __restrict__ hidden, const float* __restrict__ auxc,
    const int* __restrict__ aux_idxs, float* __restrict__ hs)
{
  int gid = blockIdx.x * 256 + threadIdx.x;   // NQ*H/4 float4
  int c4 = gid & 511;                          // H/4 = 512
  int i  = gid >> 9;
  const float4* src;
  if (i < NNEW) src = (const float4*)hidden + (size_t)i * 512 + c4;
  else          src = (const float4*)auxc + (size_t)aux_idxs[i - NNEW] * 512 + c4;
  ((float4*)hs)[gid] = *src;
}

// ---------------- rmsnorm -> tiled bf16 hi/lo planes ----------------
__global__ __launch_bounds__(256) void rmsnorm_split(
    const float* __restrict__ in, const float* __restrict__ w,
    ushort* __restrict__ oh, ushort* __restrict__ ol)
{
  int row = blockIdx.x, t = threadIdx.x;
  const float4* r4 = (const float4*)(in + (size_t)row * H_);
  const float4* w4 = (const float4*)w;
  float ss = 0.f;
  float4 v0 = r4[t], v1 = r4[t + 256];
  ss += v0.x*v0.x + v0.y*v0.y + v0.z*v0.z + v0.w*v0.w;
  ss += v1.x*v1.x + v1.y*v1.y + v1.z*v1.z + v1.w*v1.w;
  __shared__ float red[256];
  red[t] = ss; __syncthreads();
  for (int s = 128; s > 0; s >>= 1) { if (t < s) red[t] += red[t + s]; __syncthreads(); }
  float inv = rsqrtf(red[0] / (float)H_ + EPSF);
  float4 wv0 = w4[t], wv1 = w4[t + 256];
  float f[8];
  f[0] = v0.x*inv*wv0.x; f[1] = v0.y*inv*wv0.y; f[2] = v0.z*inv*wv0.z; f[3] = v0.w*inv*wv0.w;
  f[4] = v1.x*inv*wv1.x; f[5] = v1.y*inv*wv1.y; f[6] = v1.z*inv*wv1.z; f[7] = v1.w*inv*wv1.w;
  ushort4 h0, l0, h1, l1;
  h0.x = f2bf(f[0]); l0.x = f2bf(f[0] - bf2f(h0.x));
  h0.y = f2bf(f[1]); l0.y = f2bf(f[1] - bf2f(h0.y));
  h0.z = f2bf(f[2]); l0.z = f2bf(f[2] - bf2f(h0.z));
  h0.w = f2bf(f[3]); l0.w = f2bf(f[3] - bf2f(h0.w));
  h1.x = f2bf(f[4]); l1.x = f2bf(f[4] - bf2f(h1.x));
  h1.y = f2bf(f[5]); l1.y = f2bf(f[5] - bf2f(h1.y));
  h1.z = f2bf(f[6]); l1.z = f2bf(f[6] - bf2f(h1.z));
  h1.w = f2bf(f[7]); l1.w = f2bf(f[7] - bf2f(h1.w));
  size_t o0 = tileoff(row, t * 4, H_);
  size_t o1 = tileoff(row, 1024 + t * 4, H_);
  *(ushort4*)(oh + o0) = h0; *(ushort4*)(ol + o0) = l0;
  *(ushort4*)(oh + o1) = h1; *(ushort4*)(ol + o1) = l1;
}

// ---------------- weight transpose + bf16 hi/lo split (tiled output) ----------------
// W[K][N] f32 -> Th/Tl tiled [N-panel][kstep][chunk][row][8].  grid = (N/64, K/64)
__global__ __launch_bounds__(256) void wsplit_t(
    const float* __restrict__ Wsrc, ushort* __restrict__ Th, ushort* __restrict__ Tl,
    int K, int N)
{
  __shared__ float tile[64][65];
  const int bn = blockIdx.x * 64, bk = blockIdx.y * 64;
  const int t = threadIdx.x;
  #pragma unroll
  for (int r = 0; r < 4; ++r) {
    int idx = t + 256 * r;
    int row = idx >> 4, c = (idx & 15) * 4;
    float4 v = *(const float4*)(Wsrc + (size_t)(bk + row) * N + bn + c);
    tile[row][c] = v.x; tile[row][c+1] = v.y; tile[row][c+2] = v.z; tile[row][c+3] = v.w;
  }
  __syncthreads();
  #pragma unroll
  for (int r = 0; r < 4; ++r) {
    int idx = t + 256 * r;
    int n = bn + (idx >> 4), k = bk + (idx & 15) * 4;
    int kl = k - bk;
    float v0 = tile[kl][n - bn], v1 = tile[kl+1][n - bn], v2 = tile[kl+2][n - bn], v3 = tile[kl+3][n - bn];
    ushort4 h, l;
    h.x = f2bf(v0); l.x = f2bf(v0 - bf2f(h.x));
    h.y = f2bf(v1); l.y = f2bf(v1 - bf2f(h.y));
    h.z = f2bf(v2); l.z = f2bf(v2 - bf2f(h.z));
    h.w = f2bf(v3); l.w = f2bf(v3 - bf2f(h.w));
    size_t off = tileoff(n, k, K);
    *(ushort4*)(Th + off) = h;
    *(ushort4*)(Tl + off) = l;
  }
}

// ---------------- bf16x3 MFMA GEMM, global_load_lds staging ----------------
// A: tiled planes Ah/Al, or f32 Af (split in-flight, chunk-major ds_write).
// B: tiled planes Bh/Bl. C f32 row-major.
// epi: 0 plain, 1 C=X+acc, 2 C=silu(X)*acc, 3 QKV-fused de-concat (N=3*2048).
// 1D grid; XCD x owns an M-slab (A panels L2-resident), B streams via L3.
__global__ __launch_bounds__(256) void gemm_mfma(
    const ushort* __restrict__ Ah, const ushort* __restrict__ Al,
    const float* __restrict__ Af,
    const ushort* __restrict__ Bh, const ushort* __restrict__ Bl,
    float* __restrict__ C, const float* __restrict__ X,
    int M, int N, int K, int epi)
{
  __shared__ __align__(16) ushort sAh[4096];
  __shared__ __align__(16) ushort sAl[4096];
  __shared__ __align__(16) ushort sBh[4096];
  __shared__ __align__(16) ushort sBl[4096];
  const int MB = M >> 7;
  const int cM = MB >> 3;                      // M-panels per XCD
  const int flat = blockIdx.x;
  const int xcd = flat & 7, idxr = flat >> 3;
  const int byi = xcd * cM + (idxr % cM);      // A panel: XCD-resident slab
  const int bxi = idxr / cM;                   // B panel: streamed (L3)
  const int bm = byi * 128, bn = bxi * 128;
  const int t = threadIdx.x;
  const int lane = t & 63;
  const int wid = t >> 6;
  const int wr = wid >> 1, wc = wid & 1;
  const int fr = lane & 31;
  const int kg = lane >> 5;
  const int ub0 = wid * 128;
  const int Ksteps = K >> 5;

  f32x16 acc[2][2];
  #pragma unroll
  for (int mi = 0; mi < 2; ++mi)
    #pragma unroll
    for (int ni = 0; ni < 2; ++ni)
      #pragma unroll
      for (int r = 0; r < 16; ++r) acc[mi][ni][r] = 0.f;

  for (int k0 = 0; k0 < K; k0 += 32) {
    const int ks = k0 >> 5;
    const size_t tB = ((size_t)(bxi * Ksteps + ks)) << 12;
    if (Af) {
      // split-stage A f32 -> chunk-major hi/lo images
      #pragma unroll
      for (int r = 0; r < 2; ++r) {
        int u = t + 256 * r;
        int row = u >> 2, ch = u & 3;
        const float* s0 = Af + (size_t)(bm + row) * K + k0 + ch * 8;
        float4 v0 = *(const float4*)s0, v1 = *(const float4*)(s0 + 4);
        float f[8] = {v0.x,v0.y,v0.z,v0.w,v1.x,v1.y,v1.z,v1.w};
        union { ushort u16[8]; uint4 q; } Hh, Ll;
        #pragma unroll
        for (int j = 0; j < 8; ++j) {
          ushort hh = f2bf(f[j]);
          Hh.u16[j] = hh; Ll.u16[j] = f2bf(f[j] - bf2f(hh));
        }
        *(uint4*)&sAh[ch * 1024 + row * 8] = Hh.q;
        *(uint4*)&sAl[ch * 1024 + row * 8] = Ll.q;
      }
    } else {
      const size_t tA = ((size_t)(byi * Ksteps + ks)) << 12;
      const ushort* a0 = Ah + tA;
      const ushort* a1 = Al + tA;
      gload16(a0 + (size_t)(ub0 + lane) * 8,      sAh + ub0 * 8);
      gload16(a0 + (size_t)(ub0 + 64 + lane) * 8, sAh + (ub0 + 64) * 8);
      gload16(a1 + (size_t)(ub0 + lane) * 8,      sAl + ub0 * 8);
      gload16(a1 + (size_t)(ub0 + 64 + lane) * 8, sAl + (ub0 + 64) * 8);
    }
    {
      const ushort* b0 = Bh + tB;
      const ushort* b1 = Bl + tB;
      gload16(b0 + (size_t)(ub0 + lane) * 8,      sBh + ub0 * 8);
      gload16(b0 + (size_t)(ub0 + 64 + lane) * 8, sBh + (ub0 + 64) * 8);
      gload16(b1 + (size_t)(ub0 + lane) * 8,      sBl + ub0 * 8);
      gload16(b1 + (size_t)(ub0 + 64 + lane) * 8, sBl + (ub0 + 64) * 8);
    }
    __syncthreads();
    #pragma unroll
    for (int ksl = 0; ksl < 2; ++ksl) {
      const int co = (ksl * 2 + kg) * 1024;
      bf16x8 ah[2], al[2], bh[2], bl[2];
      #pragma unroll
      for (int mi = 0; mi < 2; ++mi) {
        ah[mi] = *(const bf16x8*)&sAh[co + (wr * 64 + mi * 32 + fr) * 8];
        al[mi] = *(const bf16x8*)&sAl[co + (wr * 64 + mi * 32 + fr) * 8];
        bh[mi] = *(const bf16x8*)&sBh[co + (wc * 64 + mi * 32 + fr) * 8];
        bl[mi] = *(const bf16x8*)&sBl[co + (wc * 64 + mi * 32 + fr) * 8];
      }
      #pragma unroll
      for (int mi = 0; mi < 2; ++mi)
        #pragma unroll
        for (int ni = 0; ni < 2; ++ni) {
          acc[mi][ni] = __builtin_amdgcn_mfma_f32_32x32x16_bf16(ah[mi], bh[ni], acc[mi][ni], 0, 0, 0);
          acc[mi][ni] = __builtin_amdgcn_mfma_f32_32x32x16_bf16(ah[mi], bl[ni], acc[mi][ni], 0, 0, 0);
          acc[mi][ni] = __builtin_amdgcn_mfma_f32_32x32x16_bf16(al[mi], bh[ni], acc[mi][ni], 0, 0, 0);
        }
    }
    __syncthreads();
  }
  #pragma unroll
  for (int mi = 0; mi < 2; ++mi) {
    #pragma unroll
    for (int ni = 0; ni < 2; ++ni) {
      #pragma unroll
      for (int r = 0; r < 16; ++r) {
        int row = bm + wr * 64 + mi * 32 + (r & 3) + 8 * (r >> 2) + 4 * kg;
        int col = bn + wc * 64 + ni * 32 + fr;
        float v = acc[mi][ni][r];
        size_t idx;
        if (epi == 3) {
          int mtx = col >> 11, cc = col & 2047;
          idx = ((size_t)mtx * M + row) * 2048 + cc;
        } else {
          idx = (size_t)row * N + col;
          if (epi == 1) v += X[idx];
          else if (epi == 2) { float g = X[idx]; v = (g / (1.f + expf(-g))) * v; }
        }
        C[idx] = v;
      }
    }
  }
}

// ---------------- RoPE in-place on q and k ----------------
__global__ __launch_bounds__(256) void rope_k(
    float* __restrict__ qb, float* __restrict__ kb, const int* __restrict__ q_pos)
{
  int gid = blockIdx.x * 256 + threadIdx.x;   // NQ*NH*64
  int d = gid & 63;
  int h = (gid >> 6) & 15;
  int i = gid >> 10;
  int p = q_pos[i];
  double ang = (double)p * exp((double)d * -0.14391156831212787);
  float c = (float)cos(ang), s = (float)sin(ang);
  size_t ia = (size_t)i * H_ + h * HD_ + d;
  size_t ib = ia + 64;
  float qa = qb[ia], qbv = qb[ib];
  qb[ia] = qa * c - qbv * s;
  qb[ib] = qbv * c + qa * s;
  float ka = kb[ia], kbv = kb[ib];
  kb[ia] = ka * c - kbv * s;
  kb[ib] = kbv * c + ka * s;
}

// ---------------- K (hi/lo) + V^T (hi) bf16 planes ----------------
// kh/kl: [NH][NK][HD]; vth: [NH][HD][NK].  grid = (NK/64, NH)
__global__ __launch_bounds__(256) void fill_kv_planes(
    const float* __restrict__ kcache, const float* __restrict__ vcache,
    const float* __restrict__ kb, const float* __restrict__ vb,
    const int* __restrict__ kv_idxs,
    ushort* __restrict__ kh, ushort* __restrict__ kl,
    ushort* __restrict__ vth)
{
  __shared__ float vt[64][133];
  const int h = blockIdx.y;
  const int kbase = blockIdx.x * 64;
  const int t = threadIdx.x;
  #pragma unroll
  for (int r = 0; r < 8; ++r) {
    int idx = t + 256 * r;                     // 2048 float4
    int key = idx >> 5, d4 = idx & 31;
    int j = kbase + key;
    float4 kv, vv;
    if (j < NKV) {
      int tok = kv_idxs[j];
      size_t src = ((size_t)h * S_ + tok) * 32 + d4;
      kv = ((const float4*)kcache)[src];
      vv = ((const float4*)vcache)[src];
    } else {
      int i = j - NKV;
      size_t src = (size_t)i * 512 + h * 32 + d4;
      kv = ((const float4*)kb)[src];
      vv = ((const float4*)vb)[src];
    }
    ushort4 hh, ll;
    hh.x = f2bf(kv.x); ll.x = f2bf(kv.x - bf2f(hh.x));
    hh.y = f2bf(kv.y); ll.y = f2bf(kv.y - bf2f(hh.y));
    hh.z = f2bf(kv.z); ll.z = f2bf(kv.z - bf2f(hh.z));
    hh.w = f2bf(kv.w); ll.w = f2bf(kv.w - bf2f(hh.w));
    size_t dst = ((size_t)(h * NK_ + j)) * 128 + d4 * 4;
    *(ushort4*)(kh + dst) = hh;
    *(ushort4*)(kl + dst) = ll;
    vt[key][d4 * 4 + 0] = vv.x; vt[key][d4 * 4 + 1] = vv.y;
    vt[key][d4 * 4 + 2] = vv.z; vt[key][d4 * 4 + 3] = vv.w;
  }
  __syncthreads();
  #pragma unroll
  for (int r = 0; r < 8; ++r) {
    int idx = t + 256 * r;                     // 2048 groups of 4 keys
    int d = idx >> 4, kq = (idx & 15) * 4;
    float v0 = vt[kq + 0][d], v1 = vt[kq + 1][d], v2 = vt[kq + 2][d], v3 = vt[kq + 3][d];
    ushort4 hh;
    hh.x = f2bf(v0); hh.y = f2bf(v1); hh.z = f2bf(v2); hh.w = f2bf(v3);
    size_t dst = ((size_t)(h * 128 + d)) * NK_ + kbase + kq;
    *(ushort4*)(vth + dst) = hh;
  }
}

// ---------------- MFMA flash attention (barrier-free K-loop) ----------------
// Flat grid 512, XCD-affine heads + balanced q-block pairing.
// No in-loop LDS/staging: each wave loads its K/V MFMA fragments directly
// from global (L2-resident planes). Masks via __shfl of per-lane k_pos.
// ctx written as TILED bf16 hi/lo planes (A-operand of the wo GEMM).
struct MergeLDS { float acc[2][32][128]; float ml[2][2][32]; };

__global__ __launch_bounds__(256, 2) void flash_mfma(
    const float* __restrict__ qb, const ushort* __restrict__ khg,
    const ushort* __restrict__ klg, const ushort* __restrict__ vthg,
    const int* __restrict__ q_pos, const int* __restrict__ k_pos,
    ushort* __restrict__ ctxh, ushort* __restrict__ ctxl)
{
  __shared__ MergeLDS U;
  const int b = blockIdx.x;
  const int half = b >> 8, r_ = b & 255;
  const int h = (r_ & 7) * 2 + ((r_ >> 3) & 1);
  const int q16 = r_ >> 4;
  const int q0 = (half ? (31 - 2 * q16) : (2 * q16)) * 64;
  const int t = threadIdx.x;
  const int w = t >> 6, lane = t & 63;
  const int wq = w & 1, wk = w >> 1;
  const int kg = lane >> 5;
  const int qc = lane & 31;
  const int qi = q0 + wq * 32 + qc;
  const float scale = 0.08838834764831844f;    // 1/sqrt(128)

  bf16x8 qh[8], ql[8];
  {
    const float4* q4 = (const float4*)qb;
    #pragma unroll
    for (int s = 0; s < 8; ++s) {
      size_t a = (size_t)qi * 512 + h * 32 + s * 4 + kg * 2;
      float4 f0 = q4[a], f1 = q4[a + 1];
      float f[8] = {f0.x, f0.y, f0.z, f0.w, f1.x, f1.y, f1.z, f1.w};
      union { ushort u[8]; bf16x8 v; } Hq, Lq;
      #pragma unroll
      for (int j = 0; j < 8; ++j) {
        float qs = f[j] * scale;
        ushort hh = f2bf(qs);
        Hq.u[j] = hh; Lq.u[j] = f2bf(qs - bf2f(hh));
      }
      qh[s] = Hq.v; ql[s] = Lq.v;
    }
  }
  const int qp = q_pos[qi];
  const int wave_qmin = __shfl(qp, 0);
  const int wave_qmax = __shfl(qp, 31);
  const int bqmax = q_pos[q0 + 63];

  // per-wave global bases for this head
  const ushort* kh_base = khg + (size_t)h * NK_ * 128;
  const ushort* kl_base = klg + (size_t)h * NK_ * 128;
  const ushort* vt_base = vthg + (size_t)h * 128 * NK_;

  f32x16 acc[4];
  #pragma unroll
  for (int f = 0; f < 4; ++f)
    #pragma unroll
    for (int r = 0; r < 16; ++r) acc[f][r] = 0.f;
  float m_run = -INFINITY, l_run = 0.f;

  for (int kt = 0; kt < NK_ / 64; ++kt) {
    const int kbase = kt * 64;
    if (k_pos[kbase] > bqmax) continue;        // block-uniform causal skip
    const int krow0 = kbase + wk * 32;         // this wave's 32-key chunk
    // per-lane key positions for this chunk (lane l holds pos of key krow0+(l&31))
    const int kpv = k_pos[krow0 + qc];
    const int kmin = __shfl(kpv, 0);
    if (kmin > wave_qmax) continue;            // wave-uniform skip (finer)
    const bool needmask = (__shfl(kpv, 31) > wave_qmin);

    // ---- QK^T (swapped): S^T = K . Q, K frags direct from global ----
    f32x16 sA, sB;
    #pragma unroll
    for (int r = 0; r < 16; ++r) { sA[r] = 0.f; sB[r] = 0.f; }
    const ushort* krow = kh_base + (size_t)(krow0 + qc) * 128 + kg * 8;
    const ushort* lrow = kl_base + (size_t)(krow0 + qc) * 128 + kg * 8;
    __builtin_amdgcn_s_setprio(1);
    #pragma unroll
    for (int s = 0; s < 8; ++s) {
      bf16x8 khf = *(const bf16x8*)(krow + s * 16);
      bf16x8 klf = *(const bf16x8*)(lrow + s * 16);
      sA = __builtin_amdgcn_mfma_f32_32x32x16_bf16(khf, qh[s], sA, 0, 0, 0);
      sB = __builtin_amdgcn_mfma_f32_32x32x16_bf16(khf, ql[s], sB, 0, 0, 0);
      sB = __builtin_amdgcn_mfma_f32_32x32x16_bf16(klf, qh[s], sB, 0, 0, 0);
    }
    __builtin_amdgcn_s_setprio(0);
    // ---- issue V fragment loads early (hide latency under softmax) ----
    bf16x8 vf[2][4];
    #pragma unroll
    for (int ks = 0; ks < 2; ++ks) {
      const int kc = kbase + wk * 32 + ks * 16 + kg * 8;
      #pragma unroll
      for (int f = 0; f < 4; ++f)
        vf[ks][f] = *(const bf16x8*)(vt_base + (size_t)(f * 32 + qc) * NK_ + kc);
    }
    float sc[16];
    #pragma unroll
    for (int r = 0; r < 16; ++r) sc[r] = sA[r] + sB[r];
    if (needmask) {
      #pragma unroll
      for (int r = 0; r < 16; ++r) {
        int crow = (r & 3) + 8 * (r >> 2) + 4 * kg;
        sc[r] = (__shfl(kpv, crow) <= qp) ? sc[r] : -INFINITY;
      }
    }
    // ---- lane-local online softmax (q = lane column) ----
    float mloc = sc[0];
    #pragma unroll
    for (int r = 1; r < 16; ++r) mloc = fmaxf(mloc, sc[r]);
    mloc = fmaxf(mloc, __shfl_xor(mloc, 32));
    float m_new = fmaxf(m_run, mloc);
    float mexp = (m_new == -INFINITY) ? 0.f : m_new;
    if (__any(m_new > m_run)) {
      float aa = __expf(m_run - mexp);
      l_run *= aa;
      #pragma unroll
      for (int f = 0; f < 4; ++f)
        #pragma unroll
        for (int r = 0; r < 16; ++r) acc[f][r] *= aa;
    }
    m_run = m_new;
    float p[16]; float psum = 0.f;
    #pragma unroll
    for (int r = 0; r < 16; ++r) { p[r] = __expf(sc[r] - mexp); psum += p[r]; }
    psum += __shfl_xor(psum, 32);
    l_run += psum;
    // ---- pack P -> bf16 hi/lo B-fragments (cvt_pk + shfl_xor(32)) ----
    bf16x8 pfh[2], pfl[2];
    #pragma unroll
    for (int sl = 0; sl < 2; ++sl) {
      const float* pp = p + sl * 8;
      unsigned a0 = cvt_pk_bf16(pp[0], pp[1]);
      unsigned a1 = cvt_pk_bf16(pp[2], pp[3]);
      unsigned b0 = cvt_pk_bf16(pp[4], pp[5]);
      unsigned b1 = cvt_pk_bf16(pp[6], pp[7]);
      unsigned a0x = (unsigned)__shfl_xor((int)a0, 32);
      unsigned a1x = (unsigned)__shfl_xor((int)a1, 32);
      unsigned b0x = (unsigned)__shfl_xor((int)b0, 32);
      unsigned b1x = (unsigned)__shfl_xor((int)b1, 32);
      union { unsigned wd[4]; bf16x8 v; } PH, PL;
      PH.wd[0] = kg ? b0x : a0;
      PH.wd[1] = kg ? b1x : a1;
      PH.wd[2] = kg ? b0 : a0x;
      PH.wd[3] = kg ? b1 : a1x;
      float r0 = pp[0] - bflo(a0), r1 = pp[1] - bfhi(a0);
      float r2 = pp[2] - bflo(a1), r3 = pp[3] - bfhi(a1);
      float r4 = pp[4] - bflo(b0), r5 = pp[5] - bfhi(b0);
      float r6 = pp[6] - bflo(b1), r7 = pp[7] - bfhi(b1);
      unsigned c0 = cvt_pk_bf16(r0, r1);
      unsigned c1 = cvt_pk_bf16(r2, r3);
      unsigned d0 = cvt_pk_bf16(r4, r5);
      unsigned d1 = cvt_pk_bf16(r6, r7);
      unsigned c0x = (unsigned)__shfl_xor((int)c0, 32);
      unsigned c1x = (unsigned)__shfl_xor((int)c1, 32);
      unsigned d0x = (unsigned)__shfl_xor((int)d0, 32);
      unsigned d1x = (unsigned)__shfl_xor((int)d1, 32);
      PL.wd[0] = kg ? d0x : c0;
      PL.wd[1] = kg ? d1x : c1;
      PL.wd[2] = kg ? d0 : c0x;
      PL.wd[3] = kg ? d1 : c1x;
      pfh[sl] = PH.v; pfl[sl] = PL.v;
    }
    // ---- PV: ctx^T += V^T . P^T  (V hi plane only) ----
    __builtin_amdgcn_s_setprio(1);
    #pragma unroll
    for (int ks = 0; ks < 2; ++ks) {
      acc[0] = __builtin_amdgcn_mfma_f32_32x32x16_bf16(vf[ks][0], pfh[ks], acc[0], 0, 0, 0);
      acc[1] = __builtin_amdgcn_mfma_f32_32x32x16_bf16(vf[ks][1], pfh[ks], acc[1], 0, 0, 0);
      acc[2] = __builtin_amdgcn_mfma_f32_32x32x16_bf16(vf[ks][2], pfh[ks], acc[2], 0, 0, 0);
      acc[3] = __builtin_amdgcn_mfma_f32_32x32x16_bf16(vf[ks][3], pfh[ks], acc[3], 0, 0, 0);
      acc[0] = __builtin_amdgcn_mfma_f32_32x32x16_bf16(vf[ks][0], pfl[ks], acc[0], 0, 0, 0);
      acc[1] = __builtin_amdgcn_mfma_f32_32x32x16_bf16(vf[ks][1], pfl[ks], acc[1], 0, 0, 0);
      acc[2] = __builtin_amdgcn_mfma_f32_32x32x16_bf16(vf[ks][2], pfl[ks], acc[2], 0, 0, 0);
      acc[3] = __builtin_amdgcn_mfma_f32_32x32x16_bf16(vf[ks][3], pfl[ks], acc[3], 0, 0, 0);
    }
    __builtin_amdgcn_s_setprio(0);
  }

  // ---- merge key-parity halves (wk=1 publishes, wk=0 combines) ----
  if (wk == 1) {
    #pragma unroll
    for (int f = 0; f < 4; ++f)
      #pragma unroll
      for (int rq = 0; rq < 4; ++rq) {
        float4 v;
        v.x = acc[f][rq * 4 + 0]; v.y = acc[f][rq * 4 + 1];
        v.z = acc[f][rq * 4 + 2]; v.w = acc[f][rq * 4 + 3];
        *(float4*)(&U.acc[wq][qc][f * 32 + kg * 4 + rq * 8]) = v;
      }
    if (kg == 0) { U.ml[wq][0][qc] = m_run; U.ml[wq][1][qc] = l_run; }
  }
  __syncthreads();
  if (wk == 0) {
    float m2 = U.ml[wq][0][qc];
    float l2 = U.ml[wq][1][qc];
    float mm = fmaxf(m_run, m2);
    float a1 = __expf(m_run - mm);
    float a2 = __expf(m2 - mm);
    float inv = 1.f / (l_run * a1 + l2 * a2);
    #pragma unroll
    for (int f = 0; f < 4; ++f)
      #pragma unroll
      for (int rq = 0; rq < 4; ++rq) {
        float4 oth = *(const float4*)(&U.acc[wq][qc][f * 32 + kg * 4 + rq * 8]);
        float o[4];
        o[0] = (acc[f][rq * 4 + 0] * a1 + oth.x * a2) * inv;
        o[1] = (acc[f][rq * 4 + 1] * a1 + oth.y * a2) * inv;
        o[2] = (acc[f][rq * 4 + 2] * a1 + oth.z * a2) * inv;
        o[3] = (acc[f][rq * 4 + 3] * a1 + oth.w * a2) * inv;
        ushort4 hh, ll;
        hh.x = f2bf(o[0]); ll.x = f2bf(o[0] - bf2f(hh.x));
        hh.y = f2bf(o[1]); ll.y = f2bf(o[1] - bf2f(hh.y));
        hh.z = f2bf(o[2]); ll.z = f2bf(o[2] - bf2f(hh.z));
        hh.w = f2bf(o[3]); ll.w = f2bf(o[3] - bf2f(hh.w));
        int d = h * 128 + f * 32 + kg * 4 + rq * 8;
        size_t oidx = tileoff(qi, d, H_);
        *(ushort4*)(ctxh + oidx) = hh;
        *(ushort4*)(ctxl + oidx) = ll;
      }
  }
}

// ---------------- cache scatter outputs ----------------
__global__ __launch_bounds__(256) void write_kv(
    const float* __restrict__ kcache, const float* __restrict__ vcache,
    const float* __restrict__ kb, const float* __restrict__ vb,
    const int* __restrict__ in_hs, const int* __restrict__ map_full,
    float* __restrict__ kc_o, float* __restrict__ vc_o)
{
  int gid = blockIdx.x * 256 + threadIdx.x;   // NH*S*HD/4
  int d4 = gid & 31;
  int s  = (gid >> 5) & (S_ - 1);
  int h  = gid >> 17;
  float4 kv, vv;
  if (in_hs[s]) {
    int i = map_full[s];
    size_t src = (size_t)i * (H_ / 4) + h * 32 + d4;
    kv = ((const float4*)kb)[src];
    vv = ((const float4*)vb)[src];
  } else {
    kv = ((const float4*)kcache)[gid];
    vv = ((const float4*)vcache)[gid];
  }
  ((float4*)kc_o)[gid] = kv;
  ((float4*)vc_o)[gid] = vv;
}

__global__ __launch_bounds__(256) void aux_write(
    const float* __restrict__ outb, const float* __restrict__ auxc,
    const int* __restrict__ pruned_bit, const int* __restrict__ aux_bit,
    const int* __restrict__ map_full, float* __restrict__ aux_o)
{
  int gid = blockIdx.x * 256 + threadIdx.x;   // S*H/4
  int c4 = gid & 511;
  int s  = gid >> 9;
  float4 v;
  if (pruned_bit[s] && !aux_bit[s])
    v = ((const float4*)outb)[(size_t)map_full[s] * 512 + c4];
  else
    v = ((const float4*)auxc)[gid];
  ((float4*)aux_o)[gid] = v;
}

// ---------------- host ----------------
extern "C" void kernel_launch(void* const* d_in, const int* in_sizes, int n_in,
                              void* d_out, int out_size, void* d_ws, size_t ws_size,
                              hipStream_t stream) {
  (void)in_sizes; (void)n_in; (void)out_size; (void)ws_size;
  const float* hidden  = (const float*)d_in[0];
  const float* kcache  = (const float*)d_in[1];
  const float* vcache  = (const float*)d_in[2];
  const float* auxc    = (const float*)d_in[3];
  const int* kv_idxs   = (const int*)d_in[4];
  const int* aux_idxs  = (const int*)d_in[5];
  const int* new_idxs  = (const int*)d_in[6];
  const int* positions = (const int*)d_in[7];
  const float* wq      = (const float*)d_in[8];
  const float* wk      = (const float*)d_in[9];
  const float* wv      = (const float*)d_in[10];
  const float* wo      = (const float*)d_in[11];
  const float* w_gate  = (const float*)d_in[12];
  const float* w_up    = (const float*)d_in[13];
  const float* w_down  = (const float*)d_in[14];
  const float* ln1     = (const float*)d_in[15];
  const float* ln2     = (const float*)d_in[16];

  float* out_o = (float*)d_out;
  float* kc_o  = out_o + (size_t)NQ_ * H_;
  float* vc_o  = kc_o + (size_t)NH_ * S_ * HD_;
  float* aux_o = vc_o + (size_t)NH_ * S_ * HD_;

  // workspace (units of M4 = 4M floats = 16.78 MB), 11 slots + ints (round-4 layout)
  float* W = (float*)d_ws;
  const size_t M4 = 4194304;                  // NQ*H
  float* hs    = W;
  ushort* xh   = (ushort*)(W + 1 * M4);
  ushort* xl   = xh + (size_t)NQ_ * H_;
  float* qb    = W + 2 * M4;
  float* kb    = W + 3 * M4;
  float* vb    = W + 4 * M4;
  ushort* bt3_h = (ushort*)(W + 5 * M4);      // 3*H*H ushorts (slots 5-6, QKV phase)
  ushort* bt3_l = (ushort*)(W + 8 * M4);      // slots 8-9 (QKV phase only)
  ushort* khp  = (ushort*)(W + 5 * M4);
  ushort* klp  = (ushort*)(W + 6 * M4);
  ushort* vthp = (ushort*)(W + 7 * M4);
  ushort* ctxh = (ushort*)(W + 8 * M4);
  ushort* ctxl = ctxh + (size_t)NQ_ * H_;
  ushort* bt_h = (ushort*)(W + 9 * M4);
  ushort* bt_l = bt_h + (size_t)H_ * H_;
  float* hs2   = W + 10 * M4;
  float* act   = W + 2 * M4;                  // slots 2-5 (FFN phase)
  ushort* btg_h = (ushort*)(W + 6 * M4);      // slots 6-7
  ushort* btg_l = (ushort*)(W + 8 * M4);      // slots 8-9
  int* ip = (int*)(W + 11 * M4);
  int* hs_idxs = ip;           ip += NQ_;
  int* q_pos   = ip;           ip += NQ_;
  int* key_tok = ip;           ip += NK_;
  int* k_pos   = ip;           ip += NK_;
  int* map_full= ip;           ip += S_;
  int* in_hs   = ip;           ip += S_;
  int* aux_bit = ip;           ip += S_;
  int* pruned  = ip;           ip += S_;
  int* last_hs = ip;           ip += 4;

  prep_build<<<16, 256, 0, stream>>>(kv_idxs, aux_idxs, new_idxs, positions,
      hs_idxs, q_pos, key_tok, k_pos, map_full, in_hs, aux_bit, pruned, last_hs);
  prep_scatter<<<10, 256, 0, stream>>>(hs_idxs, aux_idxs, map_full, in_hs, aux_bit);
  prune_set<<<2, 256, 0, stream>>>(kv_idxs, pruned);
  build_hs<<<4096, 256, 0, stream>>>(hidden, auxc, aux_idxs, hs);
  rmsnorm_split<<<NQ_, 256, 0, stream>>>(hs, ln1, xh, xl);

  const dim3 gTH(H_ / 64, H_ / 64);
  // QKV fused: B = concat(wq,wk,wv) panels, N = 6144, epi 3 de-concats C.
  wsplit_t<<<gTH, 256, 0, stream>>>(wq, bt3_h,                      bt3_l,                      H_, H_);
  wsplit_t<<<gTH, 256, 0, stream>>>(wk, bt3_h + (size_t)H_ * H_,    bt3_l + (size_t)H_ * H_,    H_, H_);
  wsplit_t<<<gTH, 256, 0, stream>>>(wv, bt3_h + (size_t)2 * H_ * H_, bt3_l + (size_t)2 * H_ * H_, H_, H_);
  gemm_mfma<<<768, 256, 0, stream>>>(xh, xl, nullptr, bt3_h, bt3_l, qb, nullptr, NQ_, 3 * H_, H_, 3);

  rope_k<<<8192, 256, 0, stream>>>(qb, kb, q_pos);
  fill_kv_planes<<<dim3(64, 16), 256, 0, stream>>>(kcache, vcache, kb, vb, kv_idxs,
      khp, klp, vthp);

  flash_mfma<<<512, 256, 0, stream>>>(qb, khp, klp, vthp, q_pos, k_pos, ctxh, ctxl);
  write_kv<<<8192, 256, 0, stream>>>(kcache, vcache, kb, vb, in_hs, map_full, kc_o, vc_o);

  wsplit_t<<<gTH, 256, 0, stream>>>(wo, bt_h, bt_l, H_, H_);
  gemm_mfma<<<256, 256, 0, stream>>>(ctxh, ctxl, nullptr, bt_h, bt_l, hs2, hs, NQ_, H_, H_, 1);
  rmsnorm_split<<<NQ_, 256, 0, stream>>>(hs2, ln2, xh, xl);

  wsplit_t<<<dim3(FF_ / 64, H_ / 64), 256, 0, stream>>>(w_gate, btg_h, btg_l, H_, FF_);
  gemm_mfma<<<1024, 256, 0, stream>>>(xh, xl, nullptr, btg_h, btg_l, act, nullptr, NQ_, FF_, H_, 0);
  wsplit_t<<<dim3(FF_ / 64, H_ / 64), 256, 0, stream>>>(w_up, btg_h, btg_l, H_, FF_);
  gemm_mfma<<<1024, 256, 0, stream>>>(xh, xl, nullptr, btg_h, btg_l, act, act, NQ_, FF_, H_, 2);
  wsplit_t<<<dim3(H_ / 64, FF_ / 64), 256, 0, stream>>>(w_down, btg_h, btg_l, FF_, H_);
  gemm_mfma<<<256, 256, 0, stream>>>(nullptr, nullptr, act, btg_h, btg_l, out_o, hs2, NQ_, H_, FF_, 1);

  aux_write<<<8192, 256, 0, stream>>>(out_o, auxc, pruned, aux_bit, map_full, aux_o);
}

// Round 7
// 1296.678 us; speedup vs baseline: 3.9283x; 1.1505x over previous
//
#include <hip/hip_runtime.h>
#include <math.h>

// ---------------- problem constants ----------------
constexpr int S_    = 4096;
constexpr int NKV   = 2048;
constexpr int NAUX  = 512;
constexpr int NNEW  = 1536;
constexpr int H_    = 2048;
constexpr int NH_   = 16;
constexpr int HD_   = 128;
constexpr int FF_   = 8192;
constexpr int NQ_   = 2048;   // NNEW + NAUX
constexpr int NK_   = 4096;   // NKV + NQ
constexpr int PRUNE = 409;
constexpr float EPSF = 1e-6f;

typedef __attribute__((ext_vector_type(8))) short bf16x8;
typedef __attribute__((ext_vector_type(16))) float f32x16;

__device__ __forceinline__ ushort f2bf(float x) {
  union { float f; unsigned u; } a; a.f = x;
  unsigned r = a.u + 0x7fffu + ((a.u >> 16) & 1u);
  return (ushort)(r >> 16);
}
__device__ __forceinline__ float bf2f(ushort h) {
  union { unsigned u; float f; } a; a.u = ((unsigned)h) << 16;
  return a.f;
}
__device__ __forceinline__ unsigned cvt_pk_bf16(float a, float b) {
  unsigned r;
  asm("v_cvt_pk_bf16_f32 %0, %1, %2" : "=v"(r) : "v"(a), "v"(b));
  return r;
}
__device__ __forceinline__ float bflo(unsigned w) { union { unsigned u; float f; } x; x.u = w << 16; return x.f; }
__device__ __forceinline__ float bfhi(unsigned w) { union { unsigned u; float f; } x; x.u = w & 0xffff0000u; return x.f; }

// async global->LDS, 16B per lane. LDS dest = base + lane*16 (HW); global src per-lane.
__device__ __forceinline__ void gload16(const ushort* g, ushort* l) {
  __builtin_amdgcn_global_load_lds(
      (const __attribute__((address_space(1))) unsigned int*)g,
      (__attribute__((address_space(3))) unsigned int*)l, 16, 0, 0);
}

// tiled bf16-plane layout: [row>>7][k>>5][(k>>3)&3][row&127][k&7]
// each 128x32 tile = 8KB contiguous = the exact LDS staging image (chunk-major).
__device__ __forceinline__ size_t tileoff(int row, int k, int K) {
  return ((size_t)((row >> 7) * (K >> 5) + (k >> 5)) << 12)
       + (size_t)((((k >> 3) & 3) << 10) + ((row & 127) << 3) + (k & 7));
}

// ---------------- index prep ----------------
__global__ __launch_bounds__(256) void prep_build(
    const int* __restrict__ kv_idxs, const int* __restrict__ aux_idxs,
    const int* __restrict__ new_idxs, const int* __restrict__ positions,
    int* hs_idxs, int* q_pos, int* key_tok, int* k_pos,
    int* map_full, int* in_hs, int* aux_bit, int* pruned_bit, int* last_hs)
{
  int t = blockIdx.x * 256 + threadIdx.x;     // grid covers 4096
  if (t < S_) { map_full[t] = 0; in_hs[t] = 0; aux_bit[t] = 0; pruned_bit[t] = 0; }
  if (t < NQ_) {
    int tok = (t < NNEW) ? new_idxs[t] : aux_idxs[t - NNEW];
    hs_idxs[t] = tok;
    q_pos[t] = positions[tok];
  }
  if (t < NK_) {
    int tok;
    if (t < NKV) tok = kv_idxs[t];
    else { int i = t - NKV; tok = (i < NNEW) ? new_idxs[i] : aux_idxs[i - NNEW]; }
    key_tok[t] = tok;
    k_pos[t] = positions[tok];
  }
  if (t < NNEW && new_idxs[t] == S_ - 1) last_hs[0] = t;
}

__global__ __launch_bounds__(256) void prep_scatter(
    const int* __restrict__ hs_idxs, const int* __restrict__ aux_idxs,
    int* map_full, int* in_hs, int* aux_bit)
{
  int t = blockIdx.x * 256 + threadIdx.x;
  if (t < NQ_) { int tok = hs_idxs[t]; map_full[tok] = t; in_hs[tok] = 1; }
  else if (t < NQ_ + NAUX) { aux_bit[aux_idxs[t - NQ_]] = 1; }
}

// Prune semantics of the reference (bug-compatible): see previous session note.
__global__ __launch_bounds__(256) void prune_set(
    const int* __restrict__ kv_idxs, int* __restrict__ pruned_bit)
{
  int t = blockIdx.x * 256 + threadIdx.x;
  if (t < PRUNE - 1) pruned_bit[kv_idxs[t]] = 1;
  if (t == PRUNE - 1) pruned_bit[S_ - 1] = 1;
}

// ---------------- hs = concat(hidden_states, aux_cache[aux_idxs]) ----------------
__global__ __launch_bounds__(256) void build_hs(
    const float* __restrict__ hidden, const float* __restrict__ auxc,
    const int* __restrict__ aux_idxs, float* __restrict__ hs)
{
  int gid = blockIdx.x * 256 + threadIdx.x;   // NQ*H/4 float4
  int c4 = gid & 511;                          // H/4 = 512
  int i  = gid >> 9;
  const float4* src;
  if (i < NNEW) src = (const float4*)hidden + (size_t)i * 512 + c4;
  else          src = (const float4*)auxc + (size_t)aux_idxs[i - NNEW] * 512 + c4;
  ((float4*)hs)[gid] = *src;
}

// ---------------- rmsnorm -> tiled bf16 hi/lo planes ----------------
__global__ __launch_bounds__(256) void rmsnorm_split(
    const float* __restrict__ in, const float* __restrict__ w,
    ushort* __restrict__ oh, ushort* __restrict__ ol)
{
  int row = blockIdx.x, t = threadIdx.x;
  const float4* r4 = (const float4*)(in + (size_t)row * H_);
  const float4* w4 = (const float4*)w;
  float ss = 0.f;
  float4 v0 = r4[t], v1 = r4[t + 256];
  ss += v0.x*v0.x + v0.y*v0.y + v0.z*v0.z + v0.w*v0.w;
  ss += v1.x*v1.x + v1.y*v1.y + v1.z*v1.z + v1.w*v1.w;
  __shared__ float red[256];
  red[t] = ss; __syncthreads();
  for (int s = 128; s > 0; s >>= 1) { if (t < s) red[t] += red[t + s]; __syncthreads(); }
  float inv = rsqrtf(red[0] / (float)H_ + EPSF);
  float4 wv0 = w4[t], wv1 = w4[t + 256];
  float f[8];
  f[0] = v0.x*inv*wv0.x; f[1] = v0.y*inv*wv0.y; f[2] = v0.z*inv*wv0.z; f[3] = v0.w*inv*wv0.w;
  f[4] = v1.x*inv*wv1.x; f[5] = v1.y*inv*wv1.y; f[6] = v1.z*inv*wv1.z; f[7] = v1.w*inv*wv1.w;
  ushort4 h0, l0, h1, l1;
  h0.x = f2bf(f[0]); l0.x = f2bf(f[0] - bf2f(h0.x));
  h0.y = f2bf(f[1]); l0.y = f2bf(f[1] - bf2f(h0.y));
  h0.z = f2bf(f[2]); l0.z = f2bf(f[2] - bf2f(h0.z));
  h0.w = f2bf(f[3]); l0.w = f2bf(f[3] - bf2f(h0.w));
  h1.x = f2bf(f[4]); l1.x = f2bf(f[4] - bf2f(h1.x));
  h1.y = f2bf(f[5]); l1.y = f2bf(f[5] - bf2f(h1.y));
  h1.z = f2bf(f[6]); l1.z = f2bf(f[6] - bf2f(h1.z));
  h1.w = f2bf(f[7]); l1.w = f2bf(f[7] - bf2f(h1.w));
  size_t o0 = tileoff(row, t * 4, H_);
  size_t o1 = tileoff(row, 1024 + t * 4, H_);
  *(ushort4*)(oh + o0) = h0; *(ushort4*)(ol + o0) = l0;
  *(ushort4*)(oh + o1) = h1; *(ushort4*)(ol + o1) = l1;
}

// ---------------- weight transpose + bf16 hi/lo split (tiled output) ----------------
// W[K][N] f32 -> Th/Tl tiled [N-panel][kstep][chunk][row][8].  grid = (N/64, K/64)
__global__ __launch_bounds__(256) void wsplit_t(
    const float* __restrict__ Wsrc, ushort* __restrict__ Th, ushort* __restrict__ Tl,
    int K, int N)
{
  __shared__ float tile[64][65];
  const int bn = blockIdx.x * 64, bk = blockIdx.y * 64;
  const int t = threadIdx.x;
  #pragma unroll
  for (int r = 0; r < 4; ++r) {
    int idx = t + 256 * r;
    int row = idx >> 4, c = (idx & 15) * 4;
    float4 v = *(const float4*)(Wsrc + (size_t)(bk + row) * N + bn + c);
    tile[row][c] = v.x; tile[row][c+1] = v.y; tile[row][c+2] = v.z; tile[row][c+3] = v.w;
  }
  __syncthreads();
  #pragma unroll
  for (int r = 0; r < 4; ++r) {
    int idx = t + 256 * r;
    int n = bn + (idx >> 4), k = bk + (idx & 15) * 4;
    int kl = k - bk;
    float v0 = tile[kl][n - bn], v1 = tile[kl+1][n - bn], v2 = tile[kl+2][n - bn], v3 = tile[kl+3][n - bn];
    ushort4 h, l;
    h.x = f2bf(v0); l.x = f2bf(v0 - bf2f(h.x));
    h.y = f2bf(v1); l.y = f2bf(v1 - bf2f(h.y));
    h.z = f2bf(v2); l.z = f2bf(v2 - bf2f(h.z));
    h.w = f2bf(v3); l.w = f2bf(v3 - bf2f(h.w));
    size_t off = tileoff(n, k, K);
    *(ushort4*)(Th + off) = h;
    *(ushort4*)(Tl + off) = l;
  }
}

// ---------------- bf16x3 MFMA GEMM, global_load_lds staging ----------------
// A: tiled planes Ah/Al, or f32 Af (split in-flight, chunk-major ds_write).
// B: tiled planes Bh/Bl. C f32 row-major.
// epi: 0 plain, 1 C=X+acc, 2 C=silu(X)*acc, 3 QKV-fused de-concat (N=3*2048).
// split=1: K halved across grid halves; upper half writes partials to C2 (epi ignored).
// Proven single-buffer __syncthreads loop (benched 1492 us) — only split added.
__global__ __launch_bounds__(256) void gemm_mfma(
    const ushort* __restrict__ Ah, const ushort* __restrict__ Al,
    const float* __restrict__ Af,
    const ushort* __restrict__ Bh, const ushort* __restrict__ Bl,
    float* __restrict__ C, float* __restrict__ C2, const float* __restrict__ X,
    int M, int N, int K, int epi, int split)
{
  __shared__ __align__(16) ushort sAh[4096];
  __shared__ __align__(16) ushort sAl[4096];
  __shared__ __align__(16) ushort sBh[4096];
  __shared__ __align__(16) ushort sBl[4096];
  int flat = blockIdx.x;
  int kbeg = 0, kend = K;
  float* Cout = C;
  if (split) {
    int nb2 = gridDim.x >> 1;
    if (flat >= nb2) { flat -= nb2; Cout = C2; kbeg = K >> 1; }
    else             { kend = K >> 1; }
  }
  const int MB = M >> 7;
  const int cM = MB >> 3;
  const int xcd = flat & 7, idxr = flat >> 3;
  const int byi = xcd * cM + (idxr % cM);      // A panel: XCD-resident slab
  const int bxi = idxr / cM;                   // B panel: streamed (L3)
  const int bm = byi * 128, bn = bxi * 128;
  const int t = threadIdx.x;
  const int lane = t & 63;
  const int wid = t >> 6;
  const int wr = wid >> 1, wc = wid & 1;
  const int fr = lane & 31;
  const int kg = lane >> 5;
  const int ub0 = wid * 128;
  const int Ksteps = K >> 5;

  f32x16 acc[2][2];
  #pragma unroll
  for (int mi = 0; mi < 2; ++mi)
    #pragma unroll
    for (int ni = 0; ni < 2; ++ni)
      #pragma unroll
      for (int r = 0; r < 16; ++r) acc[mi][ni][r] = 0.f;

  for (int k0 = kbeg; k0 < kend; k0 += 32) {
    const int ks = k0 >> 5;
    const size_t tB = ((size_t)(bxi * Ksteps + ks)) << 12;
    if (Af) {
      // split-stage A f32 -> chunk-major hi/lo images
      #pragma unroll
      for (int r = 0; r < 2; ++r) {
        int u = t + 256 * r;
        int row = u >> 2, ch = u & 3;
        const float* s0 = Af + (size_t)(bm + row) * K + k0 + ch * 8;
        float4 v0 = *(const float4*)s0, v1 = *(const float4*)(s0 + 4);
        float f[8] = {v0.x,v0.y,v0.z,v0.w,v1.x,v1.y,v1.z,v1.w};
        union { ushort u16[8]; uint4 q; } Hh, Ll;
        #pragma unroll
        for (int j = 0; j < 8; ++j) {
          ushort hh = f2bf(f[j]);
          Hh.u16[j] = hh; Ll.u16[j] = f2bf(f[j] - bf2f(hh));
        }
        *(uint4*)&sAh[ch * 1024 + row * 8] = Hh.q;
        *(uint4*)&sAl[ch * 1024 + row * 8] = Ll.q;
      }
    } else {
      const size_t tA = ((size_t)(byi * Ksteps + ks)) << 12;
      const ushort* a0 = Ah + tA;
      const ushort* a1 = Al + tA;
      gload16(a0 + (size_t)(ub0 + lane) * 8,      sAh + ub0 * 8);
      gload16(a0 + (size_t)(ub0 + 64 + lane) * 8, sAh + (ub0 + 64) * 8);
      gload16(a1 + (size_t)(ub0 + lane) * 8,      sAl + ub0 * 8);
      gload16(a1 + (size_t)(ub0 + 64 + lane) * 8, sAl + (ub0 + 64) * 8);
    }
    {
      const ushort* b0 = Bh + tB;
      const ushort* b1 = Bl + tB;
      gload16(b0 + (size_t)(ub0 + lane) * 8,      sBh + ub0 * 8);
      gload16(b0 + (size_t)(ub0 + 64 + lane) * 8, sBh + (ub0 + 64) * 8);
      gload16(b1 + (size_t)(ub0 + lane) * 8,      sBl + ub0 * 8);
      gload16(b1 + (size_t)(ub0 + 64 + lane) * 8, sBl + (ub0 + 64) * 8);
    }
    __syncthreads();
    #pragma unroll
    for (int ksl = 0; ksl < 2; ++ksl) {
      const int co = (ksl * 2 + kg) * 1024;
      bf16x8 ah[2], al[2], bh[2], bl[2];
      #pragma unroll
      for (int mi = 0; mi < 2; ++mi) {
        ah[mi] = *(const bf16x8*)&sAh[co + (wr * 64 + mi * 32 + fr) * 8];
        al[mi] = *(const bf16x8*)&sAl[co + (wr * 64 + mi * 32 + fr) * 8];
        bh[mi] = *(const bf16x8*)&sBh[co + (wc * 64 + mi * 32 + fr) * 8];
        bl[mi] = *(const bf16x8*)&sBl[co + (wc * 64 + mi * 32 + fr) * 8];
      }
      #pragma unroll
      for (int mi = 0; mi < 2; ++mi)
        #pragma unroll
        for (int ni = 0; ni < 2; ++ni) {
          acc[mi][ni] = __builtin_amdgcn_mfma_f32_32x32x16_bf16(ah[mi], bh[ni], acc[mi][ni], 0, 0, 0);
          acc[mi][ni] = __builtin_amdgcn_mfma_f32_32x32x16_bf16(ah[mi], bl[ni], acc[mi][ni], 0, 0, 0);
          acc[mi][ni] = __builtin_amdgcn_mfma_f32_32x32x16_bf16(al[mi], bh[ni], acc[mi][ni], 0, 0, 0);
        }
    }
    __syncthreads();
  }
  #pragma unroll
  for (int mi = 0; mi < 2; ++mi) {
    #pragma unroll
    for (int ni = 0; ni < 2; ++ni) {
      #pragma unroll
      for (int r = 0; r < 16; ++r) {
        int row = bm + wr * 64 + mi * 32 + (r & 3) + 8 * (r >> 2) + 4 * kg;
        int col = bn + wc * 64 + ni * 32 + fr;
        float v = acc[mi][ni][r];
        size_t idx;
        if (epi == 3) {
          int mtx = col >> 11, cc = col & 2047;
          idx = ((size_t)mtx * M + row) * 2048 + cc;
        } else {
          idx = (size_t)row * N + col;
          if (!split) {
            if (epi == 1) v += X[idx];
            else if (epi == 2) { float g = X[idx]; v = (g / (1.f + expf(-g))) * v; }
          }
        }
        Cout[idx] = v;
      }
    }
  }
}

// ---------------- out = a + b + x (split-K reduce + residual) ----------------
__global__ __launch_bounds__(256) void reduce3(
    const float* __restrict__ a, const float* __restrict__ b,
    const float* __restrict__ x, float* __restrict__ o)
{
  int g = blockIdx.x * 256 + threadIdx.x;     // NQ*H/4 float4
  float4 va = ((const float4*)a)[g];
  float4 vb = ((const float4*)b)[g];
  float4 vx = ((const float4*)x)[g];
  float4 vo;
  vo.x = va.x + vb.x + vx.x; vo.y = va.y + vb.y + vx.y;
  vo.z = va.z + vb.z + vx.z; vo.w = va.w + vb.w + vx.w;
  ((float4*)o)[g] = vo;
}

// ---------------- RoPE in-place on q and k ----------------
__global__ __launch_bounds__(256) void rope_k(
    float* __restrict__ qb, float* __restrict__ kb, const int* __restrict__ q_pos)
{
  int gid = blockIdx.x * 256 + threadIdx.x;   // NQ*NH*64
  int d = gid & 63;
  int h = (gid >> 6) & 15;
  int i = gid >> 10;
  int p = q_pos[i];
  double ang = (double)p * exp((double)d * -0.14391156831212787);
  float c = (float)cos(ang), s = (float)sin(ang);
  size_t ia = (size_t)i * H_ + h * HD_ + d;
  size_t ib = ia + 64;
  float qa = qb[ia], qbv = qb[ib];
  qb[ia] = qa * c - qbv * s;
  qb[ib] = qbv * c + qa * s;
  float ka = kb[ia], kbv = kb[ib];
  kb[ia] = ka * c - kbv * s;
  kb[ib] = kbv * c + ka * s;
}

// ---------------- K (hi/lo) + V^T (hi) bf16 planes ----------------
// kh/kl: [NH][NK][HD]; vth: [NH][HD][NK].  grid = (NK/64, NH)
__global__ __launch_bounds__(256) void fill_kv_planes(
    const float* __restrict__ kcache, const float* __restrict__ vcache,
    const float* __restrict__ kb, const float* __restrict__ vb,
    const int* __restrict__ kv_idxs,
    ushort* __restrict__ kh, ushort* __restrict__ kl,
    ushort* __restrict__ vth)
{
  __shared__ float vt[64][133];
  const int h = blockIdx.y;
  const int kbase = blockIdx.x * 64;
  const int t = threadIdx.x;
  #pragma unroll
  for (int r = 0; r < 8; ++r) {
    int idx = t + 256 * r;                     // 2048 float4
    int key = idx >> 5, d4 = idx & 31;
    int j = kbase + key;
    float4 kv, vv;
    if (j < NKV) {
      int tok = kv_idxs[j];
      size_t src = ((size_t)h * S_ + tok) * 32 + d4;
      kv = ((const float4*)kcache)[src];
      vv = ((const float4*)vcache)[src];
    } else {
      int i = j - NKV;
      size_t src = (size_t)i * 512 + h * 32 + d4;
      kv = ((const float4*)kb)[src];
      vv = ((const float4*)vb)[src];
    }
    ushort4 hh, ll;
    hh.x = f2bf(kv.x); ll.x = f2bf(kv.x - bf2f(hh.x));
    hh.y = f2bf(kv.y); ll.y = f2bf(kv.y - bf2f(hh.y));
    hh.z = f2bf(kv.z); ll.z = f2bf(kv.z - bf2f(hh.z));
    hh.w = f2bf(kv.w); ll.w = f2bf(kv.w - bf2f(hh.w));
    size_t dst = ((size_t)(h * NK_ + j)) * 128 + d4 * 4;
    *(ushort4*)(kh + dst) = hh;
    *(ushort4*)(kl + dst) = ll;
    vt[key][d4 * 4 + 0] = vv.x; vt[key][d4 * 4 + 1] = vv.y;
    vt[key][d4 * 4 + 2] = vv.z; vt[key][d4 * 4 + 3] = vv.w;
  }
  __syncthreads();
  #pragma unroll
  for (int r = 0; r < 8; ++r) {
    int idx = t + 256 * r;                     // 2048 groups of 4 keys
    int d = idx >> 4, kq = (idx & 15) * 4;
    float v0 = vt[kq + 0][d], v1 = vt[kq + 1][d], v2 = vt[kq + 2][d], v3 = vt[kq + 3][d];
    ushort4 hh;
    hh.x = f2bf(v0); hh.y = f2bf(v1); hh.z = f2bf(v2); hh.w = f2bf(v3);
    size_t dst = ((size_t)(h * 128 + d)) * NK_ + kbase + kq;
    *(ushort4*)(vth + dst) = hh;
  }
}

// ---------------- MFMA flash attention (barrier-free K-loop) ----------------
// Flat grid 512, XCD-affine heads + balanced q-block pairing.
// No in-loop LDS/staging: each wave loads its K/V MFMA fragments directly
// from global (L2-resident planes). Masks via __shfl of per-lane k_pos.
// ctx written as TILED bf16 hi/lo planes (A-operand of the wo GEMM).
struct MergeLDS { float acc[2][32][128]; float ml[2][2][32]; };

__global__ __launch_bounds__(256, 2) void flash_mfma(
    const float* __restrict__ qb, const ushort* __restrict__ khg,
    const ushort* __restrict__ klg, const ushort* __restrict__ vthg,
    const int* __restrict__ q_pos, const int* __restrict__ k_pos,
    ushort* __restrict__ ctxh, ushort* __restrict__ ctxl)
{
  __shared__ MergeLDS U;
  const int b = blockIdx.x;
  const int half = b >> 8, r_ = b & 255;
  const int h = (r_ & 7) * 2 + ((r_ >> 3) & 1);
  const int q16 = r_ >> 4;
  const int q0 = (half ? (31 - 2 * q16) : (2 * q16)) * 64;
  const int t = threadIdx.x;
  const int w = t >> 6, lane = t & 63;
  const int wq = w & 1, wk = w >> 1;
  const int kg = lane >> 5;
  const int qc = lane & 31;
  const int qi = q0 + wq * 32 + qc;
  const float scale = 0.08838834764831844f;    // 1/sqrt(128)

  bf16x8 qh[8], ql[8];
  {
    const float4* q4 = (const float4*)qb;
    #pragma unroll
    for (int s = 0; s < 8; ++s) {
      size_t a = (size_t)qi * 512 + h * 32 + s * 4 + kg * 2;
      float4 f0 = q4[a], f1 = q4[a + 1];
      float f[8] = {f0.x, f0.y, f0.z, f0.w, f1.x, f1.y, f1.z, f1.w};
      union { ushort u[8]; bf16x8 v; } Hq, Lq;
      #pragma unroll
      for (int j = 0; j < 8; ++j) {
        float qs = f[j] * scale;
        ushort hh = f2bf(qs);
        Hq.u[j] = hh; Lq.u[j] = f2bf(qs - bf2f(hh));
      }
      qh[s] = Hq.v; ql[s] = Lq.v;
    }
  }
  const int qp = q_pos[qi];
  const int wave_qmin = __shfl(qp, 0);
  const int wave_qmax = __shfl(qp, 31);
  const int bqmax = q_pos[q0 + 63];

  const ushort* kh_base = khg + (size_t)h * NK_ * 128;
  const ushort* kl_base = klg + (size_t)h * NK_ * 128;
  const ushort* vt_base = vthg + (size_t)h * 128 * NK_;

  f32x16 acc[4];
  #pragma unroll
  for (int f = 0; f < 4; ++f)
    #pragma unroll
    for (int r = 0; r < 16; ++r) acc[f][r] = 0.f;
  float m_run = -INFINITY, l_run = 0.f;

  for (int kt = 0; kt < NK_ / 64; ++kt) {
    const int kbase = kt * 64;
    if (k_pos[kbase] > bqmax) continue;        // block-uniform causal skip
    const int krow0 = kbase + wk * 32;
    const int kpv = k_pos[krow0 + qc];
    const int kmin = __shfl(kpv, 0);
    if (kmin > wave_qmax) continue;            // wave-uniform skip (finer)
    const bool needmask = (__shfl(kpv, 31) > wave_qmin);

    f32x16 sA, sB;
    #pragma unroll
    for (int r = 0; r < 16; ++r) { sA[r] = 0.f; sB[r] = 0.f; }
    const ushort* krow = kh_base + (size_t)(krow0 + qc) * 128 + kg * 8;
    const ushort* lrow = kl_base + (size_t)(krow0 + qc) * 128 + kg * 8;
    __builtin_amdgcn_s_setprio(1);
    #pragma unroll
    for (int s = 0; s < 8; ++s) {
      bf16x8 khf = *(const bf16x8*)(krow + s * 16);
      bf16x8 klf = *(const bf16x8*)(lrow + s * 16);
      sA = __builtin_amdgcn_mfma_f32_32x32x16_bf16(khf, qh[s], sA, 0, 0, 0);
      sB = __builtin_amdgcn_mfma_f32_32x32x16_bf16(khf, ql[s], sB, 0, 0, 0);
      sB = __builtin_amdgcn_mfma_f32_32x32x16_bf16(klf, qh[s], sB, 0, 0, 0);
    }
    __builtin_amdgcn_s_setprio(0);
    bf16x8 vf[2][4];
    #pragma unroll
    for (int ks = 0; ks < 2; ++ks) {
      const int kc = kbase + wk * 32 + ks * 16 + kg * 8;
      #pragma unroll
      for (int f = 0; f < 4; ++f)
        vf[ks][f] = *(const bf16x8*)(vt_base + (size_t)(f * 32 + qc) * NK_ + kc);
    }
    float sc[16];
    #pragma unroll
    for (int r = 0; r < 16; ++r) sc[r] = sA[r] + sB[r];
    if (needmask) {
      #pragma unroll
      for (int r = 0; r < 16; ++r) {
        int crow = (r & 3) + 8 * (r >> 2) + 4 * kg;
        sc[r] = (__shfl(kpv, crow) <= qp) ? sc[r] : -INFINITY;
      }
    }
    float mloc = sc[0];
    #pragma unroll
    for (int r = 1; r < 16; ++r) mloc = fmaxf(mloc, sc[r]);
    mloc = fmaxf(mloc, __shfl_xor(mloc, 32));
    float m_new = fmaxf(m_run, mloc);
    float mexp = (m_new == -INFINITY) ? 0.f : m_new;
    if (__any(m_new > m_run)) {
      float aa = __expf(m_run - mexp);
      l_run *= aa;
      #pragma unroll
      for (int f = 0; f < 4; ++f)
        #pragma unroll
        for (int r = 0; r < 16; ++r) acc[f][r] *= aa;
    }
    m_run = m_new;
    float p[16]; float psum = 0.f;
    #pragma unroll
    for (int r = 0; r < 16; ++r) { p[r] = __expf(sc[r] - mexp); psum += p[r]; }
    psum += __shfl_xor(psum, 32);
    l_run += psum;
    bf16x8 pfh[2], pfl[2];
    #pragma unroll
    for (int sl = 0; sl < 2; ++sl) {
      const float* pp = p + sl * 8;
      unsigned a0 = cvt_pk_bf16(pp[0], pp[1]);
      unsigned a1 = cvt_pk_bf16(pp[2], pp[3]);
      unsigned b0 = cvt_pk_bf16(pp[4], pp[5]);
      unsigned b1 = cvt_pk_bf16(pp[6], pp[7]);
      unsigned a0x = (unsigned)__shfl_xor((int)a0, 32);
      unsigned a1x = (unsigned)__shfl_xor((int)a1, 32);
      unsigned b0x = (unsigned)__shfl_xor((int)b0, 32);
      unsigned b1x = (unsigned)__shfl_xor((int)b1, 32);
      union { unsigned wd[4]; bf16x8 v; } PH, PL;
      PH.wd[0] = kg ? b0x : a0;
      PH.wd[1] = kg ? b1x : a1;
      PH.wd[2] = kg ? b0 : a0x;
      PH.wd[3] = kg ? b1 : a1x;
      float r0 = pp[0] - bflo(a0), r1 = pp[1] - bfhi(a0);
      float r2 = pp[2] - bflo(a1), r3 = pp[3] - bfhi(a1);
      float r4 = pp[4] - bflo(b0), r5 = pp[5] - bfhi(b0);
      float r6 = pp[6] - bflo(b1), r7 = pp[7] - bfhi(b1);
      unsigned c0 = cvt_pk_bf16(r0, r1);
      unsigned c1 = cvt_pk_bf16(r2, r3);
      unsigned d0 = cvt_pk_bf16(r4, r5);
      unsigned d1 = cvt_pk_bf16(r6, r7);
      unsigned c0x = (unsigned)__shfl_xor((int)c0, 32);
      unsigned c1x = (unsigned)__shfl_xor((int)c1, 32);
      unsigned d0x = (unsigned)__shfl_xor((int)d0, 32);
      unsigned d1x = (unsigned)__shfl_xor((int)d1, 32);
      PL.wd[0] = kg ? d0x : c0;
      PL.wd[1] = kg ? d1x : c1;
      PL.wd[2] = kg ? d0 : c0x;
      PL.wd[3] = kg ? d1 : c1x;
      pfh[sl] = PH.v; pfl[sl] = PL.v;
    }
    __builtin_amdgcn_s_setprio(1);
    #pragma unroll
    for (int ks = 0; ks < 2; ++ks) {
      acc[0] = __builtin_amdgcn_mfma_f32_32x32x16_bf16(vf[ks][0], pfh[ks], acc[0], 0, 0, 0);
      acc[1] = __builtin_amdgcn_mfma_f32_32x32x16_bf16(vf[ks][1], pfh[ks], acc[1], 0, 0, 0);
      acc[2] = __builtin_amdgcn_mfma_f32_32x32x16_bf16(vf[ks][2], pfh[ks], acc[2], 0, 0, 0);
      acc[3] = __builtin_amdgcn_mfma_f32_32x32x16_bf16(vf[ks][3], pfh[ks], acc[3], 0, 0, 0);
      acc[0] = __builtin_amdgcn_mfma_f32_32x32x16_bf16(vf[ks][0], pfl[ks], acc[0], 0, 0, 0);
      acc[1] = __builtin_amdgcn_mfma_f32_32x32x16_bf16(vf[ks][1], pfl[ks], acc[1], 0, 0, 0);
      acc[2] = __builtin_amdgcn_mfma_f32_32x32x16_bf16(vf[ks][2], pfl[ks], acc[2], 0, 0, 0);
      acc[3] = __builtin_amdgcn_mfma_f32_32x32x16_bf16(vf[ks][3], pfl[ks], acc[3], 0, 0, 0);
    }
    __builtin_amdgcn_s_setprio(0);
  }

  if (wk == 1) {
    #pragma unroll
    for (int f = 0; f < 4; ++f)
      #pragma unroll
      for (int rq = 0; rq < 4; ++rq) {
        float4 v;
        v.x = acc[f][rq * 4 + 0]; v.y = acc[f][rq * 4 + 1];
        v.z = acc[f][rq * 4 + 2]; v.w = acc[f][rq * 4 + 3];
        *(float4*)(&U.acc[wq][qc][f * 32 + kg * 4 + rq * 8]) = v;
      }
    if (kg == 0) { U.ml[wq][0][qc] = m_run; U.ml[wq][1][qc] = l_run; }
  }
  __syncthreads();
  if (wk == 0) {
    float m2 = U.ml[wq][0][qc];
    float l2 = U.ml[wq][1][qc];
    float mm = fmaxf(m_run, m2);
    float a1 = __expf(m_run - mm);
    float a2 = __expf(m2 - mm);
    float inv = 1.f / (l_run * a1 + l2 * a2);
    #pragma unroll
    for (int f = 0; f < 4; ++f)
      #pragma unroll
      for (int rq = 0; rq < 4; ++rq) {
        float4 oth = *(const float4*)(&U.acc[wq][qc][f * 32 + kg * 4 + rq * 8]);
        float o[4];
        o[0] = (acc[f][rq * 4 + 0] * a1 + oth.x * a2) * inv;
        o[1] = (acc[f][rq * 4 + 1] * a1 + oth.y * a2) * inv;
        o[2] = (acc[f][rq * 4 + 2] * a1 + oth.z * a2) * inv;
        o[3] = (acc[f][rq * 4 + 3] * a1 + oth.w * a2) * inv;
        ushort4 hh, ll;
        hh.x = f2bf(o[0]); ll.x = f2bf(o[0] - bf2f(hh.x));
        hh.y = f2bf(o[1]); ll.y = f2bf(o[1] - bf2f(hh.y));
        hh.z = f2bf(o[2]); ll.z = f2bf(o[2] - bf2f(hh.z));
        hh.w = f2bf(o[3]); ll.w = f2bf(o[3] - bf2f(hh.w));
        int d = h * 128 + f * 32 + kg * 4 + rq * 8;
        size_t oidx = tileoff(qi, d, H_);
        *(ushort4*)(ctxh + oidx) = hh;
        *(ushort4*)(ctxl + oidx) = ll;
      }
  }
}

// ---------------- cache scatter outputs ----------------
__global__ __launch_bounds__(256) void write_kv(
    const float* __restrict__ kcache, const float* __restrict__ vcache,
    const float* __restrict__ kb, const float* __restrict__ vb,
    const int* __restrict__ in_hs, const int* __restrict__ map_full,
    float* __restrict__ kc_o, float* __restrict__ vc_o)
{
  int gid = blockIdx.x * 256 + threadIdx.x;   // NH*S*HD/4
  int d4 = gid & 31;
  int s  = (gid >> 5) & (S_ - 1);
  int h  = gid >> 17;
  float4 kv, vv;
  if (in_hs[s]) {
    int i = map_full[s];
    size_t src = (size_t)i * (H_ / 4) + h * 32 + d4;
    kv = ((const float4*)kb)[src];
    vv = ((const float4*)vb)[src];
  } else {
    kv = ((const float4*)kcache)[gid];
    vv = ((const float4*)vcache)[gid];
  }
  ((float4*)kc_o)[gid] = kv;
  ((float4*)vc_o)[gid] = vv;
}

__global__ __launch_bounds__(256) void aux_write(
    const float* __restrict__ outb, const float* __restrict__ auxc,
    const int* __restrict__ pruned_bit, const int* __restrict__ aux_bit,
    const int* __restrict__ map_full, float* __restrict__ aux_o)
{
  int gid = blockIdx.x * 256 + threadIdx.x;   // S*H/4
  int c4 = gid & 511;
  int s  = gid >> 9;
  float4 v;
  if (pruned_bit[s] && !aux_bit[s])
    v = ((const float4*)outb)[(size_t)map_full[s] * 512 + c4];
  else
    v = ((const float4*)auxc)[gid];
  ((float4*)aux_o)[gid] = v;
}

// ---------------- host ----------------
extern "C" void kernel_launch(void* const* d_in, const int* in_sizes, int n_in,
                              void* d_out, int out_size, void* d_ws, size_t ws_size,
                              hipStream_t stream) {
  (void)in_sizes; (void)n_in; (void)out_size; (void)ws_size;
  const float* hidden  = (const float*)d_in[0];
  const float* kcache  = (const float*)d_in[1];
  const float* vcache  = (const float*)d_in[2];
  const float* auxc    = (const float*)d_in[3];
  const int* kv_idxs   = (const int*)d_in[4];
  const int* aux_idxs  = (const int*)d_in[5];
  const int* new_idxs  = (const int*)d_in[6];
  const int* positions = (const int*)d_in[7];
  const float* wq      = (const float*)d_in[8];
  const float* wk      = (const float*)d_in[9];
  const float* wv      = (const float*)d_in[10];
  const float* wo      = (const float*)d_in[11];
  const float* w_gate  = (const float*)d_in[12];
  const float* w_up    = (const float*)d_in[13];
  const float* w_down  = (const float*)d_in[14];
  const float* ln1     = (const float*)d_in[15];
  const float* ln2     = (const float*)d_in[16];

  float* out_o = (float*)d_out;
  float* kc_o  = out_o + (size_t)NQ_ * H_;
  float* vc_o  = kc_o + (size_t)NH_ * S_ * HD_;
  float* aux_o = vc_o + (size_t)NH_ * S_ * HD_;

  // workspace (units of M4 = 4M floats = 16.78 MB), 11 slots + ints.
  // QKV phase:   0:hs 1:x-planes 2-4:qb/kb/vb 5-6:bt3_h 7:vthp(later) 8-9:bt3_l
  // attn phase:  5:khp 6:klp 7:vthp 8:ctx-planes 9:bt(wo)
  // wo split-K:  partials -> slots 2,3 (qb/kb dead); reduce3 -> hs2(10) w/ X=hs(0)
  // FFN:         act f32 -> 2-5; btg_h -> 6-7; btg_l -> 8-9
  // down split-K: partials -> slots 0,1 (hs, x-planes dead); reduce3 -> out w/ X=hs2
  float* W = (float*)d_ws;
  const size_t M4 = 4194304;                  // NQ*H
  float* hs    = W;
  ushort* xh   = (ushort*)(W + 1 * M4);
  ushort* xl   = xh + (size_t)NQ_ * H_;
  float* qb    = W + 2 * M4;
  float* kb    = W + 3 * M4;
  float* vb    = W + 4 * M4;
  ushort* bt3_h = (ushort*)(W + 5 * M4);      // 3*H*H ushorts (slots 5-6, QKV phase)
  ushort* bt3_l = (ushort*)(W + 8 * M4);      // slots 8-9 (QKV phase only)
  ushort* khp  = (ushort*)(W + 5 * M4);
  ushort* klp  = (ushort*)(W + 6 * M4);
  ushort* vthp = (ushort*)(W + 7 * M4);
  ushort* ctxh = (ushort*)(W + 8 * M4);
  ushort* ctxl = ctxh + (size_t)NQ_ * H_;
  ushort* bt_h = (ushort*)(W + 9 * M4);
  ushort* bt_l = bt_h + (size_t)H_ * H_;
  float* hs2   = W + 10 * M4;
  float* act   = W + 2 * M4;                  // slots 2-5 (FFN phase)
  ushort* btg_h = (ushort*)(W + 6 * M4);      // slots 6-7
  ushort* btg_l = (ushort*)(W + 8 * M4);      // slots 8-9
  float* wo_p0 = W + 2 * M4;                  // wo split-K partials (qb/kb dead)
  float* wo_p1 = W + 3 * M4;
  float* dn_p0 = W + 0 * M4;                  // down split-K partials (hs, x dead)
  float* dn_p1 = W + 1 * M4;
  int* ip = (int*)(W + 11 * M4);
  int* hs_idxs = ip;           ip += NQ_;
  int* q_pos   = ip;           ip += NQ_;
  int* key_tok = ip;           ip += NK_;
  int* k_pos   = ip;           ip += NK_;
  int* map_full= ip;           ip += S_;
  int* in_hs   = ip;           ip += S_;
  int* aux_bit = ip;           ip += S_;
  int* pruned  = ip;           ip += S_;
  int* last_hs = ip;           ip += 4;

  prep_build<<<16, 256, 0, stream>>>(kv_idxs, aux_idxs, new_idxs, positions,
      hs_idxs, q_pos, key_tok, k_pos, map_full, in_hs, aux_bit, pruned, last_hs);
  prep_scatter<<<10, 256, 0, stream>>>(hs_idxs, aux_idxs, map_full, in_hs, aux_bit);
  prune_set<<<2, 256, 0, stream>>>(kv_idxs, pruned);
  build_hs<<<4096, 256, 0, stream>>>(hidden, auxc, aux_idxs, hs);
  rmsnorm_split<<<NQ_, 256, 0, stream>>>(hs, ln1, xh, xl);

  const dim3 gTH(H_ / 64, H_ / 64);
  // QKV fused: B = concat(wq,wk,wv) panels, N = 6144, epi 3 de-concats C.
  wsplit_t<<<gTH, 256, 0, stream>>>(wq, bt3_h,                      bt3_l,                      H_, H_);
  wsplit_t<<<gTH, 256, 0, stream>>>(wk, bt3_h + (size_t)H_ * H_,    bt3_l + (size_t)H_ * H_,    H_, H_);
  wsplit_t<<<gTH, 256, 0, stream>>>(wv, bt3_h + (size_t)2 * H_ * H_, bt3_l + (size_t)2 * H_ * H_, H_, H_);
  gemm_mfma<<<768, 256, 0, stream>>>(xh, xl, nullptr, bt3_h, bt3_l, qb, nullptr, nullptr, NQ_, 3 * H_, H_, 3, 0);

  rope_k<<<8192, 256, 0, stream>>>(qb, kb, q_pos);
  fill_kv_planes<<<dim3(64, 16), 256, 0, stream>>>(kcache, vcache, kb, vb, kv_idxs,
      khp, klp, vthp);

  flash_mfma<<<512, 256, 0, stream>>>(qb, khp, klp, vthp, q_pos, k_pos, ctxh, ctxl);
  write_kv<<<8192, 256, 0, stream>>>(kcache, vcache, kb, vb, in_hs, map_full, kc_o, vc_o);

  // wo GEMM: split-K=2 (grid 512), partials then residual-add into hs2
  wsplit_t<<<gTH, 256, 0, stream>>>(wo, bt_h, bt_l, H_, H_);
  gemm_mfma<<<512, 256, 0, stream>>>(ctxh, ctxl, nullptr, bt_h, bt_l, wo_p0, wo_p1, nullptr, NQ_, H_, H_, 0, 1);
  reduce3<<<4096, 256, 0, stream>>>(wo_p0, wo_p1, hs, hs2);
  rmsnorm_split<<<NQ_, 256, 0, stream>>>(hs2, ln2, xh, xl);

  wsplit_t<<<dim3(FF_ / 64, H_ / 64), 256, 0, stream>>>(w_gate, btg_h, btg_l, H_, FF_);
  gemm_mfma<<<1024, 256, 0, stream>>>(xh, xl, nullptr, btg_h, btg_l, act, nullptr, nullptr, NQ_, FF_, H_, 0, 0);
  wsplit_t<<<dim3(FF_ / 64, H_ / 64), 256, 0, stream>>>(w_up, btg_h, btg_l, H_, FF_);
  gemm_mfma<<<1024, 256, 0, stream>>>(xh, xl, nullptr, btg_h, btg_l, act, nullptr, act, NQ_, FF_, H_, 2, 0);
  // down GEMM: split-K=2 (grid 512), f32-A split path, partials then residual-add
  wsplit_t<<<dim3(H_ / 64, FF_ / 64), 256, 0, stream>>>(w_down, btg_h, btg_l, FF_, H_);
  gemm_mfma<<<512, 256, 0, stream>>>(nullptr, nullptr, act, btg_h, btg_l, dn_p0, dn_p1, nullptr, NQ_, H_, FF_, 0, 1);
  reduce3<<<4096, 256, 0, stream>>>(dn_p0, dn_p1, hs2, out_o);

  aux_write<<<8192, 256, 0, stream>>>(out_o, auxc, pruned, aux_bit, map_full, aux_o);
}

// Round 8
// 1293.992 us; speedup vs baseline: 3.9364x; 1.0021x over previous
//
#include <hip/hip_runtime.h>
#include <math.h>

// ---------------- problem constants ----------------
constexpr int S_    = 4096;
constexpr int NKV   = 2048;
constexpr int NAUX  = 512;
constexpr int NNEW  = 1536;
constexpr int H_    = 2048;
constexpr int NH_   = 16;
constexpr int HD_   = 128;
constexpr int FF_   = 8192;
constexpr int NQ_   = 2048;   // NNEW + NAUX
constexpr int NK_   = 4096;   // NKV + NQ
constexpr int PRUNE = 409;
constexpr float EPSF = 1e-6f;

typedef __attribute__((ext_vector_type(8))) short bf16x8;
typedef __attribute__((ext_vector_type(16))) float f32x16;

__device__ __forceinline__ ushort f2bf(float x) {
  union { float f; unsigned u; } a; a.f = x;
  unsigned r = a.u + 0x7fffu + ((a.u >> 16) & 1u);
  return (ushort)(r >> 16);
}
__device__ __forceinline__ float bf2f(ushort h) {
  union { unsigned u; float f; } a; a.u = ((unsigned)h) << 16;
  return a.f;
}
__device__ __forceinline__ unsigned cvt_pk_bf16(float a, float b) {
  unsigned r;
  asm("v_cvt_pk_bf16_f32 %0, %1, %2" : "=v"(r) : "v"(a), "v"(b));
  return r;
}
__device__ __forceinline__ float bflo(unsigned w) { union { unsigned u; float f; } x; x.u = w << 16; return x.f; }
__device__ __forceinline__ float bfhi(unsigned w) { union { unsigned u; float f; } x; x.u = w & 0xffff0000u; return x.f; }

// async global->LDS, 16B per lane. LDS dest = base + lane*16 (HW); global src per-lane.
__device__ __forceinline__ void gload16(const ushort* g, ushort* l) {
  __builtin_amdgcn_global_load_lds(
      (const __attribute__((address_space(1))) unsigned int*)g,
      (__attribute__((address_space(3))) unsigned int*)l, 16, 0, 0);
}

// tiled bf16-plane layout: [row>>7][k>>5][(k>>3)&3][row&127][k&7]
// each 128x32 tile = 8KB contiguous = the exact LDS staging image (chunk-major).
__device__ __forceinline__ size_t tileoff(int row, int k, int K) {
  return ((size_t)((row >> 7) * (K >> 5) + (k >> 5)) << 12)
       + (size_t)((((k >> 3) & 3) << 10) + ((row & 127) << 3) + (k & 7));
}

// ---------------- index prep ----------------
__global__ __launch_bounds__(256) void prep_build(
    const int* __restrict__ kv_idxs, const int* __restrict__ aux_idxs,
    const int* __restrict__ new_idxs, const int* __restrict__ positions,
    int* hs_idxs, int* q_pos, int* key_tok, int* k_pos,
    int* map_full, int* in_hs, int* aux_bit, int* pruned_bit, int* last_hs)
{
  int t = blockIdx.x * 256 + threadIdx.x;     // grid covers 4096
  if (t < S_) { map_full[t] = 0; in_hs[t] = 0; aux_bit[t] = 0; pruned_bit[t] = 0; }
  if (t < NQ_) {
    int tok = (t < NNEW) ? new_idxs[t] : aux_idxs[t - NNEW];
    hs_idxs[t] = tok;
    q_pos[t] = positions[tok];
  }
  if (t < NK_) {
    int tok;
    if (t < NKV) tok = kv_idxs[t];
    else { int i = t - NKV; tok = (i < NNEW) ? new_idxs[i] : aux_idxs[i - NNEW]; }
    key_tok[t] = tok;
    k_pos[t] = positions[tok];
  }
  if (t < NNEW && new_idxs[t] == S_ - 1) last_hs[0] = t;
}

__global__ __launch_bounds__(256) void prep_scatter(
    const int* __restrict__ hs_idxs, const int* __restrict__ aux_idxs,
    int* map_full, int* in_hs, int* aux_bit)
{
  int t = blockIdx.x * 256 + threadIdx.x;
  if (t < NQ_) { int tok = hs_idxs[t]; map_full[tok] = t; in_hs[tok] = 1; }
  else if (t < NQ_ + NAUX) { aux_bit[aux_idxs[t - NQ_]] = 1; }
}

// Prune semantics of the reference (bug-compatible): see previous session note.
__global__ __launch_bounds__(256) void prune_set(
    const int* __restrict__ kv_idxs, int* __restrict__ pruned_bit)
{
  int t = blockIdx.x * 256 + threadIdx.x;
  if (t < PRUNE - 1) pruned_bit[kv_idxs[t]] = 1;
  if (t == PRUNE - 1) pruned_bit[S_ - 1] = 1;
}

// ---------------- hs = concat(hidden_states, aux_cache[aux_idxs]) ----------------
__global__ __launch_bounds__(256) void build_hs(
    const float* __restrict__ hidden, const float* __restrict__ auxc,
    const int* __restrict__ aux_idxs, float* __restrict__ hs)
{
  int gid = blockIdx.x * 256 + threadIdx.x;   // NQ*H/4 float4
  int c4 = gid & 511;                          // H/4 = 512
  int i  = gid >> 9;
  const float4* src;
  if (i < NNEW) src = (const float4*)hidden + (size_t)i * 512 + c4;
  else          src = (const float4*)auxc + (size_t)aux_idxs[i - NNEW] * 512 + c4;
  ((float4*)hs)[gid] = *src;
}

// ---------------- rmsnorm -> tiled bf16 hi/lo planes ----------------
__global__ __launch_bounds__(256) void rmsnorm_split(
    const float* __restrict__ in, const float* __restrict__ w,
    ushort* __restrict__ oh, ushort* __restrict__ ol)
{
  int row = blockIdx.x, t = threadIdx.x;
  const float4* r4 = (const float4*)(in + (size_t)row * H_);
  const float4* w4 = (const float4*)w;
  float ss = 0.f;
  float4 v0 = r4[t], v1 = r4[t + 256];
  ss += v0.x*v0.x + v0.y*v0.y + v0.z*v0.z + v0.w*v0.w;
  ss += v1.x*v1.x + v1.y*v1.y + v1.z*v1.z + v1.w*v1.w;
  __shared__ float red[256];
  red[t] = ss; __syncthreads();
  for (int s = 128; s > 0; s >>= 1) { if (t < s) red[t] += red[t + s]; __syncthreads(); }
  float inv = rsqrtf(red[0] / (float)H_ + EPSF);
  float4 wv0 = w4[t], wv1 = w4[t + 256];
  float f[8];
  f[0] = v0.x*inv*wv0.x; f[1] = v0.y*inv*wv0.y; f[2] = v0.z*inv*wv0.z; f[3] = v0.w*inv*wv0.w;
  f[4] = v1.x*inv*wv1.x; f[5] = v1.y*inv*wv1.y; f[6] = v1.z*inv*wv1.z; f[7] = v1.w*inv*wv1.w;
  ushort4 h0, l0, h1, l1;
  h0.x = f2bf(f[0]); l0.x = f2bf(f[0] - bf2f(h0.x));
  h0.y = f2bf(f[1]); l0.y = f2bf(f[1] - bf2f(h0.y));
  h0.z = f2bf(f[2]); l0.z = f2bf(f[2] - bf2f(h0.z));
  h0.w = f2bf(f[3]); l0.w = f2bf(f[3] - bf2f(h0.w));
  h1.x = f2bf(f[4]); l1.x = f2bf(f[4] - bf2f(h1.x));
  h1.y = f2bf(f[5]); l1.y = f2bf(f[5] - bf2f(h1.y));
  h1.z = f2bf(f[6]); l1.z = f2bf(f[6] - bf2f(h1.z));
  h1.w = f2bf(f[7]); l1.w = f2bf(f[7] - bf2f(h1.w));
  size_t o0 = tileoff(row, t * 4, H_);
  size_t o1 = tileoff(row, 1024 + t * 4, H_);
  *(ushort4*)(oh + o0) = h0; *(ushort4*)(ol + o0) = l0;
  *(ushort4*)(oh + o1) = h1; *(ushort4*)(ol + o1) = l1;
}

// ---------------- weight transpose + bf16 hi/lo split (tiled output) ----------------
// W[K][N] f32 -> Th/Tl tiled [N-panel][kstep][chunk][row][8].  grid = (N/64, K/64)
__global__ __launch_bounds__(256) void wsplit_t(
    const float* __restrict__ Wsrc, ushort* __restrict__ Th, ushort* __restrict__ Tl,
    int K, int N)
{
  __shared__ float tile[64][65];
  const int bn = blockIdx.x * 64, bk = blockIdx.y * 64;
  const int t = threadIdx.x;
  #pragma unroll
  for (int r = 0; r < 4; ++r) {
    int idx = t + 256 * r;
    int row = idx >> 4, c = (idx & 15) * 4;
    float4 v = *(const float4*)(Wsrc + (size_t)(bk + row) * N + bn + c);
    tile[row][c] = v.x; tile[row][c+1] = v.y; tile[row][c+2] = v.z; tile[row][c+3] = v.w;
  }
  __syncthreads();
  #pragma unroll
  for (int r = 0; r < 4; ++r) {
    int idx = t + 256 * r;
    int n = bn + (idx >> 4), k = bk + (idx & 15) * 4;
    int kl = k - bk;
    float v0 = tile[kl][n - bn], v1 = tile[kl+1][n - bn], v2 = tile[kl+2][n - bn], v3 = tile[kl+3][n - bn];
    ushort4 h, l;
    h.x = f2bf(v0); l.x = f2bf(v0 - bf2f(h.x));
    h.y = f2bf(v1); l.y = f2bf(v1 - bf2f(h.y));
    h.z = f2bf(v2); l.z = f2bf(v2 - bf2f(h.z));
    h.w = f2bf(v3); l.w = f2bf(v3 - bf2f(h.w));
    size_t off = tileoff(n, k, K);
    *(ushort4*)(Th + off) = h;
    *(ushort4*)(Tl + off) = l;
  }
}

// ---------------- bf16x3 MFMA GEMM, double-buffered global_load_lds staging ----------------
// A: tiled planes Ah/Al, or f32 Af (split in-flight via regs, T14 issue-early).
// B: tiled planes Bh/Bl. C f32 row-major.
// epi: 0 plain, 1 C=X+acc, 2 C=silu(X)*acc, 3 QKV-fused de-concat (N=3*2048).
// split=1: K halved across grid halves; upper half writes partials to C2.
// Pipeline per k-step: issue next-tile staging into buf nxt -> MFMAs on buf cur ->
// [Af: convert+ds_write nxt] -> __syncthreads() (compiler-managed drain; no raw
// barriers / no inline-asm waitcnt -> no rule-18 reordering hazard).
__global__ __launch_bounds__(256) void gemm_mfma(
    const ushort* __restrict__ Ah, const ushort* __restrict__ Al,
    const float* __restrict__ Af,
    const ushort* __restrict__ Bh, const ushort* __restrict__ Bl,
    float* __restrict__ C, float* __restrict__ C2, const float* __restrict__ X,
    int M, int N, int K, int epi, int split)
{
  __shared__ __align__(16) ushort sAh[2][4096];
  __shared__ __align__(16) ushort sAl[2][4096];
  __shared__ __align__(16) ushort sBh[2][4096];
  __shared__ __align__(16) ushort sBl[2][4096];
  int flat = blockIdx.x;
  int kbeg = 0, kend = K;
  float* Cout = C;
  if (split) {
    int nb2 = gridDim.x >> 1;
    if (flat >= nb2) { flat -= nb2; Cout = C2; kbeg = K >> 1; }
    else             { kend = K >> 1; }
  }
  const int MB = M >> 7;
  const int cM = MB >> 3;
  const int xcd = flat & 7, idxr = flat >> 3;
  const int byi = xcd * cM + (idxr % cM);      // A panel: XCD-resident slab
  const int bxi = idxr / cM;                   // B panel: streamed (L3)
  const int bm = byi * 128, bn = bxi * 128;
  const int t = threadIdx.x;
  const int lane = t & 63;
  const int wid = t >> 6;
  const int wr = wid >> 1, wc = wid & 1;
  const int fr = lane & 31;
  const int kg = lane >> 5;
  const int ub0 = wid * 128;
  const int Ksteps = K >> 5;
  const int ks0 = kbeg >> 5;
  const int NS = (kend - kbeg) >> 5;

  f32x16 acc[2][2];
  #pragma unroll
  for (int mi = 0; mi < 2; ++mi)
    #pragma unroll
    for (int ni = 0; ni < 2; ++ni)
      #pragma unroll
      for (int r = 0; r < 16; ++r) acc[mi][ni][r] = 0.f;

  // ---- prologue: stage k-step ks0 into buf 0 ----
  {
    const size_t tB = ((size_t)(bxi * Ksteps + ks0)) << 12;
    const ushort* b0 = Bh + tB;
    const ushort* b1 = Bl + tB;
    gload16(b0 + (size_t)(ub0 + lane) * 8,      &sBh[0][ub0 * 8]);
    gload16(b0 + (size_t)(ub0 + 64 + lane) * 8, &sBh[0][(ub0 + 64) * 8]);
    gload16(b1 + (size_t)(ub0 + lane) * 8,      &sBl[0][ub0 * 8]);
    gload16(b1 + (size_t)(ub0 + 64 + lane) * 8, &sBl[0][(ub0 + 64) * 8]);
    if (Af) {
      #pragma unroll
      for (int r = 0; r < 2; ++r) {
        int u = t + 256 * r;
        int row = u >> 2, ch = u & 3;
        const float* s0 = Af + (size_t)(bm + row) * K + kbeg + ch * 8;
        float4 v0 = *(const float4*)s0, v1 = *(const float4*)(s0 + 4);
        float f[8] = {v0.x,v0.y,v0.z,v0.w,v1.x,v1.y,v1.z,v1.w};
        union { ushort u16[8]; uint4 q; } Hh, Ll;
        #pragma unroll
        for (int j = 0; j < 8; ++j) {
          ushort hh = f2bf(f[j]);
          Hh.u16[j] = hh; Ll.u16[j] = f2bf(f[j] - bf2f(hh));
        }
        *(uint4*)&sAh[0][ch * 1024 + row * 8] = Hh.q;
        *(uint4*)&sAl[0][ch * 1024 + row * 8] = Ll.q;
      }
    } else {
      const size_t tA = ((size_t)(byi * Ksteps + ks0)) << 12;
      const ushort* a0 = Ah + tA;
      const ushort* a1 = Al + tA;
      gload16(a0 + (size_t)(ub0 + lane) * 8,      &sAh[0][ub0 * 8]);
      gload16(a0 + (size_t)(ub0 + 64 + lane) * 8, &sAh[0][(ub0 + 64) * 8]);
      gload16(a1 + (size_t)(ub0 + lane) * 8,      &sAl[0][ub0 * 8]);
      gload16(a1 + (size_t)(ub0 + 64 + lane) * 8, &sAl[0][(ub0 + 64) * 8]);
    }
  }
  __syncthreads();

  int cur = 0;
  for (int s = 0; s < NS; ++s) {
    const int nxt = cur ^ 1;
    const bool hasNext = (s + 1 < NS);
    // ---- issue next-tile staging first (latency hides under MFMAs) ----
    float4 av0[2], av1[2];
    if (hasNext) {
      const int ksn = ks0 + s + 1;
      const size_t tB = ((size_t)(bxi * Ksteps + ksn)) << 12;
      const ushort* b0 = Bh + tB;
      const ushort* b1 = Bl + tB;
      gload16(b0 + (size_t)(ub0 + lane) * 8,      &sBh[nxt][ub0 * 8]);
      gload16(b0 + (size_t)(ub0 + 64 + lane) * 8, &sBh[nxt][(ub0 + 64) * 8]);
      gload16(b1 + (size_t)(ub0 + lane) * 8,      &sBl[nxt][ub0 * 8]);
      gload16(b1 + (size_t)(ub0 + 64 + lane) * 8, &sBl[nxt][(ub0 + 64) * 8]);
      if (Af) {
        #pragma unroll
        for (int r = 0; r < 2; ++r) {
          int u = t + 256 * r;
          int row = u >> 2, ch = u & 3;
          const float* s0 = Af + (size_t)(bm + row) * K + ksn * 32 + ch * 8;
          av0[r] = *(const float4*)s0;
          av1[r] = *(const float4*)(s0 + 4);
        }
      } else {
        const size_t tA = ((size_t)(byi * Ksteps + ksn)) << 12;
        const ushort* a0 = Ah + tA;
        const ushort* a1 = Al + tA;
        gload16(a0 + (size_t)(ub0 + lane) * 8,      &sAh[nxt][ub0 * 8]);
        gload16(a0 + (size_t)(ub0 + 64 + lane) * 8, &sAh[nxt][(ub0 + 64) * 8]);
        gload16(a1 + (size_t)(ub0 + lane) * 8,      &sAl[nxt][ub0 * 8]);
        gload16(a1 + (size_t)(ub0 + 64 + lane) * 8, &sAl[nxt][(ub0 + 64) * 8]);
      }
    }
    // ---- MFMAs on buf cur (both K=16 sub-slices) ----
    #pragma unroll
    for (int ksl = 0; ksl < 2; ++ksl) {
      const int co = (ksl * 2 + kg) * 1024;
      bf16x8 ah[2], al[2], bh[2], bl[2];
      #pragma unroll
      for (int mi = 0; mi < 2; ++mi) {
        ah[mi] = *(const bf16x8*)&sAh[cur][co + (wr * 64 + mi * 32 + fr) * 8];
        al[mi] = *(const bf16x8*)&sAl[cur][co + (wr * 64 + mi * 32 + fr) * 8];
        bh[mi] = *(const bf16x8*)&sBh[cur][co + (wc * 64 + mi * 32 + fr) * 8];
        bl[mi] = *(const bf16x8*)&sBl[cur][co + (wc * 64 + mi * 32 + fr) * 8];
      }
      __builtin_amdgcn_s_setprio(1);
      #pragma unroll
      for (int mi = 0; mi < 2; ++mi)
        #pragma unroll
        for (int ni = 0; ni < 2; ++ni) {
          acc[mi][ni] = __builtin_amdgcn_mfma_f32_32x32x16_bf16(ah[mi], bh[ni], acc[mi][ni], 0, 0, 0);
          acc[mi][ni] = __builtin_amdgcn_mfma_f32_32x32x16_bf16(ah[mi], bl[ni], acc[mi][ni], 0, 0, 0);
          acc[mi][ni] = __builtin_amdgcn_mfma_f32_32x32x16_bf16(al[mi], bh[ni], acc[mi][ni], 0, 0, 0);
        }
      __builtin_amdgcn_s_setprio(0);
    }
    // ---- finish A split for Af path (convert regs -> LDS nxt) ----
    if (hasNext && Af) {
      #pragma unroll
      for (int r = 0; r < 2; ++r) {
        int u = t + 256 * r;
        int row = u >> 2, ch = u & 3;
        float f[8] = {av0[r].x,av0[r].y,av0[r].z,av0[r].w,av1[r].x,av1[r].y,av1[r].z,av1[r].w};
        union { ushort u16[8]; uint4 q; } Hh, Ll;
        #pragma unroll
        for (int j = 0; j < 8; ++j) {
          ushort hh = f2bf(f[j]);
          Hh.u16[j] = hh; Ll.u16[j] = f2bf(f[j] - bf2f(hh));
        }
        *(uint4*)&sAh[nxt][ch * 1024 + row * 8] = Hh.q;
        *(uint4*)&sAl[nxt][ch * 1024 + row * 8] = Ll.q;
      }
    }
    __syncthreads();
    cur = nxt;
  }

  #pragma unroll
  for (int mi = 0; mi < 2; ++mi) {
    #pragma unroll
    for (int ni = 0; ni < 2; ++ni) {
      #pragma unroll
      for (int r = 0; r < 16; ++r) {
        int row = bm + wr * 64 + mi * 32 + (r & 3) + 8 * (r >> 2) + 4 * kg;
        int col = bn + wc * 64 + ni * 32 + fr;
        float v = acc[mi][ni][r];
        size_t idx;
        if (epi == 3) {
          int mtx = col >> 11, cc = col & 2047;
          idx = ((size_t)mtx * M + row) * 2048 + cc;
        } else {
          idx = (size_t)row * N + col;
          if (!split) {
            if (epi == 1) v += X[idx];
            else if (epi == 2) { float g = X[idx]; v = (g / (1.f + expf(-g))) * v; }
          }
        }
        Cout[idx] = v;
      }
    }
  }
}

// ---------------- out = a + b + x (split-K reduce + residual) ----------------
__global__ __launch_bounds__(256) void reduce3(
    const float* __restrict__ a, const float* __restrict__ b,
    const float* __restrict__ x, float* __restrict__ o)
{
  int g = blockIdx.x * 256 + threadIdx.x;     // NQ*H/4 float4
  float4 va = ((const float4*)a)[g];
  float4 vb = ((const float4*)b)[g];
  float4 vx = ((const float4*)x)[g];
  float4 vo;
  vo.x = va.x + vb.x + vx.x; vo.y = va.y + vb.y + vx.y;
  vo.z = va.z + vb.z + vx.z; vo.w = va.w + vb.w + vx.w;
  ((float4*)o)[g] = vo;
}

// ---------------- RoPE in-place on q and k ----------------
__global__ __launch_bounds__(256) void rope_k(
    float* __restrict__ qb, float* __restrict__ kb, const int* __restrict__ q_pos)
{
  int gid = blockIdx.x * 256 + threadIdx.x;   // NQ*NH*64
  int d = gid & 63;
  int h = (gid >> 6) & 15;
  int i = gid >> 10;
  int p = q_pos[i];
  double ang = (double)p * exp((double)d * -0.14391156831212787);
  float c = (float)cos(ang), s = (float)sin(ang);
  size_t ia = (size_t)i * H_ + h * HD_ + d;
  size_t ib = ia + 64;
  float qa = qb[ia], qbv = qb[ib];
  qb[ia] = qa * c - qbv * s;
  qb[ib] = qbv * c + qa * s;
  float ka = kb[ia], kbv = kb[ib];
  kb[ia] = ka * c - kbv * s;
  kb[ib] = kbv * c + ka * s;
}

// ---------------- K (hi/lo) + V^T (hi) bf16 planes ----------------
// kh/kl: [NH][NK][HD]; vth: TILE-MAJOR [NH][NK/64][HD][64] so flash V-frag
// loads stride 128B (2 lanes per 64B line) instead of 8KB (1 lane/line).
// grid = (NK/64, NH)
__global__ __launch_bounds__(256) void fill_kv_planes(
    const float* __restrict__ kcache, const float* __restrict__ vcache,
    const float* __restrict__ kb, const float* __restrict__ vb,
    const int* __restrict__ kv_idxs,
    ushort* __restrict__ kh, ushort* __restrict__ kl,
    ushort* __restrict__ vth)
{
  __shared__ float vt[64][133];
  const int h = blockIdx.y;
  const int kbase = blockIdx.x * 64;
  const int t = threadIdx.x;
  #pragma unroll
  for (int r = 0; r < 8; ++r) {
    int idx = t + 256 * r;                     // 2048 float4
    int key = idx >> 5, d4 = idx & 31;
    int j = kbase + key;
    float4 kv, vv;
    if (j < NKV) {
      int tok = kv_idxs[j];
      size_t src = ((size_t)h * S_ + tok) * 32 + d4;
      kv = ((const float4*)kcache)[src];
      vv = ((const float4*)vcache)[src];
    } else {
      int i = j - NKV;
      size_t src = (size_t)i * 512 + h * 32 + d4;
      kv = ((const float4*)kb)[src];
      vv = ((const float4*)vb)[src];
    }
    ushort4 hh, ll;
    hh.x = f2bf(kv.x); ll.x = f2bf(kv.x - bf2f(hh.x));
    hh.y = f2bf(kv.y); ll.y = f2bf(kv.y - bf2f(hh.y));
    hh.z = f2bf(kv.z); ll.z = f2bf(kv.z - bf2f(hh.z));
    hh.w = f2bf(kv.w); ll.w = f2bf(kv.w - bf2f(hh.w));
    size_t dst = ((size_t)(h * NK_ + j)) * 128 + d4 * 4;
    *(ushort4*)(kh + dst) = hh;
    *(ushort4*)(kl + dst) = ll;
    vt[key][d4 * 4 + 0] = vv.x; vt[key][d4 * 4 + 1] = vv.y;
    vt[key][d4 * 4 + 2] = vv.z; vt[key][d4 * 4 + 3] = vv.w;
  }
  __syncthreads();
  #pragma unroll
  for (int r = 0; r < 8; ++r) {
    int idx = t + 256 * r;                     // 2048 groups of 4 keys
    int d = idx >> 4, kq = (idx & 15) * 4;
    float v0 = vt[kq + 0][d], v1 = vt[kq + 1][d], v2 = vt[kq + 2][d], v3 = vt[kq + 3][d];
    ushort4 hh;
    hh.x = f2bf(v0); hh.y = f2bf(v1); hh.z = f2bf(v2); hh.w = f2bf(v3);
    size_t dst = (((size_t)h * 64 + blockIdx.x) * 128 + d) * 64 + kq;
    *(ushort4*)(vth + dst) = hh;
  }
}

// ---------------- MFMA flash attention (barrier-free K-loop) ----------------
// Flat grid 512, XCD-affine heads + balanced q-block pairing.
// No in-loop LDS/staging: each wave loads its K/V MFMA fragments directly
// from global (L2-resident planes). V^T is tile-major -> coalesced frag loads.
// ctx written as TILED bf16 hi/lo planes (A-operand of the wo GEMM).
struct MergeLDS { float acc[2][32][128]; float ml[2][2][32]; };

__global__ __launch_bounds__(256, 2) void flash_mfma(
    const float* __restrict__ qb, const ushort* __restrict__ khg,
    const ushort* __restrict__ klg, const ushort* __restrict__ vthg,
    const int* __restrict__ q_pos, const int* __restrict__ k_pos,
    ushort* __restrict__ ctxh, ushort* __restrict__ ctxl)
{
  __shared__ MergeLDS U;
  const int b = blockIdx.x;
  const int half = b >> 8, r_ = b & 255;
  const int h = (r_ & 7) * 2 + ((r_ >> 3) & 1);
  const int q16 = r_ >> 4;
  const int q0 = (half ? (31 - 2 * q16) : (2 * q16)) * 64;
  const int t = threadIdx.x;
  const int w = t >> 6, lane = t & 63;
  const int wq = w & 1, wk = w >> 1;
  const int kg = lane >> 5;
  const int qc = lane & 31;
  const int qi = q0 + wq * 32 + qc;
  const float scale = 0.08838834764831844f;    // 1/sqrt(128)

  bf16x8 qh[8], ql[8];
  {
    const float4* q4 = (const float4*)qb;
    #pragma unroll
    for (int s = 0; s < 8; ++s) {
      size_t a = (size_t)qi * 512 + h * 32 + s * 4 + kg * 2;
      float4 f0 = q4[a], f1 = q4[a + 1];
      float f[8] = {f0.x, f0.y, f0.z, f0.w, f1.x, f1.y, f1.z, f1.w};
      union { ushort u[8]; bf16x8 v; } Hq, Lq;
      #pragma unroll
      for (int j = 0; j < 8; ++j) {
        float qs = f[j] * scale;
        ushort hh = f2bf(qs);
        Hq.u[j] = hh; Lq.u[j] = f2bf(qs - bf2f(hh));
      }
      qh[s] = Hq.v; ql[s] = Lq.v;
    }
  }
  const int qp = q_pos[qi];
  const int wave_qmin = __shfl(qp, 0);
  const int wave_qmax = __shfl(qp, 31);
  const int bqmax = q_pos[q0 + 63];

  const ushort* kh_base = khg + (size_t)h * NK_ * 128;
  const ushort* kl_base = klg + (size_t)h * NK_ * 128;
  const ushort* vt_base = vthg + (size_t)h * NK_ * 128;   // [NK/64][128][64]

  f32x16 acc[4];
  #pragma unroll
  for (int f = 0; f < 4; ++f)
    #pragma unroll
    for (int r = 0; r < 16; ++r) acc[f][r] = 0.f;
  float m_run = -INFINITY, l_run = 0.f;

  for (int kt = 0; kt < NK_ / 64; ++kt) {
    const int kbase = kt * 64;
    if (k_pos[kbase] > bqmax) continue;        // block-uniform causal skip
    const int krow0 = kbase + wk * 32;
    const int kpv = k_pos[krow0 + qc];
    const int kmin = __shfl(kpv, 0);
    if (kmin > wave_qmax) continue;            // wave-uniform skip (finer)
    const bool needmask = (__shfl(kpv, 31) > wave_qmin);

    f32x16 sA, sB;
    #pragma unroll
    for (int r = 0; r < 16; ++r) { sA[r] = 0.f; sB[r] = 0.f; }
    const ushort* krow = kh_base + (size_t)(krow0 + qc) * 128 + kg * 8;
    const ushort* lrow = kl_base + (size_t)(krow0 + qc) * 128 + kg * 8;
    __builtin_amdgcn_s_setprio(1);
    #pragma unroll
    for (int s = 0; s < 8; ++s) {
      bf16x8 khf = *(const bf16x8*)(krow + s * 16);
      bf16x8 klf = *(const bf16x8*)(lrow + s * 16);
      sA = __builtin_amdgcn_mfma_f32_32x32x16_bf16(khf, qh[s], sA, 0, 0, 0);
      sB = __builtin_amdgcn_mfma_f32_32x32x16_bf16(khf, ql[s], sB, 0, 0, 0);
      sB = __builtin_amdgcn_mfma_f32_32x32x16_bf16(klf, qh[s], sB, 0, 0, 0);
    }
    __builtin_amdgcn_s_setprio(0);
    // V fragments from tile-major layout (issued early, hide under softmax)
    bf16x8 vf[2][4];
    {
      const ushort* vtile = vt_base + (size_t)kt * 8192;   // 128*64
      #pragma unroll
      for (int ks = 0; ks < 2; ++ks) {
        const int kc = wk * 32 + ks * 16 + kg * 8;          // within-tile key
        #pragma unroll
        for (int f = 0; f < 4; ++f)
          vf[ks][f] = *(const bf16x8*)(vtile + (f * 32 + qc) * 64 + kc);
      }
    }
    float sc[16];
    #pragma unroll
    for (int r = 0; r < 16; ++r) sc[r] = sA[r] + sB[r];
    if (needmask) {
      #pragma unroll
      for (int r = 0; r < 16; ++r) {
        int crow = (r & 3) + 8 * (r >> 2) + 4 * kg;
        sc[r] = (__shfl(kpv, crow) <= qp) ? sc[r] : -INFINITY;
      }
    }
    float mloc = sc[0];
    #pragma unroll
    for (int r = 1; r < 16; ++r) mloc = fmaxf(mloc, sc[r]);
    mloc = fmaxf(mloc, __shfl_xor(mloc, 32));
    float m_new = fmaxf(m_run, mloc);
    float mexp = (m_new == -INFINITY) ? 0.f : m_new;
    if (__any(m_new > m_run)) {
      float aa = __expf(m_run - mexp);
      l_run *= aa;
      #pragma unroll
      for (int f = 0; f < 4; ++f)
        #pragma unroll
        for (int r = 0; r < 16; ++r) acc[f][r] *= aa;
    }
    m_run = m_new;
    float p[16]; float psum = 0.f;
    #pragma unroll
    for (int r = 0; r < 16; ++r) { p[r] = __expf(sc[r] - mexp); psum += p[r]; }
    psum += __shfl_xor(psum, 32);
    l_run += psum;
    bf16x8 pfh[2], pfl[2];
    #pragma unroll
    for (int sl = 0; sl < 2; ++sl) {
      const float* pp = p + sl * 8;
      unsigned a0 = cvt_pk_bf16(pp[0], pp[1]);
      unsigned a1 = cvt_pk_bf16(pp[2], pp[3]);
      unsigned b0 = cvt_pk_bf16(pp[4], pp[5]);
      unsigned b1 = cvt_pk_bf16(pp[6], pp[7]);
      unsigned a0x = (unsigned)__shfl_xor((int)a0, 32);
      unsigned a1x = (unsigned)__shfl_xor((int)a1, 32);
      unsigned b0x = (unsigned)__shfl_xor((int)b0, 32);
      unsigned b1x = (unsigned)__shfl_xor((int)b1, 32);
      union { unsigned wd[4]; bf16x8 v; } PH, PL;
      PH.wd[0] = kg ? b0x : a0;
      PH.wd[1] = kg ? b1x : a1;
      PH.wd[2] = kg ? b0 : a0x;
      PH.wd[3] = kg ? b1 : a1x;
      float r0 = pp[0] - bflo(a0), r1 = pp[1] - bfhi(a0);
      float r2 = pp[2] - bflo(a1), r3 = pp[3] - bfhi(a1);
      float r4 = pp[4] - bflo(b0), r5 = pp[5] - bfhi(b0);
      float r6 = pp[6] - bflo(b1), r7 = pp[7] - bfhi(b1);
      unsigned c0 = cvt_pk_bf16(r0, r1);
      unsigned c1 = cvt_pk_bf16(r2, r3);
      unsigned d0 = cvt_pk_bf16(r4, r5);
      unsigned d1 = cvt_pk_bf16(r6, r7);
      unsigned c0x = (unsigned)__shfl_xor((int)c0, 32);
      unsigned c1x = (unsigned)__shfl_xor((int)c1, 32);
      unsigned d0x = (unsigned)__shfl_xor((int)d0, 32);
      unsigned d1x = (unsigned)__shfl_xor((int)d1, 32);
      PL.wd[0] = kg ? d0x : c0;
      PL.wd[1] = kg ? d1x : c1;
      PL.wd[2] = kg ? d0 : c0x;
      PL.wd[3] = kg ? d1 : c1x;
      pfh[sl] = PH.v; pfl[sl] = PL.v;
    }
    __builtin_amdgcn_s_setprio(1);
    #pragma unroll
    for (int ks = 0; ks < 2; ++ks) {
      acc[0] = __builtin_amdgcn_mfma_f32_32x32x16_bf16(vf[ks][0], pfh[ks], acc[0], 0, 0, 0);
      acc[1] = __builtin_amdgcn_mfma_f32_32x32x16_bf16(vf[ks][1], pfh[ks], acc[1], 0, 0, 0);
      acc[2] = __builtin_amdgcn_mfma_f32_32x32x16_bf16(vf[ks][2], pfh[ks], acc[2], 0, 0, 0);
      acc[3] = __builtin_amdgcn_mfma_f32_32x32x16_bf16(vf[ks][3], pfh[ks], acc[3], 0, 0, 0);
      acc[0] = __builtin_amdgcn_mfma_f32_32x32x16_bf16(vf[ks][0], pfl[ks], acc[0], 0, 0, 0);
      acc[1] = __builtin_amdgcn_mfma_f32_32x32x16_bf16(vf[ks][1], pfl[ks], acc[1], 0, 0, 0);
      acc[2] = __builtin_amdgcn_mfma_f32_32x32x16_bf16(vf[ks][2], pfl[ks], acc[2], 0, 0, 0);
      acc[3] = __builtin_amdgcn_mfma_f32_32x32x16_bf16(vf[ks][3], pfl[ks], acc[3], 0, 0, 0);
    }
    __builtin_amdgcn_s_setprio(0);
  }

  if (wk == 1) {
    #pragma unroll
    for (int f = 0; f < 4; ++f)
      #pragma unroll
      for (int rq = 0; rq < 4; ++rq) {
        float4 v;
        v.x = acc[f][rq * 4 + 0]; v.y = acc[f][rq * 4 + 1];
        v.z = acc[f][rq * 4 + 2]; v.w = acc[f][rq * 4 + 3];
        *(float4*)(&U.acc[wq][qc][f * 32 + kg * 4 + rq * 8]) = v;
      }
    if (kg == 0) { U.ml[wq][0][qc] = m_run; U.ml[wq][1][qc] = l_run; }
  }
  __syncthreads();
  if (wk == 0) {
    float m2 = U.ml[wq][0][qc];
    float l2 = U.ml[wq][1][qc];
    float mm = fmaxf(m_run, m2);
    float a1 = __expf(m_run - mm);
    float a2 = __expf(m2 - mm);
    float inv = 1.f / (l_run * a1 + l2 * a2);
    #pragma unroll
    for (int f = 0; f < 4; ++f)
      #pragma unroll
      for (int rq = 0; rq < 4; ++rq) {
        float4 oth = *(const float4*)(&U.acc[wq][qc][f * 32 + kg * 4 + rq * 8]);
        float o[4];
        o[0] = (acc[f][rq * 4 + 0] * a1 + oth.x * a2) * inv;
        o[1] = (acc[f][rq * 4 + 1] * a1 + oth.y * a2) * inv;
        o[2] = (acc[f][rq * 4 + 2] * a1 + oth.z * a2) * inv;
        o[3] = (acc[f][rq * 4 + 3] * a1 + oth.w * a2) * inv;
        ushort4 hh, ll;
        hh.x = f2bf(o[0]); ll.x = f2bf(o[0] - bf2f(hh.x));
        hh.y = f2bf(o[1]); ll.y = f2bf(o[1] - bf2f(hh.y));
        hh.z = f2bf(o[2]); ll.z = f2bf(o[2] - bf2f(hh.z));
        hh.w = f2bf(o[3]); ll.w = f2bf(o[3] - bf2f(hh.w));
        int d = h * 128 + f * 32 + kg * 4 + rq * 8;
        size_t oidx = tileoff(qi, d, H_);
        *(ushort4*)(ctxh + oidx) = hh;
        *(ushort4*)(ctxl + oidx) = ll;
      }
  }
}

// ---------------- cache scatter outputs ----------------
__global__ __launch_bounds__(256) void write_kv(
    const float* __restrict__ kcache, const float* __restrict__ vcache,
    const float* __restrict__ kb, const float* __restrict__ vb,
    const int* __restrict__ in_hs, const int* __restrict__ map_full,
    float* __restrict__ kc_o, float* __restrict__ vc_o)
{
  int gid = blockIdx.x * 256 + threadIdx.x;   // NH*S*HD/4
  int d4 = gid & 31;
  int s  = (gid >> 5) & (S_ - 1);
  int h  = gid >> 17;
  float4 kv, vv;
  if (in_hs[s]) {
    int i = map_full[s];
    size_t src = (size_t)i * (H_ / 4) + h * 32 + d4;
    kv = ((const float4*)kb)[src];
    vv = ((const float4*)vb)[src];
  } else {
    kv = ((const float4*)kcache)[gid];
    vv = ((const float4*)vcache)[gid];
  }
  ((float4*)kc_o)[gid] = kv;
  ((float4*)vc_o)[gid] = vv;
}

__global__ __launch_bounds__(256) void aux_write(
    const float* __restrict__ outb, const float* __restrict__ auxc,
    const int* __restrict__ pruned_bit, const int* __restrict__ aux_bit,
    const int* __restrict__ map_full, float* __restrict__ aux_o)
{
  int gid = blockIdx.x * 256 + threadIdx.x;   // S*H/4
  int c4 = gid & 511;
  int s  = gid >> 9;
  float4 v;
  if (pruned_bit[s] && !aux_bit[s])
    v = ((const float4*)outb)[(size_t)map_full[s] * 512 + c4];
  else
    v = ((const float4*)auxc)[gid];
  ((float4*)aux_o)[gid] = v;
}

// ---------------- host ----------------
extern "C" void kernel_launch(void* const* d_in, const int* in_sizes, int n_in,
                              void* d_out, int out_size, void* d_ws, size_t ws_size,
                              hipStream_t stream) {
  (void)in_sizes; (void)n_in; (void)out_size; (void)ws_size;
  const float* hidden  = (const float*)d_in[0];
  const float* kcache  = (const float*)d_in[1];
  const float* vcache  = (const float*)d_in[2];
  const float* auxc    = (const float*)d_in[3];
  const int* kv_idxs   = (const int*)d_in[4];
  const int* aux_idxs  = (const int*)d_in[5];
  const int* new_idxs  = (const int*)d_in[6];
  const int* positions = (const int*)d_in[7];
  const float* wq      = (const float*)d_in[8];
  const float* wk      = (const float*)d_in[9];
  const float* wv      = (const float*)d_in[10];
  const float* wo      = (const float*)d_in[11];
  const float* w_gate  = (const float*)d_in[12];
  const float* w_up    = (const float*)d_in[13];
  const float* w_down  = (const float*)d_in[14];
  const float* ln1     = (const float*)d_in[15];
  const float* ln2     = (const float*)d_in[16];

  float* out_o = (float*)d_out;
  float* kc_o  = out_o + (size_t)NQ_ * H_;
  float* vc_o  = kc_o + (size_t)NH_ * S_ * HD_;
  float* aux_o = vc_o + (size_t)NH_ * S_ * HD_;

  // workspace (units of M4 = 4M floats = 16.78 MB), 11 slots + ints (round-7 layout)
  float* W = (float*)d_ws;
  const size_t M4 = 4194304;                  // NQ*H
  float* hs    = W;
  ushort* xh   = (ushort*)(W + 1 * M4);
  ushort* xl   = xh + (size_t)NQ_ * H_;
  float* qb    = W + 2 * M4;
  float* kb    = W + 3 * M4;
  float* vb    = W + 4 * M4;
  ushort* bt3_h = (ushort*)(W + 5 * M4);      // 3*H*H ushorts (slots 5-6, QKV phase)
  ushort* bt3_l = (ushort*)(W + 8 * M4);      // slots 8-9 (QKV phase only)
  ushort* khp  = (ushort*)(W + 5 * M4);
  ushort* klp  = (ushort*)(W + 6 * M4);
  ushort* vthp = (ushort*)(W + 7 * M4);
  ushort* ctxh = (ushort*)(W + 8 * M4);
  ushort* ctxl = ctxh + (size_t)NQ_ * H_;
  ushort* bt_h = (ushort*)(W + 9 * M4);
  ushort* bt_l = bt_h + (size_t)H_ * H_;
  float* hs2   = W + 10 * M4;
  float* act   = W + 2 * M4;                  // slots 2-5 (FFN phase)
  ushort* btg_h = (ushort*)(W + 6 * M4);      // slots 6-7
  ushort* btg_l = (ushort*)(W + 8 * M4);      // slots 8-9
  float* wo_p0 = W + 2 * M4;                  // wo split-K partials (qb/kb dead)
  float* wo_p1 = W + 3 * M4;
  float* dn_p0 = W + 0 * M4;                  // down split-K partials (hs, x dead)
  float* dn_p1 = W + 1 * M4;
  int* ip = (int*)(W + 11 * M4);
  int* hs_idxs = ip;           ip += NQ_;
  int* q_pos   = ip;           ip += NQ_;
  int* key_tok = ip;           ip += NK_;
  int* k_pos   = ip;           ip += NK_;
  int* map_full= ip;           ip += S_;
  int* in_hs   = ip;           ip += S_;
  int* aux_bit = ip;           ip += S_;
  int* pruned  = ip;           ip += S_;
  int* last_hs = ip;           ip += 4;

  prep_build<<<16, 256, 0, stream>>>(kv_idxs, aux_idxs, new_idxs, positions,
      hs_idxs, q_pos, key_tok, k_pos, map_full, in_hs, aux_bit, pruned, last_hs);
  prep_scatter<<<10, 256, 0, stream>>>(hs_idxs, aux_idxs, map_full, in_hs, aux_bit);
  prune_set<<<2, 256, 0, stream>>>(kv_idxs, pruned);
  build_hs<<<4096, 256, 0, stream>>>(hidden, auxc, aux_idxs, hs);
  rmsnorm_split<<<NQ_, 256, 0, stream>>>(hs, ln1, xh, xl);

  const dim3 gTH(H_ / 64, H_ / 64);
  // QKV fused: B = concat(wq,wk,wv) panels, N = 6144, epi 3 de-concats C.
  wsplit_t<<<gTH, 256, 0, stream>>>(wq, bt3_h,                      bt3_l,                      H_, H_);
  wsplit_t<<<gTH, 256, 0, stream>>>(wk, bt3_h + (size_t)H_ * H_,    bt3_l + (size_t)H_ * H_,    H_, H_);
  wsplit_t<<<gTH, 256, 0, stream>>>(wv, bt3_h + (size_t)2 * H_ * H_, bt3_l + (size_t)2 * H_ * H_, H_, H_);
  gemm_mfma<<<768, 256, 0, stream>>>(xh, xl, nullptr, bt3_h, bt3_l, qb, nullptr, nullptr, NQ_, 3 * H_, H_, 3, 0);

  rope_k<<<8192, 256, 0, stream>>>(qb, kb, q_pos);
  fill_kv_planes<<<dim3(64, 16), 256, 0, stream>>>(kcache, vcache, kb, vb, kv_idxs,
      khp, klp, vthp);

  flash_mfma<<<512, 256, 0, stream>>>(qb, khp, klp, vthp, q_pos, k_pos, ctxh, ctxl);
  write_kv<<<8192, 256, 0, stream>>>(kcache, vcache, kb, vb, in_hs, map_full, kc_o, vc_o);

  // wo GEMM: split-K=2 (grid 512), partials then residual-add into hs2
  wsplit_t<<<gTH, 256, 0, stream>>>(wo, bt_h, bt_l, H_, H_);
  gemm_mfma<<<512, 256, 0, stream>>>(ctxh, ctxl, nullptr, bt_h, bt_l, wo_p0, wo_p1, nullptr, NQ_, H_, H_, 0, 1);
  reduce3<<<4096, 256, 0, stream>>>(wo_p0, wo_p1, hs, hs2);
  rmsnorm_split<<<NQ_, 256, 0, stream>>>(hs2, ln2, xh, xl);

  wsplit_t<<<dim3(FF_ / 64, H_ / 64), 256, 0, stream>>>(w_gate, btg_h, btg_l, H_, FF_);
  gemm_mfma<<<1024, 256, 0, stream>>>(xh, xl, nullptr, btg_h, btg_l, act, nullptr, nullptr, NQ_, FF_, H_, 0, 0);
  wsplit_t<<<dim3(FF_ / 64, H_ / 64), 256, 0, stream>>>(w_up, btg_h, btg_l, H_, FF_);
  gemm_mfma<<<1024, 256, 0, stream>>>(xh, xl, nullptr, btg_h, btg_l, act, nullptr, act, NQ_, FF_, H_, 2, 0);
  // down GEMM: split-K=2 (grid 512), f32-A split path, partials then residual-add
  wsplit_t<<<dim3(H_ / 64, FF_ / 64), 256, 0, stream>>>(w_down, btg_h, btg_l, FF_, H_);
  gemm_mfma<<<512, 256, 0, stream>>>(nullptr, nullptr, act, btg_h, btg_l, dn_p0, dn_p1, nullptr, NQ_, H_, FF_, 0, 1);
  reduce3<<<4096, 256, 0, stream>>>(dn_p0, dn_p1, hs2, out_o);

  aux_write<<<8192, 256, 0, stream>>>(out_o, auxc, pruned, aux_bit, map_full, aux_o);
}